// Round 1
// baseline (1551.223 us; speedup 1.0000x reference)
//
#include <hip/hip_runtime.h>
#include <math.h>

// ---------------- problem constants ----------------
constexpr int Bn  = 2;
constexpr int HWn = 4096;     // H*W
constexpr int Nn  = 4096;
constexpr int KQn = 32;
constexpr int KNn = 16;
constexpr int R1n = Bn*HWn*KQn;   // 262144 rows stage 1
constexpr int R2n = Bn*HWn*KNn;   // 131072 rows stage 2
constexpr float INV_R1 = 1.0f/262144.0f;   // exact pow2
constexpr float INV_R2 = 1.0f/131072.0f;   // exact pow2

__device__ __forceinline__ float wred64(float v){
  #pragma unroll
  for (int m = 32; m > 0; m >>= 1) v += __shfl_xor(v, m, 64);
  return v;
}
__device__ __forceinline__ float leakyf(float v){ return v > 0.f ? v : 0.1f*v; }

// BN affine from raw (sum,sumsq) stats: y_norm = y*sc + sh, then leaky outside.
__device__ __forceinline__ void bn_param(const float* st, int c, float inv_n,
                                         const float* g, const float* e,
                                         float& sc, float& sh){
  float mu  = st[c]*inv_n;
  float var = st[128+c]*inv_n - mu*mu;
  float s   = g[c]*rsqrtf(var + 1e-5f);
  sc = s; sh = e[c] - mu*s;
}

// Build the 70-channel stage-1 input row: [wxyz(3), f2_xyz[idx](3), normW*normF2(64)]
__device__ __forceinline__ void build_x70(int row,
    const float* __restrict__ wxyz, const float* __restrict__ f2_xyz,
    const float* __restrict__ normW, const float* __restrict__ normF2,
    const int* __restrict__ idxq, float* x){
  int p = row >> 5;         // (b*HW + i)
  int b = p >> 12;
  int idx = idxq[row];
  const float* wx = wxyz + (size_t)p*3;
  const float* fx = f2_xyz + ((size_t)b*Nn + idx)*3;
  x[0]=wx[0]; x[1]=wx[1]; x[2]=wx[2];
  x[3]=fx[0]; x[4]=fx[1]; x[5]=fx[2];
  const float4* nw = (const float4*)(normW  + (size_t)p*64);
  const float4* nf = (const float4*)(normF2 + ((size_t)b*Nn + idx)*64);
  #pragma unroll
  for (int c=0;c<16;c++){
    float4 a = nw[c], q = nf[c];
    x[6+4*c+0]=a.x*q.x; x[6+4*c+1]=a.y*q.y; x[6+4*c+2]=a.z*q.z; x[6+4*c+3]=a.w*q.w;
  }
}

// Build the 10-channel stage-2 geometry row
__device__ __forceinline__ void build_x10(int row,
    const float* __restrict__ wxyz, const int* __restrict__ idx2, float* x){
  int p = row >> 4, b = p >> 12;
  int idx = idx2[row];
  const float* nw = wxyz + (size_t)p*3;
  const float* gw = wxyz + ((size_t)b*HWn + idx)*3;
  float n0=nw[0],n1=nw[1],n2=nw[2];
  float g0=gw[0],g1=gw[1],g2=gw[2];
  float d0=g0-n0, d1=g1-n1, d2=g2-n2;
  x[0]=n0;x[1]=n1;x[2]=n2; x[3]=g0;x[4]=g1;x[5]=g2;
  x[6]=d0;x[7]=d1;x[8]=d2; x[9]=sqrtf(d0*d0+d1*d1+d2*d2+1e-20f);
}

// ---------------- prep: norms, wxyz, weight transposes ----------------
__global__ __launch_bounds__(256) void k_prep(
    const float* __restrict__ warped_xyz, const float* __restrict__ lidar_z,
    const float* __restrict__ warped_points, const float* __restrict__ f2_points,
    const float* __restrict__ m1w0, const float* __restrict__ piw, const float* __restrict__ pcw,
    float* __restrict__ wxyz, float* __restrict__ normW, float* __restrict__ normF2,
    float* __restrict__ w0t, float* __restrict__ piwT, float* __restrict__ pcwT)
{
  int blk = blockIdx.x, tid = threadIdx.x;
  if (blk < 4096){
    int lane = tid & 63;
    int p = blk*4 + (tid >> 6);            // 0..16383
    const float* src; float* dst;
    if (p < Bn*HWn){ src = warped_points + (size_t)p*64; dst = normW + (size_t)p*64; }
    else { int q = p - Bn*HWn; src = f2_points + (size_t)q*64; dst = normF2 + (size_t)q*64; }
    float x = src[lane];
    float m = wred64(x) * (1.f/64.f);
    float d = x - m;
    float ss = wred64(d*d);
    float s = fmaxf(sqrtf(ss*(1.f/63.f)), 1e-12f);   // unbiased std, clipped
    dst[lane] = d / s;
  } else if (blk < 4192){
    int e = (blk-4096)*256 + tid;          // < 24576
    wxyz[e] = warped_xyz[e] * lidar_z[e/3];
  } else {
    int e = (blk-4192)*256 + tid;
    if (e < 8960){ int i = e >> 7, j = e & 127; w0t[j*70 + i] = m1w0[e]; }
    else if (e < 8960+384){ int f = e-8960; piwT[(f & 63)*6  + (f >> 6)] = piw[f]; }
    else if (e < 8960+384+640){ int f = e-9344; pcwT[(f & 63)*10 + (f >> 6)] = pcw[f]; }
  }
}

// ---------------- exact k-smallest via 8-bit radix select ----------------
template<int K, bool WRITE_VALID>
__global__ __launch_bounds__(256) void k_knn(
    const float* __restrict__ qpts, const float* __restrict__ pts,
    int* __restrict__ oidx, float* __restrict__ ovalid)
{
  __shared__ unsigned int sd[Nn];
  __shared__ unsigned int hist[256];
  __shared__ unsigned int sh_prefix;
  __shared__ int sh_rem, cnt_lt, cnt_eq;
  int b = blockIdx.x >> 12;
  int qi = blockIdx.x & 4095;
  int tid = threadIdx.x;
  const float* qp = qpts + ((size_t)(b*HWn+qi))*3;
  float qx=qp[0], qy=qp[1], qz=qp[2];
  const float* pb = pts + (size_t)b*Nn*3;
  for (int t=tid; t<Nn; t+=256){
    float dx = __fsub_rn(qx, pb[t*3+0]);
    float dy = __fsub_rn(qy, pb[t*3+1]);
    float dz = __fsub_rn(qz, pb[t*3+2]);
    float d2 = __fadd_rn(__fadd_rn(__fmul_rn(dx,dx), __fmul_rn(dy,dy)), __fmul_rn(dz,dz));
    sd[t] = __float_as_uint(d2);           // nonneg floats: uint order == float order
  }
  if (tid == 0){ cnt_lt = 0; cnt_eq = 0; }
  unsigned int prefix = 0; int rem = K;
  for (int shift = 24; shift >= 0; shift -= 8){
    __syncthreads();
    hist[tid] = 0;
    __syncthreads();
    unsigned int maskhi = (shift == 24) ? 0u : (0xFFFFFFFFu << (shift+8));
    for (int t=tid; t<Nn; t+=256){
      unsigned int v = sd[t];
      if ((v & maskhi) == prefix) atomicAdd(&hist[(v >> shift) & 255], 1u);
    }
    __syncthreads();
    if (tid == 0){
      int acc = 0; unsigned int bsel = 255; int cb = 0;
      for (int bkt = 0; bkt < 256; bkt++){
        int h = (int)hist[bkt];
        if (acc + h >= rem){ bsel = (unsigned int)bkt; cb = acc; break; }
        acc += h;
      }
      sh_prefix = prefix | (bsel << shift);
      sh_rem = rem - cb;
    }
    __syncthreads();
    prefix = sh_prefix; rem = sh_rem;
  }
  unsigned int kth = prefix;               // exact k-th smallest key
  int nless = K - rem;                     // # strictly smaller
  size_t obase = ((size_t)(b*HWn+qi))*K;
  const unsigned int U100 = __float_as_uint(100.0f);  // DIST*DIST
  for (int t=tid; t<Nn; t+=256){
    unsigned int v = sd[t];
    if (v < kth){
      int s = atomicAdd(&cnt_lt, 1);
      oidx[obase+s] = t;
      if constexpr (WRITE_VALID) ovalid[obase+s] = (v < U100) ? 1.f : 0.f;
    }
  }
  for (int t=tid; t<Nn; t+=256){
    unsigned int v = sd[t];
    if (v == kth){
      int s = atomicAdd(&cnt_eq, 1);
      if (s < rem){
        oidx[obase+nless+s] = t;
        if constexpr (WRITE_VALID) ovalid[obase+nless+s] = (v < U100) ? 1.f : 0.f;
      }
    }
  }
}

// ---------------- stats-only passes: y1 (128ch), pi_enc (64ch), pc_enc (64ch) ----------------
__global__ __launch_bounds__(256) void k_stats(
    const float* __restrict__ wxyz, const float* __restrict__ f2_xyz,
    const float* __restrict__ normW, const float* __restrict__ normF2,
    const int* __restrict__ idxq, const int* __restrict__ idx2,
    const float* __restrict__ w0t, const float* __restrict__ m1b0,
    const float* __restrict__ piw, const float* __restrict__ pib,
    const float* __restrict__ pcw, const float* __restrict__ pcb,
    float* stats)
{
  __shared__ float ssum[128], sssq[128];
  int blk = blockIdx.x, tid = threadIdx.x, lane = tid & 63;
  if (tid < 128){ ssum[tid]=0.f; sssq[tid]=0.f; }
  __syncthreads();
  if (blk < 1024){
    int row = blk*256 + tid;
    float x[70];
    build_x70(row, wxyz, f2_xyz, normW, normF2, idxq, x);
    for (int j=0;j<128;j++){
      const float* wr = w0t + j*70;
      float t = m1b0[j];
      #pragma unroll
      for (int i=0;i<70;i++) t += x[i]*wr[i];
      float s1 = wred64(t), s2 = wred64(t*t);
      if (lane==0){ atomicAdd(&ssum[j], s1); atomicAdd(&sssq[j], s2); }
    }
    __syncthreads();
    if (tid < 128){ atomicAdd(&stats[tid], ssum[tid]); atomicAdd(&stats[128+tid], sssq[tid]); }
  } else if (blk < 2048){
    int row = (blk-1024)*256 + tid;
    int p = row >> 5, b = p >> 12;
    int idx = idxq[row];
    const float* wx = wxyz + (size_t)p*3;
    const float* fx = f2_xyz + ((size_t)b*Nn + idx)*3;
    float x[6] = {wx[0],wx[1],wx[2],fx[0],fx[1],fx[2]};
    float acc[64];
    #pragma unroll
    for (int d=0;d<64;d++) acc[d] = pib[d];
    #pragma unroll
    for (int i=0;i<6;i++){
      const float* wr = piw + i*64; float xi = x[i];
      #pragma unroll
      for (int d=0;d<64;d++) acc[d] += xi*wr[d];
    }
    #pragma unroll
    for (int d=0;d<64;d++){
      float s1 = wred64(acc[d]), s2 = wred64(acc[d]*acc[d]);
      if (lane==0){ atomicAdd(&ssum[d], s1); atomicAdd(&sssq[d], s2); }
    }
    __syncthreads();
    if (tid < 64){ atomicAdd(&stats[2*256+tid], ssum[tid]); atomicAdd(&stats[2*256+128+tid], sssq[tid]); }
  } else {
    int row = (blk-2048)*256 + tid;
    float x[10];
    build_x10(row, wxyz, idx2, x);
    float acc[64];
    #pragma unroll
    for (int d=0;d<64;d++) acc[d] = pcb[d];
    #pragma unroll
    for (int i=0;i<10;i++){
      const float* wr = pcw + i*64; float xi = x[i];
      #pragma unroll
      for (int d=0;d<64;d++) acc[d] += xi*wr[d];
    }
    #pragma unroll
    for (int d=0;d<64;d++){
      float s1 = wred64(acc[d]), s2 = wred64(acc[d]*acc[d]);
      if (lane==0){ atomicAdd(&ssum[d], s1); atomicAdd(&sssq[d], s2); }
    }
    __syncthreads();
    if (tid < 64){ atomicAdd(&stats[5*256+tid], ssum[tid]); atomicAdd(&stats[5*256+128+tid], sssq[tid]); }
  }
}

// ---------------- fused m1: recompute y1, BN+leaky, x m1w1 -> y2 (A) + stats ----------------
__global__ __launch_bounds__(256) void k_conv_m1(
    const float* __restrict__ wxyz, const float* __restrict__ f2_xyz,
    const float* __restrict__ normW, const float* __restrict__ normF2,
    const int* __restrict__ idxq,
    const float* __restrict__ w0t, const float* __restrict__ m1b0,
    const float* __restrict__ m1g0, const float* __restrict__ m1e0,
    const float* __restrict__ m1w1, const float* __restrict__ m1b1,
    float* stats, float* __restrict__ A)
{
  __shared__ float sc1[128], sh1[128], ssum[64], sssq[64];
  int tid = threadIdx.x, lane = tid & 63;
  if (tid < 128){
    float s,h; bn_param(stats, tid, INV_R1, m1g0, m1e0, s, h);
    sc1[tid]=s; sh1[tid]=h;
  }
  if (tid < 64){ ssum[tid]=0.f; sssq[tid]=0.f; }
  __syncthreads();
  int row = blockIdx.x*256 + tid;
  float x[70];
  build_x70(row, wxyz, f2_xyz, normW, normF2, idxq, x);
  float acc[64];
  #pragma unroll
  for (int d=0;d<64;d++) acc[d] = m1b1[d];
  for (int j=0;j<128;j++){
    const float* wr = w0t + j*70;
    float t = m1b0[j];
    #pragma unroll
    for (int i=0;i<70;i++) t += x[i]*wr[i];
    t = leakyf(t*sc1[j] + sh1[j]);
    const float* w1r = m1w1 + j*64;
    #pragma unroll
    for (int d=0;d<64;d++) acc[d] += t*w1r[d];
  }
  float4* Ar = (float4*)(A + (size_t)row*64);
  #pragma unroll
  for (int d=0;d<16;d++) Ar[d] = make_float4(acc[4*d],acc[4*d+1],acc[4*d+2],acc[4*d+3]);
  #pragma unroll
  for (int d=0;d<64;d++){
    float s1 = wred64(acc[d]), s2 = wred64(acc[d]*acc[d]);
    if (lane==0){ atomicAdd(&ssum[d], s1); atomicAdd(&sssq[d], s2); }
  }
  __syncthreads();
  if (tid < 64){ atomicAdd(&stats[1*256+tid], ssum[tid]); atomicAdd(&stats[1*256+128+tid], sssq[tid]); }
}

// ---------------- m2a: [pi_enc | feat] x m2w0 -> y3 (B) + stats ----------------
__global__ __launch_bounds__(256) void k_conv_m2a(
    const float* __restrict__ wxyz, const float* __restrict__ f2_xyz,
    const int* __restrict__ idxq,
    const float* __restrict__ piwT, const float* __restrict__ pib,
    const float* __restrict__ pig, const float* __restrict__ pie,
    const float* __restrict__ m1g1, const float* __restrict__ m1e1,
    const float* __restrict__ m2w0, const float* __restrict__ m2b0,
    float* stats, const float* __restrict__ A, float* __restrict__ Bb)
{
  __shared__ float scp[64], shp[64], sc2[64], sh2[64], ssum[64], sssq[64];
  int tid = threadIdx.x, lane = tid & 63;
  if (tid < 64){
    float s,h;
    bn_param(stats+2*256, tid, INV_R1, pig,  pie,  s, h); scp[tid]=s; shp[tid]=h;
    bn_param(stats+1*256, tid, INV_R1, m1g1, m1e1, s, h); sc2[tid]=s; sh2[tid]=h;
    ssum[tid]=0.f; sssq[tid]=0.f;
  }
  __syncthreads();
  int row = blockIdx.x*256 + tid;
  int p = row >> 5, b = p >> 12;
  int idx = idxq[row];
  const float* wx = wxyz + (size_t)p*3;
  const float* fx = f2_xyz + ((size_t)b*Nn + idx)*3;
  float x0=wx[0],x1=wx[1],x2=wx[2],x3=fx[0],x4=fx[1],x5=fx[2];
  float acc[64];
  #pragma unroll
  for (int d=0;d<64;d++) acc[d] = m2b0[d];
  for (int j=0;j<64;j++){
    const float* pw = piwT + j*6;
    float t = pib[j] + x0*pw[0]+x1*pw[1]+x2*pw[2]+x3*pw[3]+x4*pw[4]+x5*pw[5];
    t = leakyf(t*scp[j] + shp[j]);
    const float* wr = m2w0 + j*64;
    #pragma unroll
    for (int d=0;d<64;d++) acc[d] += t*wr[d];
  }
  const float4* Ar = (const float4*)(A + (size_t)row*64);
  for (int jg=0;jg<16;jg++){
    float4 q = Ar[jg];
    float t0 = leakyf(q.x*sc2[jg*4+0]+sh2[jg*4+0]);
    float t1 = leakyf(q.y*sc2[jg*4+1]+sh2[jg*4+1]);
    float t2 = leakyf(q.z*sc2[jg*4+2]+sh2[jg*4+2]);
    float t3 = leakyf(q.w*sc2[jg*4+3]+sh2[jg*4+3]);
    const float* w0r = m2w0 + (64+jg*4+0)*64;
    const float* w1r = m2w0 + (64+jg*4+1)*64;
    const float* w2r = m2w0 + (64+jg*4+2)*64;
    const float* w3r = m2w0 + (64+jg*4+3)*64;
    #pragma unroll
    for (int d=0;d<64;d++) acc[d] += t0*w0r[d]+t1*w1r[d]+t2*w2r[d]+t3*w3r[d];
  }
  float4* Br = (float4*)(Bb + (size_t)row*64);
  #pragma unroll
  for (int d=0;d<16;d++) Br[d] = make_float4(acc[4*d],acc[4*d+1],acc[4*d+2],acc[4*d+3]);
  #pragma unroll
  for (int d=0;d<64;d++){
    float s1 = wred64(acc[d]), s2 = wred64(acc[d]*acc[d]);
    if (lane==0){ atomicAdd(&ssum[d], s1); atomicAdd(&sssq[d], s2); }
  }
  __syncthreads();
  if (tid < 64){ atomicAdd(&stats[3*256+tid], ssum[tid]); atomicAdd(&stats[3*256+128+tid], sssq[tid]); }
}

// ---------------- generic in-place 64->64 conv (m2_1 and m3_1) ----------------
__global__ __launch_bounds__(256) void k_conv64(
    float* __restrict__ buf, const float* statsIn, float inv_n,
    const float* __restrict__ g, const float* __restrict__ e,
    const float* __restrict__ w, const float* __restrict__ bias,
    float* statsOut)
{
  __shared__ float sc[64], sh[64], ssum[64], sssq[64];
  int tid = threadIdx.x, lane = tid & 63;
  if (tid < 64){
    float s,h; bn_param(statsIn, tid, inv_n, g, e, s, h);
    sc[tid]=s; sh[tid]=h; ssum[tid]=0.f; sssq[tid]=0.f;
  }
  __syncthreads();
  size_t row = (size_t)blockIdx.x*256 + tid;
  float* r = buf + row*64;
  float acc[64];
  #pragma unroll
  for (int d=0;d<64;d++) acc[d] = bias[d];
  const float4* r4 = (const float4*)r;
  for (int jg=0;jg<16;jg++){
    float4 q = r4[jg];
    float t0 = leakyf(q.x*sc[jg*4+0]+sh[jg*4+0]);
    float t1 = leakyf(q.y*sc[jg*4+1]+sh[jg*4+1]);
    float t2 = leakyf(q.z*sc[jg*4+2]+sh[jg*4+2]);
    float t3 = leakyf(q.w*sc[jg*4+3]+sh[jg*4+3]);
    const float* w0r = w + (jg*4+0)*64;
    const float* w1r = w + (jg*4+1)*64;
    const float* w2r = w + (jg*4+2)*64;
    const float* w3r = w + (jg*4+3)*64;
    #pragma unroll
    for (int d=0;d<64;d++) acc[d] += t0*w0r[d]+t1*w1r[d]+t2*w2r[d]+t3*w3r[d];
  }
  float4* rw = (float4*)r;
  #pragma unroll
  for (int d=0;d<16;d++) rw[d] = make_float4(acc[4*d],acc[4*d+1],acc[4*d+2],acc[4*d+3]);
  #pragma unroll
  for (int d=0;d<64;d++){
    float s1 = wred64(acc[d]), s2 = wred64(acc[d]*acc[d]);
    if (lane==0){ atomicAdd(&ssum[d], s1); atomicAdd(&sssq[d], s2); }
  }
  __syncthreads();
  if (tid < 64){ atomicAdd(&statsOut[tid], ssum[tid]); atomicAdd(&statsOut[128+tid], sssq[tid]); }
}

// ---------------- stage-1 softmax over KQ, weighted sum of feat -> pi_feat1 ----------------
__global__ __launch_bounds__(256) void k_softmax1(
    const float* __restrict__ A, const float* __restrict__ Bb,
    const float* stats,
    const float* __restrict__ m1g1, const float* __restrict__ m1e1,
    const float* __restrict__ m2g1, const float* __restrict__ m2e1,
    float* __restrict__ pif1)
{
  int tid = threadIdx.x, lane = tid & 63;
  int p = blockIdx.x*4 + (tid >> 6);
  int d = lane;
  float sc2,sh2,sc4,sh4;
  bn_param(stats+1*256, d, INV_R1, m1g1, m1e1, sc2, sh2);
  bn_param(stats+4*256, d, INV_R1, m2g1, m2e1, sc4, sh4);
  size_t rb = (size_t)p*KQn;
  float v[32]; float mx = -1e30f;
  #pragma unroll
  for (int k=0;k<32;k++){
    float t = leakyf(Bb[(rb+k)*64 + d]*sc4 + sh4);
    v[k] = t; mx = fmaxf(mx, t);
  }
  float se = 0.f;
  #pragma unroll
  for (int k=0;k<32;k++){ float ev = __expf(v[k]-mx); v[k]=ev; se += ev; }
  float inv = 1.f/se, acc = 0.f;
  #pragma unroll
  for (int k=0;k<32;k++){
    float f = leakyf(A[(rb+k)*64 + d]*sc2 + sh2);
    acc += v[k]*f;
  }
  pif1[(size_t)p*64 + d] = acc*inv;
}

// ---------------- m3a: [pc_enc | warped_points | gathered pi_feat1] x m3w0 -> y5 ----------------
__global__ __launch_bounds__(256) void k_conv_m3a(
    const float* __restrict__ wxyz, const float* __restrict__ warped_points,
    const float* __restrict__ pif1, const int* __restrict__ idx2,
    const float* __restrict__ pcwT, const float* __restrict__ pcb,
    const float* __restrict__ pcg, const float* __restrict__ pce,
    const float* __restrict__ m3w0, const float* __restrict__ m3b0,
    float* stats, float* __restrict__ Y)
{
  __shared__ float scp[64], shp[64], ssum[64], sssq[64];
  int tid = threadIdx.x, lane = tid & 63;
  if (tid < 64){
    float s,h; bn_param(stats+5*256, tid, INV_R2, pcg, pce, s, h);
    scp[tid]=s; shp[tid]=h; ssum[tid]=0.f; sssq[tid]=0.f;
  }
  __syncthreads();
  int row = blockIdx.x*256 + tid;
  int p = row >> 4, b = p >> 12;
  int idx = idx2[row];
  float x[10];
  build_x10(row, wxyz, idx2, x);
  float acc[64];
  #pragma unroll
  for (int d=0;d<64;d++) acc[d] = m3b0[d];
  for (int j=0;j<64;j++){
    const float* pw = pcwT + j*10;
    float t = pcb[j];
    #pragma unroll
    for (int i=0;i<10;i++) t += x[i]*pw[i];
    t = leakyf(t*scp[j] + shp[j]);
    const float* wr = m3w0 + j*64;
    #pragma unroll
    for (int d=0;d<64;d++) acc[d] += t*wr[d];
  }
  const float4* wpr = (const float4*)(warped_points + (size_t)p*64);
  for (int jg=0;jg<16;jg++){
    float4 q = wpr[jg];
    const float* w0r = m3w0 + (64+jg*4+0)*64;
    const float* w1r = m3w0 + (64+jg*4+1)*64;
    const float* w2r = m3w0 + (64+jg*4+2)*64;
    const float* w3r = m3w0 + (64+jg*4+3)*64;
    #pragma unroll
    for (int d=0;d<64;d++) acc[d] += q.x*w0r[d]+q.y*w1r[d]+q.z*w2r[d]+q.w*w3r[d];
  }
  const float4* pgr = (const float4*)(pif1 + ((size_t)b*HWn + idx)*64);
  for (int jg=0;jg<16;jg++){
    float4 q = pgr[jg];
    const float* w0r = m3w0 + (128+jg*4+0)*64;
    const float* w1r = m3w0 + (128+jg*4+1)*64;
    const float* w2r = m3w0 + (128+jg*4+2)*64;
    const float* w3r = m3w0 + (128+jg*4+3)*64;
    #pragma unroll
    for (int d=0;d<64;d++) acc[d] += q.x*w0r[d]+q.y*w1r[d]+q.z*w2r[d]+q.w*w3r[d];
  }
  float4* Yr = (float4*)(Y + (size_t)row*64);
  #pragma unroll
  for (int d=0;d<16;d++) Yr[d] = make_float4(acc[4*d],acc[4*d+1],acc[4*d+2],acc[4*d+3]);
  #pragma unroll
  for (int d=0;d<64;d++){
    float s1 = wred64(acc[d]), s2 = wred64(acc[d]*acc[d]);
    if (lane==0){ atomicAdd(&ssum[d], s1); atomicAdd(&sssq[d], s2); }
  }
  __syncthreads();
  if (tid < 64){ atomicAdd(&stats[6*256+tid], ssum[tid]); atomicAdd(&stats[6*256+128+tid], sssq[tid]); }
}

// ---------------- stage-2 masked softmax over KN, weighted sum of gathered pi_feat1 ----------------
__global__ __launch_bounds__(256) void k_softmax2(
    const float* __restrict__ Y, const float* __restrict__ pif1,
    const int* __restrict__ idx2, const float* __restrict__ validf,
    const float* stats,
    const float* __restrict__ m3g1, const float* __restrict__ m3e1,
    float* __restrict__ out)
{
  int tid = threadIdx.x, lane = tid & 63;
  int p = blockIdx.x*4 + (tid >> 6);
  int b = p >> 12;
  int d = lane;
  float sc,sh; bn_param(stats+7*256, d, INV_R2, m3g1, m3e1, sc, sh);
  size_t rb = (size_t)p*KNn;
  float v[16]; float mx = -1e30f;
  #pragma unroll
  for (int k=0;k<16;k++){
    float t = leakyf(Y[(rb+k)*64 + d]*sc + sh);
    t = (validf[rb+k] > 0.5f) ? t : -1e10f;
    v[k] = t; mx = fmaxf(mx, t);
  }
  float se = 0.f;
  #pragma unroll
  for (int k=0;k<16;k++){ float ev = __expf(v[k]-mx); v[k]=ev; se += ev; }
  float inv = 1.f/se, acc = 0.f;
  #pragma unroll
  for (int k=0;k<16;k++){
    int idx = idx2[rb+k];
    acc += v[k]*pif1[((size_t)b*HWn + idx)*64 + d];
  }
  out[(size_t)p*64 + d] = acc*inv;
}

// ---------------- launcher ----------------
extern "C" void kernel_launch(void* const* d_in, const int* in_sizes, int n_in,
                              void* d_out, int out_size, void* d_ws, size_t ws_size,
                              hipStream_t stream)
{
  (void)in_sizes; (void)n_in; (void)out_size; (void)ws_size;
  const float* xyz_proj      = (const float*)d_in[0];
  const float* warped_xyz    = (const float*)d_in[1];
  const float* warped_points = (const float*)d_in[2];
  const float* f2_xyz        = (const float*)d_in[4];
  const float* f2_points     = (const float*)d_in[5];
  const float* lidar_z       = (const float*)d_in[6];
  const float* m1w0=(const float*)d_in[7],  *m1b0=(const float*)d_in[8],  *m1g0=(const float*)d_in[9],  *m1e0=(const float*)d_in[10];
  const float* m1w1=(const float*)d_in[11], *m1b1=(const float*)d_in[12], *m1g1=(const float*)d_in[13], *m1e1=(const float*)d_in[14];
  const float* piw =(const float*)d_in[15], *pib =(const float*)d_in[16], *pig =(const float*)d_in[17], *pie =(const float*)d_in[18];
  const float* m2w0=(const float*)d_in[19], *m2b0=(const float*)d_in[20], *m2g0=(const float*)d_in[21], *m2e0=(const float*)d_in[22];
  const float* m2w1=(const float*)d_in[23], *m2b1=(const float*)d_in[24], *m2g1=(const float*)d_in[25], *m2e1=(const float*)d_in[26];
  const float* pcw =(const float*)d_in[27], *pcb =(const float*)d_in[28], *pcg =(const float*)d_in[29], *pce =(const float*)d_in[30];
  const float* m3w0=(const float*)d_in[31], *m3b0=(const float*)d_in[32], *m3g0=(const float*)d_in[33], *m3e0=(const float*)d_in[34];
  const float* m3w1=(const float*)d_in[35], *m3b1=(const float*)d_in[36], *m3g1=(const float*)d_in[37], *m3e1=(const float*)d_in[38];
  float* out = (float*)d_out;

  float* ws     = (float*)d_ws;
  float* wxyz   = ws;                        // 24576
  float* normW  = wxyz   + 24576;            // 524288
  float* normF2 = normW  + 524288;           // 524288
  float* pif1   = normF2 + 524288;           // 524288
  float* w0t    = pif1   + 524288;           // 8960
  float* piwT   = w0t    + 8960;             // 384
  float* pcwT   = piwT   + 384;              // 640
  float* stats  = pcwT   + 640;              // 2048 (8 BNs x [sum128|ssq128])
  int*   idxq   = (int*)(stats + 2048);      // 262144
  int*   idx2   = idxq   + 262144;           // 131072
  float* validf = (float*)(idx2 + 131072);   // 131072
  float* Abuf   = validf + 131072;           // 16777216 (y2 / y5,y6)
  float* Bbuf   = Abuf   + 16777216;         // 16777216 (y3,y4)
  // total ~142.8 MB

  hipMemsetAsync(stats, 0, 2048*sizeof(float), stream);
  k_prep<<<4231,256,0,stream>>>(warped_xyz, lidar_z, warped_points, f2_points,
                                m1w0, piw, pcw, wxyz, normW, normF2, w0t, piwT, pcwT);
  k_knn<32,false><<<8192,256,0,stream>>>(warped_xyz, f2_xyz, idxq, nullptr);
  k_knn<16,true ><<<8192,256,0,stream>>>(xyz_proj, xyz_proj, idx2, validf);
  k_stats<<<2560,256,0,stream>>>(wxyz, f2_xyz, normW, normF2, idxq, idx2,
                                 w0t, m1b0, piw, pib, pcw, pcb, stats);
  k_conv_m1<<<1024,256,0,stream>>>(wxyz, f2_xyz, normW, normF2, idxq,
                                   w0t, m1b0, m1g0, m1e0, m1w1, m1b1, stats, Abuf);
  k_conv_m2a<<<1024,256,0,stream>>>(wxyz, f2_xyz, idxq, piwT, pib, pig, pie,
                                    m1g1, m1e1, m2w0, m2b0, stats, Abuf, Bbuf);
  k_conv64<<<1024,256,0,stream>>>(Bbuf, stats+3*256, INV_R1, m2g0, m2e0, m2w1, m2b1, stats+4*256);
  k_softmax1<<<2048,256,0,stream>>>(Abuf, Bbuf, stats, m1g1, m1e1, m2g1, m2e1, pif1);
  k_conv_m3a<<<512,256,0,stream>>>(wxyz, warped_points, pif1, idx2, pcwT, pcb, pcg, pce,
                                   m3w0, m3b0, stats, Abuf);
  k_conv64<<<512,256,0,stream>>>(Abuf, stats+6*256, INV_R2, m3g0, m3e0, m3w1, m3b1, stats+7*256);
  k_softmax2<<<2048,256,0,stream>>>(Abuf, pif1, idx2, validf, stats, m3g1, m3e1, out);
}

// Round 2
// 1505.649 us; speedup vs baseline: 1.0303x; 1.0303x over previous
//
#include <hip/hip_runtime.h>
#include <math.h>

// ---------------- problem constants ----------------
constexpr int Bn  = 2;
constexpr int HWn = 4096;     // H*W
constexpr int Nn  = 4096;
constexpr int KQn = 32;
constexpr int KNn = 16;
constexpr float INV_R1 = 1.0f/262144.0f;   // exact pow2
constexpr float INV_R2 = 1.0f/131072.0f;   // exact pow2

typedef _Float16 f16x8 __attribute__((ext_vector_type(8)));
typedef float    f32x4 __attribute__((ext_vector_type(4)));

__device__ __forceinline__ float wred64(float v){
  #pragma unroll
  for (int m = 32; m > 0; m >>= 1) v += __shfl_xor(v, m, 64);
  return v;
}
__device__ __forceinline__ float leakyf(float v){ return v > 0.f ? v : 0.1f*v; }

// BN affine from raw (sum,sumsq) stats: y_norm = y*sc + sh, then leaky outside.
__device__ __forceinline__ void bn_param(const float* st, int c, float inv_n,
                                         const float* g, const float* e,
                                         float& sc, float& sh){
  float mu  = st[c]*inv_n;
  float var = st[128+c]*inv_n - mu*mu;
  float s   = g[c]*rsqrtf(var + 1e-5f);
  sc = s; sh = e[c] - mu*s;
}

// Build the 70-channel stage-1 input row: [wxyz(3), f2_xyz[idx](3), normW*normF2(64)]
__device__ __forceinline__ void build_x70(int row,
    const float* __restrict__ wxyz, const float* __restrict__ f2_xyz,
    const float* __restrict__ normW, const float* __restrict__ normF2,
    const int* __restrict__ idxq, float* x){
  int p = row >> 5;         // (b*HW + i)
  int b = p >> 12;
  int idx = idxq[row];
  const float* wx = wxyz + (size_t)p*3;
  const float* fx = f2_xyz + ((size_t)b*Nn + idx)*3;
  x[0]=wx[0]; x[1]=wx[1]; x[2]=wx[2];
  x[3]=fx[0]; x[4]=fx[1]; x[5]=fx[2];
  const float4* nw = (const float4*)(normW  + (size_t)p*64);
  const float4* nf = (const float4*)(normF2 + ((size_t)b*Nn + idx)*64);
  #pragma unroll
  for (int c=0;c<16;c++){
    float4 a = nw[c], q = nf[c];
    x[6+4*c+0]=a.x*q.x; x[6+4*c+1]=a.y*q.y; x[6+4*c+2]=a.z*q.z; x[6+4*c+3]=a.w*q.w;
  }
}

// Build the 10-channel stage-2 geometry row
__device__ __forceinline__ void build_x10(int row,
    const float* __restrict__ wxyz, const int* __restrict__ idx2, float* x){
  int p = row >> 4, b = p >> 12;
  int idx = idx2[row];
  const float* nw = wxyz + (size_t)p*3;
  const float* gw = wxyz + ((size_t)b*HWn + idx)*3;
  float n0=nw[0],n1=nw[1],n2=nw[2];
  float g0=gw[0],g1=gw[1],g2=gw[2];
  float d0=g0-n0, d1=g1-n1, d2=g2-n2;
  x[0]=n0;x[1]=n1;x[2]=n2; x[3]=g0;x[4]=g1;x[5]=g2;
  x[6]=d0;x[7]=d1;x[8]=d2; x[9]=sqrtf(d0*d0+d1*d1+d2*d2+1e-20f);
}

// ---------------- prep: norms, wxyz, weight transposes + f16 weights ----------------
__global__ __launch_bounds__(256) void k_prep(
    const float* __restrict__ warped_xyz, const float* __restrict__ lidar_z,
    const float* __restrict__ warped_points, const float* __restrict__ f2_points,
    const float* __restrict__ m1w0, const float* __restrict__ piw, const float* __restrict__ pcw,
    const float* __restrict__ m1w1,
    float* __restrict__ wxyz, float* __restrict__ normW, float* __restrict__ normF2,
    float* __restrict__ w0t, float* __restrict__ piwT, float* __restrict__ pcwT,
    _Float16* __restrict__ w1h, _Float16* __restrict__ w2h)
{
  int blk = blockIdx.x, tid = threadIdx.x;
  if (blk < 4096){
    int lane = tid & 63;
    int p = blk*4 + (tid >> 6);            // 0..16383
    const float* src; float* dst;
    if (p < Bn*HWn){ src = warped_points + (size_t)p*64; dst = normW + (size_t)p*64; }
    else { int q = p - Bn*HWn; src = f2_points + (size_t)q*64; dst = normF2 + (size_t)q*64; }
    float x = src[lane];
    float m = wred64(x) * (1.f/64.f);
    float d = x - m;
    float ss = wred64(d*d);
    float s = fmaxf(sqrtf(ss*(1.f/63.f)), 1e-12f);   // unbiased std, clipped
    dst[lane] = d / s;
  } else if (blk < 4192){
    int e = (blk-4096)*256 + tid;          // < 24576
    wxyz[e] = warped_xyz[e] * lidar_z[e/3];
  } else if (blk < 4231){
    int e = (blk-4192)*256 + tid;
    if (e < 8960){ int i = e >> 7, j = e & 127; w0t[j*70 + i] = m1w0[e]; }
    else if (e < 8960+384){ int f = e-8960; piwT[(f & 63)*6  + (f >> 6)] = piw[f]; }
    else if (e < 8960+384+640){ int f = e-9344; pcwT[(f & 63)*10 + (f >> 6)] = pcw[f]; }
  } else {
    int e = (blk-4231)*256 + tid;          // < 20480
    if (e < 12288){                        // w1h[j][k] : [128 out][96 in-pad]
      int j = e/96, k = e - j*96;
      w1h[e] = (k < 70) ? (_Float16)m1w0[k*128 + j] : (_Float16)0.f;
    } else {                               // w2h[d][c] : [64 out][128 in]
      int f = e - 12288;
      int d = f >> 7, c = f & 127;
      w2h[f] = (_Float16)m1w1[c*64 + d];
    }
  }
}

// ---------------- exact k-smallest via 8-bit radix select ----------------
template<int K, bool WRITE_VALID>
__global__ __launch_bounds__(256) void k_knn(
    const float* __restrict__ qpts, const float* __restrict__ pts,
    int* __restrict__ oidx, float* __restrict__ ovalid)
{
  __shared__ unsigned int sd[Nn];
  __shared__ unsigned int hist[256];
  __shared__ unsigned int sh_prefix;
  __shared__ int sh_rem, cnt_lt, cnt_eq;
  int b = blockIdx.x >> 12;
  int qi = blockIdx.x & 4095;
  int tid = threadIdx.x;
  const float* qp = qpts + ((size_t)(b*HWn+qi))*3;
  float qx=qp[0], qy=qp[1], qz=qp[2];
  const float* pb = pts + (size_t)b*Nn*3;
  for (int t=tid; t<Nn; t+=256){
    float dx = __fsub_rn(qx, pb[t*3+0]);
    float dy = __fsub_rn(qy, pb[t*3+1]);
    float dz = __fsub_rn(qz, pb[t*3+2]);
    float d2 = __fadd_rn(__fadd_rn(__fmul_rn(dx,dx), __fmul_rn(dy,dy)), __fmul_rn(dz,dz));
    sd[t] = __float_as_uint(d2);           // nonneg floats: uint order == float order
  }
  if (tid == 0){ cnt_lt = 0; cnt_eq = 0; }
  unsigned int prefix = 0; int rem = K;
  for (int shift = 24; shift >= 0; shift -= 8){
    __syncthreads();
    hist[tid] = 0;
    __syncthreads();
    unsigned int maskhi = (shift == 24) ? 0u : (0xFFFFFFFFu << (shift+8));
    for (int t=tid; t<Nn; t+=256){
      unsigned int v = sd[t];
      if ((v & maskhi) == prefix) atomicAdd(&hist[(v >> shift) & 255], 1u);
    }
    __syncthreads();
    if (tid == 0){
      int acc = 0; unsigned int bsel = 255; int cb = 0;
      for (int bkt = 0; bkt < 256; bkt++){
        int h = (int)hist[bkt];
        if (acc + h >= rem){ bsel = (unsigned int)bkt; cb = acc; break; }
        acc += h;
      }
      sh_prefix = prefix | (bsel << shift);
      sh_rem = rem - cb;
    }
    __syncthreads();
    prefix = sh_prefix; rem = sh_rem;
  }
  unsigned int kth = prefix;               // exact k-th smallest key
  int nless = K - rem;                     // # strictly smaller
  size_t obase = ((size_t)(b*HWn+qi))*K;
  const unsigned int U100 = __float_as_uint(100.0f);  // DIST*DIST
  for (int t=tid; t<Nn; t+=256){
    unsigned int v = sd[t];
    if (v < kth){
      int s = atomicAdd(&cnt_lt, 1);
      oidx[obase+s] = t;
      if constexpr (WRITE_VALID) ovalid[obase+s] = (v < U100) ? 1.f : 0.f;
    }
  }
  for (int t=tid; t<Nn; t+=256){
    unsigned int v = sd[t];
    if (v == kth){
      int s = atomicAdd(&cnt_eq, 1);
      if (s < rem){
        oidx[obase+nless+s] = t;
        if constexpr (WRITE_VALID) ovalid[obase+nless+s] = (v < U100) ? 1.f : 0.f;
      }
    }
  }
}

// ---------------- build f16 X1 rows: [wxyz(3) f2xyz(3) prod(64) pad->96] ----------------
__global__ __launch_bounds__(256) void k_buildX1(
    const float* __restrict__ wxyz, const float* __restrict__ f2_xyz,
    const float* __restrict__ normW, const float* __restrict__ normF2,
    const int* __restrict__ idxq, _Float16* __restrict__ X1)
{
  int row = blockIdx.x*256 + threadIdx.x;
  float x[70];
  build_x70(row, wxyz, f2_xyz, normW, normF2, idxq, x);
  unsigned int* d32 = (unsigned int*)(X1 + (size_t)row*96);
  union { unsigned int u; _Float16 h[2]; } pk;
  #pragma unroll
  for (int c=0;c<35;c++){
    pk.h[0] = (_Float16)x[2*c]; pk.h[1] = (_Float16)x[2*c+1];
    d32[c] = pk.u;
  }
  #pragma unroll
  for (int c=35;c<48;c++) d32[c] = 0u;
}

// ---------------- MFMA y1 stats (bias dropped: BN is shift-invariant) ----------------
__global__ __launch_bounds__(256) void k_mfma_stats1(
    const _Float16* __restrict__ X1, const _Float16* __restrict__ w1h,
    float* stats)
{
  __shared__ _Float16 sw[128*104];           // W1 [128][96] staged with stride 104
  __shared__ float ssum[128], sssq[128];
  int tid = threadIdx.x;
  const unsigned int* wsrc = (const unsigned int*)w1h;
  for (int d = tid; d < 6144; d += 256){
    int row = d/48, col = d - row*48;
    ((unsigned int*)sw)[row*52 + col] = wsrc[d];
  }
  if (tid < 128){ ssum[tid]=0.f; sssq[tid]=0.f; }
  __syncthreads();
  int wave = tid >> 6, lane = tid & 63;
  int quad = lane >> 4, n16 = lane & 15;
  int m0 = blockIdx.x*64 + wave*16;
  const _Float16* xr = X1 + (size_t)(m0 + n16)*96 + quad*8;
  f16x8 a0 = *(const f16x8*)(xr);
  f16x8 a1 = *(const f16x8*)(xr + 32);
  f16x8 a2 = *(const f16x8*)(xr + 64);
  for (int nt = 0; nt < 8; nt++){
    const _Float16* wr = sw + (size_t)(nt*16 + n16)*104 + quad*8;
    f16x8 b0 = *(const f16x8*)(wr);
    f16x8 b1 = *(const f16x8*)(wr + 32);
    f16x8 b2 = *(const f16x8*)(wr + 64);
    f32x4 acc = {0.f,0.f,0.f,0.f};
    acc = __builtin_amdgcn_mfma_f32_16x16x32_f16(a0, b0, acc, 0,0,0);
    acc = __builtin_amdgcn_mfma_f32_16x16x32_f16(a1, b1, acc, 0,0,0);
    acc = __builtin_amdgcn_mfma_f32_16x16x32_f16(a2, b2, acc, 0,0,0);
    float s1 = acc[0]+acc[1]+acc[2]+acc[3];
    float s2 = acc[0]*acc[0]+acc[1]*acc[1]+acc[2]*acc[2]+acc[3]*acc[3];
    s1 += __shfl_xor(s1, 16, 64); s1 += __shfl_xor(s1, 32, 64);
    s2 += __shfl_xor(s2, 16, 64); s2 += __shfl_xor(s2, 32, 64);
    if (quad == 0){ atomicAdd(&ssum[nt*16+n16], s1); atomicAdd(&sssq[nt*16+n16], s2); }
  }
  __syncthreads();
  if (tid < 128){ atomicAdd(&stats[tid], ssum[tid]); atomicAdd(&stats[128+tid], sssq[tid]); }
}

// ---------------- MFMA m1: y1 -> BN/leaky -> t (LDS) -> x W2 -> y2 (f32) + stats ----------------
__global__ __launch_bounds__(256) void k_mfma_m1(
    const _Float16* __restrict__ X1, const _Float16* __restrict__ w1h,
    const _Float16* __restrict__ w2h,
    const float* __restrict__ m1g0, const float* __restrict__ m1e0,
    float* stats, float* __restrict__ A)
{
  __shared__ _Float16 sw[128*104];           // W1, stride 104
  __shared__ _Float16 sw2[64*136];           // W2t [64][128], stride 136
  __shared__ _Float16 st[64*136];            // t rows [64][128], stride 136
  __shared__ float sc1[128], sh1[128], ssum[64], sssq[64];
  int tid = threadIdx.x;
  const unsigned int* wsrc = (const unsigned int*)w1h;
  for (int d = tid; d < 6144; d += 256){
    int row = d/48, col = d - row*48;
    ((unsigned int*)sw)[row*52 + col] = wsrc[d];
  }
  const unsigned int* w2src = (const unsigned int*)w2h;
  for (int d = tid; d < 4096; d += 256){
    int row = d >> 6, col = d & 63;
    ((unsigned int*)sw2)[row*68 + col] = w2src[d];
  }
  if (tid < 128){
    float s,h; bn_param(stats, tid, INV_R1, m1g0, m1e0, s, h);
    sc1[tid]=s; sh1[tid]=h;
  }
  if (tid < 64){ ssum[tid]=0.f; sssq[tid]=0.f; }
  __syncthreads();
  int wave = tid >> 6, lane = tid & 63;
  int quad = lane >> 4, n16 = lane & 15;
  int m0 = blockIdx.x*64 + wave*16;
  const _Float16* xr = X1 + (size_t)(m0 + n16)*96 + quad*8;
  f16x8 a0 = *(const f16x8*)(xr);
  f16x8 a1 = *(const f16x8*)(xr + 32);
  f16x8 a2 = *(const f16x8*)(xr + 64);
  for (int nt = 0; nt < 8; nt++){
    const _Float16* wr = sw + (size_t)(nt*16 + n16)*104 + quad*8;
    f16x8 b0 = *(const f16x8*)(wr);
    f16x8 b1 = *(const f16x8*)(wr + 32);
    f16x8 b2 = *(const f16x8*)(wr + 64);
    f32x4 acc = {0.f,0.f,0.f,0.f};
    acc = __builtin_amdgcn_mfma_f32_16x16x32_f16(a0, b0, acc, 0,0,0);
    acc = __builtin_amdgcn_mfma_f32_16x16x32_f16(a1, b1, acc, 0,0,0);
    acc = __builtin_amdgcn_mfma_f32_16x16x32_f16(a2, b2, acc, 0,0,0);
    int ch = nt*16 + n16;
    float sc = sc1[ch], sh = sh1[ch];
    #pragma unroll
    for (int r=0;r<4;r++){
      float v = leakyf(acc[r]*sc + sh);
      st[(size_t)(wave*16 + quad*4 + r)*136 + ch] = (_Float16)v;
    }
  }
  __syncthreads();
  // second GEMM: t (64x128) x W2t -> y2 (64 ch)
  const _Float16* tr = st + (size_t)(wave*16 + n16)*136 + quad*8;
  f16x8 t0 = *(const f16x8*)(tr);
  f16x8 t1 = *(const f16x8*)(tr + 32);
  f16x8 t2 = *(const f16x8*)(tr + 64);
  f16x8 t3 = *(const f16x8*)(tr + 96);
  for (int nt = 0; nt < 4; nt++){
    const _Float16* wr = sw2 + (size_t)(nt*16 + n16)*136 + quad*8;
    f16x8 b0 = *(const f16x8*)(wr);
    f16x8 b1 = *(const f16x8*)(wr + 32);
    f16x8 b2 = *(const f16x8*)(wr + 64);
    f16x8 b3 = *(const f16x8*)(wr + 96);
    f32x4 acc = {0.f,0.f,0.f,0.f};
    acc = __builtin_amdgcn_mfma_f32_16x16x32_f16(t0, b0, acc, 0,0,0);
    acc = __builtin_amdgcn_mfma_f32_16x16x32_f16(t1, b1, acc, 0,0,0);
    acc = __builtin_amdgcn_mfma_f32_16x16x32_f16(t2, b2, acc, 0,0,0);
    acc = __builtin_amdgcn_mfma_f32_16x16x32_f16(t3, b3, acc, 0,0,0);
    int ch = nt*16 + n16;
    #pragma unroll
    for (int r=0;r<4;r++){
      int rowg = blockIdx.x*64 + wave*16 + quad*4 + r;
      A[(size_t)rowg*64 + ch] = acc[r];
    }
    float s1 = acc[0]+acc[1]+acc[2]+acc[3];
    float s2 = acc[0]*acc[0]+acc[1]*acc[1]+acc[2]*acc[2]+acc[3]*acc[3];
    s1 += __shfl_xor(s1, 16, 64); s1 += __shfl_xor(s1, 32, 64);
    s2 += __shfl_xor(s2, 16, 64); s2 += __shfl_xor(s2, 32, 64);
    if (quad == 0){ atomicAdd(&ssum[ch], s1); atomicAdd(&sssq[ch], s2); }
  }
  __syncthreads();
  if (tid < 64){ atomicAdd(&stats[1*256+tid], ssum[tid]); atomicAdd(&stats[1*256+128+tid], sssq[tid]); }
}

// ---------------- stats-only passes: pi_enc (64ch), pc_enc (64ch) ----------------
__global__ __launch_bounds__(256) void k_stats(
    const float* __restrict__ wxyz, const float* __restrict__ f2_xyz,
    const int* __restrict__ idxq, const int* __restrict__ idx2,
    const float* __restrict__ piw, const float* __restrict__ pib,
    const float* __restrict__ pcw, const float* __restrict__ pcb,
    float* stats)
{
  __shared__ float ssum[64], sssq[64];
  int blk = blockIdx.x, tid = threadIdx.x, lane = tid & 63;
  if (tid < 64){ ssum[tid]=0.f; sssq[tid]=0.f; }
  __syncthreads();
  if (blk < 1024){
    int row = blk*256 + tid;
    int p = row >> 5, b = p >> 12;
    int idx = idxq[row];
    const float* wx = wxyz + (size_t)p*3;
    const float* fx = f2_xyz + ((size_t)b*Nn + idx)*3;
    float x[6] = {wx[0],wx[1],wx[2],fx[0],fx[1],fx[2]};
    float acc[64];
    #pragma unroll
    for (int d=0;d<64;d++) acc[d] = pib[d];
    #pragma unroll
    for (int i=0;i<6;i++){
      const float* wr = piw + i*64; float xi = x[i];
      #pragma unroll
      for (int d=0;d<64;d++) acc[d] += xi*wr[d];
    }
    #pragma unroll
    for (int d=0;d<64;d++){
      float s1 = wred64(acc[d]), s2 = wred64(acc[d]*acc[d]);
      if (lane==0){ atomicAdd(&ssum[d], s1); atomicAdd(&sssq[d], s2); }
    }
    __syncthreads();
    if (tid < 64){ atomicAdd(&stats[2*256+tid], ssum[tid]); atomicAdd(&stats[2*256+128+tid], sssq[tid]); }
  } else {
    int row = (blk-1024)*256 + tid;
    float x[10];
    build_x10(row, wxyz, idx2, x);
    float acc[64];
    #pragma unroll
    for (int d=0;d<64;d++) acc[d] = pcb[d];
    #pragma unroll
    for (int i=0;i<10;i++){
      const float* wr = pcw + i*64; float xi = x[i];
      #pragma unroll
      for (int d=0;d<64;d++) acc[d] += xi*wr[d];
    }
    #pragma unroll
    for (int d=0;d<64;d++){
      float s1 = wred64(acc[d]), s2 = wred64(acc[d]*acc[d]);
      if (lane==0){ atomicAdd(&ssum[d], s1); atomicAdd(&sssq[d], s2); }
    }
    __syncthreads();
    if (tid < 64){ atomicAdd(&stats[5*256+tid], ssum[tid]); atomicAdd(&stats[5*256+128+tid], sssq[tid]); }
  }
}

// ---------------- m2a: [pi_enc | feat] x m2w0 -> y3 (B) + stats ----------------
__global__ __launch_bounds__(256) void k_conv_m2a(
    const float* __restrict__ wxyz, const float* __restrict__ f2_xyz,
    const int* __restrict__ idxq,
    const float* __restrict__ piwT, const float* __restrict__ pib,
    const float* __restrict__ pig, const float* __restrict__ pie,
    const float* __restrict__ m1g1, const float* __restrict__ m1e1,
    const float* __restrict__ m2w0, const float* __restrict__ m2b0,
    float* stats, const float* __restrict__ A, float* __restrict__ Bb)
{
  __shared__ float scp[64], shp[64], sc2[64], sh2[64], ssum[64], sssq[64];
  int tid = threadIdx.x, lane = tid & 63;
  if (tid < 64){
    float s,h;
    bn_param(stats+2*256, tid, INV_R1, pig,  pie,  s, h); scp[tid]=s; shp[tid]=h;
    bn_param(stats+1*256, tid, INV_R1, m1g1, m1e1, s, h); sc2[tid]=s; sh2[tid]=h;
    ssum[tid]=0.f; sssq[tid]=0.f;
  }
  __syncthreads();
  int row = blockIdx.x*256 + tid;
  int p = row >> 5, b = p >> 12;
  int idx = idxq[row];
  const float* wx = wxyz + (size_t)p*3;
  const float* fx = f2_xyz + ((size_t)b*Nn + idx)*3;
  float x0=wx[0],x1=wx[1],x2=wx[2],x3=fx[0],x4=fx[1],x5=fx[2];
  float acc[64];
  #pragma unroll
  for (int d=0;d<64;d++) acc[d] = m2b0[d];
  for (int j=0;j<64;j++){
    const float* pw = piwT + j*6;
    float t = pib[j] + x0*pw[0]+x1*pw[1]+x2*pw[2]+x3*pw[3]+x4*pw[4]+x5*pw[5];
    t = leakyf(t*scp[j] + shp[j]);
    const float* wr = m2w0 + j*64;
    #pragma unroll
    for (int d=0;d<64;d++) acc[d] += t*wr[d];
  }
  const float4* Ar = (const float4*)(A + (size_t)row*64);
  for (int jg=0;jg<16;jg++){
    float4 q = Ar[jg];
    float t0 = leakyf(q.x*sc2[jg*4+0]+sh2[jg*4+0]);
    float t1 = leakyf(q.y*sc2[jg*4+1]+sh2[jg*4+1]);
    float t2 = leakyf(q.z*sc2[jg*4+2]+sh2[jg*4+2]);
    float t3 = leakyf(q.w*sc2[jg*4+3]+sh2[jg*4+3]);
    const float* w0r = m2w0 + (64+jg*4+0)*64;
    const float* w1r = m2w0 + (64+jg*4+1)*64;
    const float* w2r = m2w0 + (64+jg*4+2)*64;
    const float* w3r = m2w0 + (64+jg*4+3)*64;
    #pragma unroll
    for (int d=0;d<64;d++) acc[d] += t0*w0r[d]+t1*w1r[d]+t2*w2r[d]+t3*w3r[d];
  }
  float4* Br = (float4*)(Bb + (size_t)row*64);
  #pragma unroll
  for (int d=0;d<16;d++) Br[d] = make_float4(acc[4*d],acc[4*d+1],acc[4*d+2],acc[4*d+3]);
  #pragma unroll
  for (int d=0;d<64;d++){
    float s1 = wred64(acc[d]), s2 = wred64(acc[d]*acc[d]);
    if (lane==0){ atomicAdd(&ssum[d], s1); atomicAdd(&sssq[d], s2); }
  }
  __syncthreads();
  if (tid < 64){ atomicAdd(&stats[3*256+tid], ssum[tid]); atomicAdd(&stats[3*256+128+tid], sssq[tid]); }
}

// ---------------- generic in-place 64->64 conv (m2_1 and m3_1) ----------------
__global__ __launch_bounds__(256) void k_conv64(
    float* __restrict__ buf, const float* statsIn, float inv_n,
    const float* __restrict__ g, const float* __restrict__ e,
    const float* __restrict__ w, const float* __restrict__ bias,
    float* statsOut)
{
  __shared__ float sc[64], sh[64], ssum[64], sssq[64];
  int tid = threadIdx.x, lane = tid & 63;
  if (tid < 64){
    float s,h; bn_param(statsIn, tid, inv_n, g, e, s, h);
    sc[tid]=s; sh[tid]=h; ssum[tid]=0.f; sssq[tid]=0.f;
  }
  __syncthreads();
  size_t row = (size_t)blockIdx.x*256 + tid;
  float* r = buf + row*64;
  float acc[64];
  #pragma unroll
  for (int d=0;d<64;d++) acc[d] = bias[d];
  const float4* r4 = (const float4*)r;
  for (int jg=0;jg<16;jg++){
    float4 q = r4[jg];
    float t0 = leakyf(q.x*sc[jg*4+0]+sh[jg*4+0]);
    float t1 = leakyf(q.y*sc[jg*4+1]+sh[jg*4+1]);
    float t2 = leakyf(q.z*sc[jg*4+2]+sh[jg*4+2]);
    float t3 = leakyf(q.w*sc[jg*4+3]+sh[jg*4+3]);
    const float* w0r = w + (jg*4+0)*64;
    const float* w1r = w + (jg*4+1)*64;
    const float* w2r = w + (jg*4+2)*64;
    const float* w3r = w + (jg*4+3)*64;
    #pragma unroll
    for (int d=0;d<64;d++) acc[d] += t0*w0r[d]+t1*w1r[d]+t2*w2r[d]+t3*w3r[d];
  }
  float4* rw = (float4*)r;
  #pragma unroll
  for (int d=0;d<16;d++) rw[d] = make_float4(acc[4*d],acc[4*d+1],acc[4*d+2],acc[4*d+3]);
  #pragma unroll
  for (int d=0;d<64;d++){
    float s1 = wred64(acc[d]), s2 = wred64(acc[d]*acc[d]);
    if (lane==0){ atomicAdd(&ssum[d], s1); atomicAdd(&sssq[d], s2); }
  }
  __syncthreads();
  if (tid < 64){ atomicAdd(&statsOut[tid], ssum[tid]); atomicAdd(&statsOut[128+tid], sssq[tid]); }
}

// ---------------- stage-1 softmax over KQ, weighted sum of feat -> pi_feat1 ----------------
__global__ __launch_bounds__(256) void k_softmax1(
    const float* __restrict__ A, const float* __restrict__ Bb,
    const float* stats,
    const float* __restrict__ m1g1, const float* __restrict__ m1e1,
    const float* __restrict__ m2g1, const float* __restrict__ m2e1,
    float* __restrict__ pif1)
{
  int tid = threadIdx.x, lane = tid & 63;
  int p = blockIdx.x*4 + (tid >> 6);
  int d = lane;
  float sc2,sh2,sc4,sh4;
  bn_param(stats+1*256, d, INV_R1, m1g1, m1e1, sc2, sh2);
  bn_param(stats+4*256, d, INV_R1, m2g1, m2e1, sc4, sh4);
  size_t rb = (size_t)p*KQn;
  float v[32]; float mx = -1e30f;
  #pragma unroll
  for (int k=0;k<32;k++){
    float t = leakyf(Bb[(rb+k)*64 + d]*sc4 + sh4);
    v[k] = t; mx = fmaxf(mx, t);
  }
  float se = 0.f;
  #pragma unroll
  for (int k=0;k<32;k++){ float ev = __expf(v[k]-mx); v[k]=ev; se += ev; }
  float inv = 1.f/se, acc = 0.f;
  #pragma unroll
  for (int k=0;k<32;k++){
    float f = leakyf(A[(rb+k)*64 + d]*sc2 + sh2);
    acc += v[k]*f;
  }
  pif1[(size_t)p*64 + d] = acc*inv;
}

// ---------------- m3a: [pc_enc | warped_points | gathered pi_feat1] x m3w0 -> y5 ----------------
__global__ __launch_bounds__(256) void k_conv_m3a(
    const float* __restrict__ wxyz, const float* __restrict__ warped_points,
    const float* __restrict__ pif1, const int* __restrict__ idx2,
    const float* __restrict__ pcwT, const float* __restrict__ pcb,
    const float* __restrict__ pcg, const float* __restrict__ pce,
    const float* __restrict__ m3w0, const float* __restrict__ m3b0,
    float* stats, float* __restrict__ Y)
{
  __shared__ float scp[64], shp[64], ssum[64], sssq[64];
  int tid = threadIdx.x, lane = tid & 63;
  if (tid < 64){
    float s,h; bn_param(stats+5*256, tid, INV_R2, pcg, pce, s, h);
    scp[tid]=s; shp[tid]=h; ssum[tid]=0.f; sssq[tid]=0.f;
  }
  __syncthreads();
  int row = blockIdx.x*256 + tid;
  int p = row >> 4, b = p >> 12;
  int idx = idx2[row];
  float x[10];
  build_x10(row, wxyz, idx2, x);
  float acc[64];
  #pragma unroll
  for (int d=0;d<64;d++) acc[d] = m3b0[d];
  for (int j=0;j<64;j++){
    const float* pw = pcwT + j*10;
    float t = pcb[j];
    #pragma unroll
    for (int i=0;i<10;i++) t += x[i]*pw[i];
    t = leakyf(t*scp[j] + shp[j]);
    const float* wr = m3w0 + j*64;
    #pragma unroll
    for (int d=0;d<64;d++) acc[d] += t*wr[d];
  }
  const float4* wpr = (const float4*)(warped_points + (size_t)p*64);
  for (int jg=0;jg<16;jg++){
    float4 q = wpr[jg];
    const float* w0r = m3w0 + (64+jg*4+0)*64;
    const float* w1r = m3w0 + (64+jg*4+1)*64;
    const float* w2r = m3w0 + (64+jg*4+2)*64;
    const float* w3r = m3w0 + (64+jg*4+3)*64;
    #pragma unroll
    for (int d=0;d<64;d++) acc[d] += q.x*w0r[d]+q.y*w1r[d]+q.z*w2r[d]+q.w*w3r[d];
  }
  const float4* pgr = (const float4*)(pif1 + ((size_t)b*HWn + idx)*64);
  for (int jg=0;jg<16;jg++){
    float4 q = pgr[jg];
    const float* w0r = m3w0 + (128+jg*4+0)*64;
    const float* w1r = m3w0 + (128+jg*4+1)*64;
    const float* w2r = m3w0 + (128+jg*4+2)*64;
    const float* w3r = m3w0 + (128+jg*4+3)*64;
    #pragma unroll
    for (int d=0;d<64;d++) acc[d] += q.x*w0r[d]+q.y*w1r[d]+q.z*w2r[d]+q.w*w3r[d];
  }
  float4* Yr = (float4*)(Y + (size_t)row*64);
  #pragma unroll
  for (int d=0;d<16;d++) Yr[d] = make_float4(acc[4*d],acc[4*d+1],acc[4*d+2],acc[4*d+3]);
  #pragma unroll
  for (int d=0;d<64;d++){
    float s1 = wred64(acc[d]), s2 = wred64(acc[d]*acc[d]);
    if (lane==0){ atomicAdd(&ssum[d], s1); atomicAdd(&sssq[d], s2); }
  }
  __syncthreads();
  if (tid < 64){ atomicAdd(&stats[6*256+tid], ssum[tid]); atomicAdd(&stats[6*256+128+tid], sssq[tid]); }
}

// ---------------- stage-2 masked softmax over KN, weighted sum of gathered pi_feat1 ----------------
__global__ __launch_bounds__(256) void k_softmax2(
    const float* __restrict__ Y, const float* __restrict__ pif1,
    const int* __restrict__ idx2, const float* __restrict__ validf,
    const float* stats,
    const float* __restrict__ m3g1, const float* __restrict__ m3e1,
    float* __restrict__ out)
{
  int tid = threadIdx.x, lane = tid & 63;
  int p = blockIdx.x*4 + (tid >> 6);
  int b = p >> 12;
  int d = lane;
  float sc,sh; bn_param(stats+7*256, d, INV_R2, m3g1, m3e1, sc, sh);
  size_t rb = (size_t)p*KNn;
  float v[16]; float mx = -1e30f;
  #pragma unroll
  for (int k=0;k<16;k++){
    float t = leakyf(Y[(rb+k)*64 + d]*sc + sh);
    t = (validf[rb+k] > 0.5f) ? t : -1e10f;
    v[k] = t; mx = fmaxf(mx, t);
  }
  float se = 0.f;
  #pragma unroll
  for (int k=0;k<16;k++){ float ev = __expf(v[k]-mx); v[k]=ev; se += ev; }
  float inv = 1.f/se, acc = 0.f;
  #pragma unroll
  for (int k=0;k<16;k++){
    int idx = idx2[rb+k];
    acc += v[k]*pif1[((size_t)b*HWn + idx)*64 + d];
  }
  out[(size_t)p*64 + d] = acc*inv;
}

// ---------------- launcher ----------------
extern "C" void kernel_launch(void* const* d_in, const int* in_sizes, int n_in,
                              void* d_out, int out_size, void* d_ws, size_t ws_size,
                              hipStream_t stream)
{
  (void)in_sizes; (void)n_in; (void)out_size; (void)ws_size;
  const float* xyz_proj      = (const float*)d_in[0];
  const float* warped_xyz    = (const float*)d_in[1];
  const float* warped_points = (const float*)d_in[2];
  const float* f2_xyz        = (const float*)d_in[4];
  const float* f2_points     = (const float*)d_in[5];
  const float* lidar_z       = (const float*)d_in[6];
  const float* m1w0=(const float*)d_in[7],  *m1b0=(const float*)d_in[8],  *m1g0=(const float*)d_in[9],  *m1e0=(const float*)d_in[10];
  const float* m1w1=(const float*)d_in[11], *m1b1=(const float*)d_in[12], *m1g1=(const float*)d_in[13], *m1e1=(const float*)d_in[14];
  const float* piw =(const float*)d_in[15], *pib =(const float*)d_in[16], *pig =(const float*)d_in[17], *pie =(const float*)d_in[18];
  const float* m2w0=(const float*)d_in[19], *m2b0=(const float*)d_in[20], *m2g0=(const float*)d_in[21], *m2e0=(const float*)d_in[22];
  const float* m2w1=(const float*)d_in[23], *m2b1=(const float*)d_in[24], *m2g1=(const float*)d_in[25], *m2e1=(const float*)d_in[26];
  const float* pcw =(const float*)d_in[27], *pcb =(const float*)d_in[28], *pcg =(const float*)d_in[29], *pce =(const float*)d_in[30];
  const float* m3w0=(const float*)d_in[31], *m3b0=(const float*)d_in[32], *m3g0=(const float*)d_in[33], *m3e0=(const float*)d_in[34];
  const float* m3w1=(const float*)d_in[35], *m3b1=(const float*)d_in[36], *m3g1=(const float*)d_in[37], *m3e1=(const float*)d_in[38];
  float* out = (float*)d_out;

  float* ws     = (float*)d_ws;
  float* wxyz   = ws;                        // 24576
  float* normW  = wxyz   + 24576;            // 524288
  float* normF2 = normW  + 524288;           // 524288
  float* pif1   = normF2 + 524288;           // 524288
  float* w0t    = pif1   + 524288;           // 8960
  float* piwT   = w0t    + 8960;             // 384
  float* pcwT   = piwT   + 384;              // 640
  float* stats  = pcwT   + 640;              // 2048 (8 BNs x [sum128|ssq128])
  int*   idxq   = (int*)(stats + 2048);      // 262144
  int*   idx2   = idxq   + 262144;           // 131072
  float* validf = (float*)(idx2 + 131072);   // 131072
  float* Abuf   = validf + 131072;           // 16777216 (y2 / y5,y6)
  float* Bbuf   = Abuf   + 16777216;         // 16777216 (y3,y4)
  // X1 (f16, 262144x96 = 12582912 floats) aliases the start of Bbuf: it is
  // fully consumed by k_mfma_m1 before k_conv_m2a writes Bbuf.
  _Float16* X1  = (_Float16*)Bbuf;
  // f16 weights live in the tail of Bbuf (beyond X1), also dead before m2a.
  _Float16* w1h = (_Float16*)(Bbuf + 13631488);   // 12288 f16
  _Float16* w2h = w1h + 12288;                    // 8192 f16

  hipMemsetAsync(stats, 0, 2048*sizeof(float), stream);
  k_prep<<<4311,256,0,stream>>>(warped_xyz, lidar_z, warped_points, f2_points,
                                m1w0, piw, pcw, m1w1,
                                wxyz, normW, normF2, w0t, piwT, pcwT, w1h, w2h);
  k_knn<32,false><<<8192,256,0,stream>>>(warped_xyz, f2_xyz, idxq, nullptr);
  k_knn<16,true ><<<8192,256,0,stream>>>(xyz_proj, xyz_proj, idx2, validf);
  k_buildX1<<<1024,256,0,stream>>>(wxyz, f2_xyz, normW, normF2, idxq, X1);
  k_stats<<<1536,256,0,stream>>>(wxyz, f2_xyz, idxq, idx2, piw, pib, pcw, pcb, stats);
  k_mfma_stats1<<<4096,256,0,stream>>>(X1, w1h, stats);
  k_mfma_m1<<<4096,256,0,stream>>>(X1, w1h, w2h, m1g0, m1e0, stats, Abuf);
  k_conv_m2a<<<1024,256,0,stream>>>(wxyz, f2_xyz, idxq, piwT, pib, pig, pie,
                                    m1g1, m1e1, m2w0, m2b0, stats, Abuf, Bbuf);
  k_conv64<<<1024,256,0,stream>>>(Bbuf, stats+3*256, INV_R1, m2g0, m2e0, m2w1, m2b1, stats+4*256);
  k_softmax1<<<2048,256,0,stream>>>(Abuf, Bbuf, stats, m1g1, m1e1, m2g1, m2e1, pif1);
  k_conv_m3a<<<512,256,0,stream>>>(wxyz, warped_points, pif1, idx2, pcwT, pcb, pcg, pce,
                                   m3w0, m3b0, stats, Abuf);
  k_conv64<<<512,256,0,stream>>>(Abuf, stats+6*256, INV_R2, m3g0, m3e0, m3w1, m3b1, stats+7*256);
  k_softmax2<<<2048,256,0,stream>>>(Abuf, pif1, idx2, validf, stats, m3g1, m3e1, out);
}

// Round 3
// 1029.701 us; speedup vs baseline: 1.5065x; 1.4622x over previous
//
#include <hip/hip_runtime.h>
#include <math.h>

// ---------------- problem constants ----------------
constexpr int Bn  = 2;
constexpr int HWn = 4096;     // H*W
constexpr int Nn  = 4096;
constexpr int KQn = 32;
constexpr int KNn = 16;
constexpr float INV_R1 = 1.0f/262144.0f;   // exact pow2
constexpr float INV_R2 = 1.0f/131072.0f;   // exact pow2

typedef _Float16 f16x8 __attribute__((ext_vector_type(8)));
typedef float    f32x4 __attribute__((ext_vector_type(4)));

__device__ __forceinline__ float wred64(float v){
  #pragma unroll
  for (int m = 32; m > 0; m >>= 1) v += __shfl_xor(v, m, 64);
  return v;
}
__device__ __forceinline__ float leakyf(float v){ return v > 0.f ? v : 0.1f*v; }

// BN affine from raw (sum,sumsq) stats: y_norm = y*sc + sh, then leaky outside.
__device__ __forceinline__ void bn_param(const float* st, int c, float inv_n,
                                         const float* g, const float* e,
                                         float& sc, float& sh){
  float mu  = st[c]*inv_n;
  float var = st[128+c]*inv_n - mu*mu;
  float s   = g[c]*rsqrtf(var + 1e-5f);
  sc = s; sh = e[c] - mu*s;
}

// Build the 70-channel stage-1 input row: [wxyz(3), f2_xyz[idx](3), normW*normF2(64)]
__device__ __forceinline__ void build_x70(int row,
    const float* __restrict__ wxyz, const float* __restrict__ f2_xyz,
    const float* __restrict__ normW, const float* __restrict__ normF2,
    const int* __restrict__ idxq, float* x){
  int p = row >> 5;         // (b*HW + i)
  int b = p >> 12;
  int idx = idxq[row];
  const float* wx = wxyz + (size_t)p*3;
  const float* fx = f2_xyz + ((size_t)b*Nn + idx)*3;
  x[0]=wx[0]; x[1]=wx[1]; x[2]=wx[2];
  x[3]=fx[0]; x[4]=fx[1]; x[5]=fx[2];
  const float4* nw = (const float4*)(normW  + (size_t)p*64);
  const float4* nf = (const float4*)(normF2 + ((size_t)b*Nn + idx)*64);
  #pragma unroll
  for (int c=0;c<16;c++){
    float4 a = nw[c], q = nf[c];
    x[6+4*c+0]=a.x*q.x; x[6+4*c+1]=a.y*q.y; x[6+4*c+2]=a.z*q.z; x[6+4*c+3]=a.w*q.w;
  }
}

// Build the 10-channel stage-2 geometry row
__device__ __forceinline__ void build_x10(int row,
    const float* __restrict__ wxyz, const int* __restrict__ idx2, float* x){
  int p = row >> 4, b = p >> 12;
  int idx = idx2[row];
  const float* nw = wxyz + (size_t)p*3;
  const float* gw = wxyz + ((size_t)b*HWn + idx)*3;
  float n0=nw[0],n1=nw[1],n2=nw[2];
  float g0=gw[0],g1=gw[1],g2=gw[2];
  float d0=g0-n0, d1=g1-n1, d2=g2-n2;
  x[0]=n0;x[1]=n1;x[2]=n2; x[3]=g0;x[4]=g1;x[5]=g2;
  x[6]=d0;x[7]=d1;x[8]=d2; x[9]=sqrtf(d0*d0+d1*d1+d2*d2+1e-20f);
}

// ---------------- prep: norms, wxyz, weight transposes + f16 weights ----------------
__global__ __launch_bounds__(256) void k_prep(
    const float* __restrict__ warped_xyz, const float* __restrict__ lidar_z,
    const float* __restrict__ warped_points, const float* __restrict__ f2_points,
    const float* __restrict__ m1w0, const float* __restrict__ piw, const float* __restrict__ pcw,
    const float* __restrict__ m1w1,
    float* __restrict__ wxyz, float* __restrict__ normW, float* __restrict__ normF2,
    float* __restrict__ w0t, float* __restrict__ piwT, float* __restrict__ pcwT,
    _Float16* __restrict__ w1h, _Float16* __restrict__ w2h)
{
  int blk = blockIdx.x, tid = threadIdx.x;
  if (blk < 4096){
    int lane = tid & 63;
    int p = blk*4 + (tid >> 6);            // 0..16383
    const float* src; float* dst;
    if (p < Bn*HWn){ src = warped_points + (size_t)p*64; dst = normW + (size_t)p*64; }
    else { int q = p - Bn*HWn; src = f2_points + (size_t)q*64; dst = normF2 + (size_t)q*64; }
    float x = src[lane];
    float m = wred64(x) * (1.f/64.f);
    float d = x - m;
    float ss = wred64(d*d);
    float s = fmaxf(sqrtf(ss*(1.f/63.f)), 1e-12f);   // unbiased std, clipped
    dst[lane] = d / s;
  } else if (blk < 4192){
    int e = (blk-4096)*256 + tid;          // < 24576
    wxyz[e] = warped_xyz[e] * lidar_z[e/3];
  } else if (blk < 4231){
    int e = (blk-4192)*256 + tid;
    if (e < 8960){ int i = e >> 7, j = e & 127; w0t[j*70 + i] = m1w0[e]; }
    else if (e < 8960+384){ int f = e-8960; piwT[(f & 63)*6  + (f >> 6)] = piw[f]; }
    else if (e < 8960+384+640){ int f = e-9344; pcwT[(f & 63)*10 + (f >> 6)] = pcw[f]; }
  } else {
    int e = (blk-4231)*256 + tid;          // < 20480
    if (e < 12288){                        // w1h[j][k] : [128 out][96 in-pad]
      int j = e/96, k = e - j*96;
      w1h[e] = (k < 70) ? (_Float16)m1w0[k*128 + j] : (_Float16)0.f;
    } else {                               // w2h[d][c] : [64 out][128 in]
      int f = e - 12288;
      int d = f >> 7, c = f & 127;
      w2h[f] = (_Float16)m1w1[c*64 + d];
    }
  }
}

// ---------------- exact k-smallest via 8-bit radix select (parallel scan) ----------------
template<int K, bool WRITE_VALID>
__global__ __launch_bounds__(256) void k_knn(
    const float* __restrict__ qpts, const float* __restrict__ pts,
    int* __restrict__ oidx, float* __restrict__ ovalid)
{
  __shared__ unsigned int sd[Nn];
  __shared__ int hist[256];
  __shared__ int wsum[4];
  __shared__ unsigned int sh_prefix;
  __shared__ int sh_rem, cnt_lt, cnt_eq;
  int b = blockIdx.x >> 12;
  int qi = blockIdx.x & 4095;
  int tid = threadIdx.x;
  int lane = tid & 63, wv = tid >> 6;
  const float* qp = qpts + ((size_t)(b*HWn+qi))*3;
  float qx=qp[0], qy=qp[1], qz=qp[2];
  const float* pb = pts + (size_t)b*Nn*3;
  for (int t=tid; t<Nn; t+=256){
    float dx = __fsub_rn(qx, pb[t*3+0]);
    float dy = __fsub_rn(qy, pb[t*3+1]);
    float dz = __fsub_rn(qz, pb[t*3+2]);
    float d2 = __fadd_rn(__fadd_rn(__fmul_rn(dx,dx), __fmul_rn(dy,dy)), __fmul_rn(dz,dz));
    sd[t] = __float_as_uint(d2);           // nonneg floats: uint order == float order
  }
  if (tid == 0){ cnt_lt = 0; cnt_eq = 0; }
  unsigned int prefix = 0; int rem = K;
  for (int shift = 24; shift >= 0; shift -= 8){
    __syncthreads();
    hist[tid] = 0;
    __syncthreads();
    unsigned int maskhi = (shift == 24) ? 0u : (0xFFFFFFFFu << (shift+8));
    for (int t=tid; t<Nn; t+=256){
      unsigned int v = sd[t];
      if ((v & maskhi) == prefix) atomicAdd(&hist[(v >> shift) & 255], 1);
    }
    __syncthreads();
    // parallel select: thread tid owns bucket tid
    int h = hist[tid];
    int pref = h;
    #pragma unroll
    for (int m=1;m<64;m<<=1){ int t = __shfl_up(pref, m, 64); if (lane >= m) pref += t; }
    if (lane == 63) wsum[wv] = pref;
    __syncthreads();
    int off = 0;
    #pragma unroll
    for (int i=0;i<3;i++) if (i < wv) off += wsum[i];
    pref += off;   // inclusive prefix over buckets 0..tid
    if (pref >= rem && (pref - h) < rem){
      sh_prefix = prefix | ((unsigned int)tid << shift);
      sh_rem = rem - (pref - h);
    }
    __syncthreads();
    prefix = sh_prefix; rem = sh_rem;
  }
  unsigned int kth = prefix;               // exact k-th smallest key
  int nless = K - rem;                     // # strictly smaller
  size_t obase = ((size_t)(b*HWn+qi))*K;
  const unsigned int U100 = __float_as_uint(100.0f);  // DIST*DIST
  for (int t=tid; t<Nn; t+=256){
    unsigned int v = sd[t];
    if (v <= kth){
      int s;
      if (v < kth) s = atomicAdd(&cnt_lt, 1);
      else { s = atomicAdd(&cnt_eq, 1); if (s >= rem) continue; s += nless; }
      oidx[obase+s] = t;
      if constexpr (WRITE_VALID) ovalid[obase+s] = (v < U100) ? 1.f : 0.f;
    }
  }
}

// ---------------- build f16 X1 rows: [wxyz(3) f2xyz(3) prod(64) pad->96] ----------------
__global__ __launch_bounds__(256) void k_buildX1(
    const float* __restrict__ wxyz, const float* __restrict__ f2_xyz,
    const float* __restrict__ normW, const float* __restrict__ normF2,
    const int* __restrict__ idxq, _Float16* __restrict__ X1)
{
  int row = blockIdx.x*256 + threadIdx.x;
  float x[70];
  build_x70(row, wxyz, f2_xyz, normW, normF2, idxq, x);
  unsigned int* d32 = (unsigned int*)(X1 + (size_t)row*96);
  union { unsigned int u; _Float16 h[2]; } pk;
  #pragma unroll
  for (int c=0;c<35;c++){
    pk.h[0] = (_Float16)x[2*c]; pk.h[1] = (_Float16)x[2*c+1];
    d32[c] = pk.u;
  }
  #pragma unroll
  for (int c=35;c<48;c++) d32[c] = 0u;
}

// ---------------- Gram-matrix stats for pi_enc (7x7) and pc_enc (11x11) ----------------
// Blocks 0..63: pi rows (x~=[wxyz,f2xyz,1], 28 upper-tri entries)
// Blocks 64..95: pc rows (x~=[new,g,diff,euc,1], 66 entries)
__global__ __launch_bounds__(256) void k_gram(
    const float* __restrict__ wxyz, const float* __restrict__ f2_xyz,
    const int* __restrict__ idxq, const int* __restrict__ idx2,
    float* __restrict__ gram)
{
  __shared__ float sacc[66];
  int blk = blockIdx.x, tid = threadIdx.x, lane = tid & 63;
  if (blk < 64){
    float a[28];
    #pragma unroll
    for (int q=0;q<28;q++) a[q]=0.f;
    int g = blk*256 + tid;                 // 0..16383
    for (int s=0;s<16;s++){
      int row = g + s*16384;
      int p = row >> 5, b = p >> 12;
      int idx = idxq[row];
      const float* wx = wxyz + (size_t)p*3;
      const float* fx = f2_xyz + ((size_t)b*Nn + idx)*3;
      float xt[7] = {wx[0],wx[1],wx[2],fx[0],fx[1],fx[2],1.f};
      int q=0;
      #pragma unroll
      for (int i=0;i<7;i++)
        #pragma unroll
        for (int j=i;j<7;j++) a[q++] += xt[i]*xt[j];
    }
    if (tid < 28) sacc[tid]=0.f;
    __syncthreads();
    #pragma unroll
    for (int q=0;q<28;q++){
      float v = wred64(a[q]);
      if (lane==0) atomicAdd(&sacc[q], v);
    }
    __syncthreads();
    if (tid < 28) atomicAdd(&gram[tid], sacc[tid]);
  } else {
    float a[66];
    #pragma unroll
    for (int q=0;q<66;q++) a[q]=0.f;
    int g = (blk-64)*256 + tid;            // 0..8191
    for (int s=0;s<16;s++){
      int row = g + s*8192;
      float x[10];
      build_x10(row, wxyz, idx2, x);
      float xt[11] = {x[0],x[1],x[2],x[3],x[4],x[5],x[6],x[7],x[8],x[9],1.f};
      int q=0;
      #pragma unroll
      for (int i=0;i<11;i++)
        #pragma unroll
        for (int j=i;j<11;j++) a[q++] += xt[i]*xt[j];
    }
    if (tid < 66) sacc[tid]=0.f;
    __syncthreads();
    #pragma unroll
    for (int q=0;q<66;q++){
      float v = wred64(a[q]);
      if (lane==0) atomicAdd(&sacc[q], v);
    }
    __syncthreads();
    if (tid < 66) atomicAdd(&gram[32+tid], sacc[tid]);
  }
}

// finalize: stats[sum,ssq] for pi_enc (slot 2) and pc_enc (slot 5) from Gram
__global__ __launch_bounds__(128) void k_gram_fin(
    const float* __restrict__ gram,
    const float* __restrict__ piw, const float* __restrict__ pib,
    const float* __restrict__ pcw, const float* __restrict__ pcb,
    float* stats)
{
  int tid = threadIdx.x;
  if (tid < 64){
    int c = tid;
    float wt[7];
    #pragma unroll
    for (int i=0;i<6;i++) wt[i] = piw[i*64+c];
    wt[6] = pib[c];
    const float* G = gram;
    float sum=0.f, ssq=0.f;
    #pragma unroll
    for (int i=0;i<7;i++){
      // off7[i] = i*7 - i*(i-1)/2
      int offi = i*7 - (i*(i-1))/2;
      sum += wt[i]*G[offi + (6-i)];
      #pragma unroll
      for (int j=0;j<7;j++){
        int ii = i<j? i : j, jj = i<j? j : i;
        int o = ii*7 - (ii*(ii-1))/2 + (jj-ii);
        ssq += wt[i]*wt[j]*G[o];
      }
    }
    stats[2*256+c] = sum; stats[2*256+128+c] = ssq;
  } else {
    int c = tid-64;
    float wt[11];
    #pragma unroll
    for (int i=0;i<10;i++) wt[i] = pcw[i*64+c];
    wt[10] = pcb[c];
    const float* G = gram + 32;
    float sum=0.f, ssq=0.f;
    #pragma unroll
    for (int i=0;i<11;i++){
      int offi = i*11 - (i*(i-1))/2;
      sum += wt[i]*G[offi + (10-i)];
      #pragma unroll
      for (int j=0;j<11;j++){
        int ii = i<j? i : j, jj = i<j? j : i;
        int o = ii*11 - (ii*(ii-1))/2 + (jj-ii);
        ssq += wt[i]*wt[j]*G[o];
      }
    }
    stats[5*256+c] = sum; stats[5*256+128+c] = ssq;
  }
}

// ---------------- MFMA y1 stats (bias dropped: BN is shift-invariant) ----------------
__global__ __launch_bounds__(256) void k_mfma_stats1(
    const _Float16* __restrict__ X1, const _Float16* __restrict__ w1h,
    float* stats)
{
  __shared__ _Float16 sw[128*104];           // W1 [128][96] staged with stride 104
  __shared__ float ssum[128], sssq[128];
  int tid = threadIdx.x;
  const unsigned int* wsrc = (const unsigned int*)w1h;
  for (int d = tid; d < 6144; d += 256){
    int row = d/48, col = d - row*48;
    ((unsigned int*)sw)[row*52 + col] = wsrc[d];
  }
  if (tid < 128){ ssum[tid]=0.f; sssq[tid]=0.f; }
  __syncthreads();
  int wave = tid >> 6, lane = tid & 63;
  int quad = lane >> 4, n16 = lane & 15;
  int m0 = blockIdx.x*64 + wave*16;
  const _Float16* xr = X1 + (size_t)(m0 + n16)*96 + quad*8;
  f16x8 a0 = *(const f16x8*)(xr);
  f16x8 a1 = *(const f16x8*)(xr + 32);
  f16x8 a2 = *(const f16x8*)(xr + 64);
  for (int nt = 0; nt < 8; nt++){
    const _Float16* wr = sw + (size_t)(nt*16 + n16)*104 + quad*8;
    f16x8 b0 = *(const f16x8*)(wr);
    f16x8 b1 = *(const f16x8*)(wr + 32);
    f16x8 b2 = *(const f16x8*)(wr + 64);
    f32x4 acc = {0.f,0.f,0.f,0.f};
    acc = __builtin_amdgcn_mfma_f32_16x16x32_f16(a0, b0, acc, 0,0,0);
    acc = __builtin_amdgcn_mfma_f32_16x16x32_f16(a1, b1, acc, 0,0,0);
    acc = __builtin_amdgcn_mfma_f32_16x16x32_f16(a2, b2, acc, 0,0,0);
    float s1 = acc[0]+acc[1]+acc[2]+acc[3];
    float s2 = acc[0]*acc[0]+acc[1]*acc[1]+acc[2]*acc[2]+acc[3]*acc[3];
    s1 += __shfl_xor(s1, 16, 64); s1 += __shfl_xor(s1, 32, 64);
    s2 += __shfl_xor(s2, 16, 64); s2 += __shfl_xor(s2, 32, 64);
    if (quad == 0){ atomicAdd(&ssum[nt*16+n16], s1); atomicAdd(&sssq[nt*16+n16], s2); }
  }
  __syncthreads();
  if (tid < 128){ atomicAdd(&stats[tid], ssum[tid]); atomicAdd(&stats[128+tid], sssq[tid]); }
}

// ---------------- MFMA m1: y1 -> BN/leaky -> t (LDS) -> x W2 -> y2 (f32) + stats ----------------
__global__ __launch_bounds__(256) void k_mfma_m1(
    const _Float16* __restrict__ X1, const _Float16* __restrict__ w1h,
    const _Float16* __restrict__ w2h,
    const float* __restrict__ m1g0, const float* __restrict__ m1e0,
    float* stats, float* __restrict__ A)
{
  __shared__ _Float16 sw[128*104];           // W1, stride 104
  __shared__ _Float16 sw2[64*136];           // W2t [64][128], stride 136
  __shared__ _Float16 st[64*136];            // t rows [64][128], stride 136
  __shared__ float sc1[128], sh1[128], ssum[64], sssq[64];
  int tid = threadIdx.x;
  const unsigned int* wsrc = (const unsigned int*)w1h;
  for (int d = tid; d < 6144; d += 256){
    int row = d/48, col = d - row*48;
    ((unsigned int*)sw)[row*52 + col] = wsrc[d];
  }
  const unsigned int* w2src = (const unsigned int*)w2h;
  for (int d = tid; d < 4096; d += 256){
    int row = d >> 6, col = d & 63;
    ((unsigned int*)sw2)[row*68 + col] = w2src[d];
  }
  if (tid < 128){
    float s,h; bn_param(stats, tid, INV_R1, m1g0, m1e0, s, h);
    sc1[tid]=s; sh1[tid]=h;
  }
  if (tid < 64){ ssum[tid]=0.f; sssq[tid]=0.f; }
  __syncthreads();
  int wave = tid >> 6, lane = tid & 63;
  int quad = lane >> 4, n16 = lane & 15;
  int m0 = blockIdx.x*64 + wave*16;
  const _Float16* xr = X1 + (size_t)(m0 + n16)*96 + quad*8;
  f16x8 a0 = *(const f16x8*)(xr);
  f16x8 a1 = *(const f16x8*)(xr + 32);
  f16x8 a2 = *(const f16x8*)(xr + 64);
  for (int nt = 0; nt < 8; nt++){
    const _Float16* wr = sw + (size_t)(nt*16 + n16)*104 + quad*8;
    f16x8 b0 = *(const f16x8*)(wr);
    f16x8 b1 = *(const f16x8*)(wr + 32);
    f16x8 b2 = *(const f16x8*)(wr + 64);
    f32x4 acc = {0.f,0.f,0.f,0.f};
    acc = __builtin_amdgcn_mfma_f32_16x16x32_f16(a0, b0, acc, 0,0,0);
    acc = __builtin_amdgcn_mfma_f32_16x16x32_f16(a1, b1, acc, 0,0,0);
    acc = __builtin_amdgcn_mfma_f32_16x16x32_f16(a2, b2, acc, 0,0,0);
    int ch = nt*16 + n16;
    float sc = sc1[ch], sh = sh1[ch];
    #pragma unroll
    for (int r=0;r<4;r++){
      float v = leakyf(acc[r]*sc + sh);
      st[(size_t)(wave*16 + quad*4 + r)*136 + ch] = (_Float16)v;
    }
  }
  __syncthreads();
  // second GEMM: t (64x128) x W2t -> y2 (64 ch)
  const _Float16* tr = st + (size_t)(wave*16 + n16)*136 + quad*8;
  f16x8 t0 = *(const f16x8*)(tr);
  f16x8 t1 = *(const f16x8*)(tr + 32);
  f16x8 t2 = *(const f16x8*)(tr + 64);
  f16x8 t3 = *(const f16x8*)(tr + 96);
  for (int nt = 0; nt < 4; nt++){
    const _Float16* wr = sw2 + (size_t)(nt*16 + n16)*136 + quad*8;
    f16x8 b0 = *(const f16x8*)(wr);
    f16x8 b1 = *(const f16x8*)(wr + 32);
    f16x8 b2 = *(const f16x8*)(wr + 64);
    f16x8 b3 = *(const f16x8*)(wr + 96);
    f32x4 acc = {0.f,0.f,0.f,0.f};
    acc = __builtin_amdgcn_mfma_f32_16x16x32_f16(t0, b0, acc, 0,0,0);
    acc = __builtin_amdgcn_mfma_f32_16x16x32_f16(t1, b1, acc, 0,0,0);
    acc = __builtin_amdgcn_mfma_f32_16x16x32_f16(t2, b2, acc, 0,0,0);
    acc = __builtin_amdgcn_mfma_f32_16x16x32_f16(t3, b3, acc, 0,0,0);
    int ch = nt*16 + n16;
    #pragma unroll
    for (int r=0;r<4;r++){
      int rowg = blockIdx.x*64 + wave*16 + quad*4 + r;
      A[(size_t)rowg*64 + ch] = acc[r];
    }
    float s1 = acc[0]+acc[1]+acc[2]+acc[3];
    float s2 = acc[0]*acc[0]+acc[1]*acc[1]+acc[2]*acc[2]+acc[3]*acc[3];
    s1 += __shfl_xor(s1, 16, 64); s1 += __shfl_xor(s1, 32, 64);
    s2 += __shfl_xor(s2, 16, 64); s2 += __shfl_xor(s2, 32, 64);
    if (quad == 0){ atomicAdd(&ssum[ch], s1); atomicAdd(&sssq[ch], s2); }
  }
  __syncthreads();
  if (tid < 64){ atomicAdd(&stats[1*256+tid], ssum[tid]); atomicAdd(&stats[1*256+128+tid], sssq[tid]); }
}

// ---------------- m2a: [pi_enc | feat] x m2w0 -> y3 (B) + stats ----------------
__global__ __launch_bounds__(256) void k_conv_m2a(
    const float* __restrict__ wxyz, const float* __restrict__ f2_xyz,
    const int* __restrict__ idxq,
    const float* __restrict__ piwT, const float* __restrict__ pib,
    const float* __restrict__ pig, const float* __restrict__ pie,
    const float* __restrict__ m1g1, const float* __restrict__ m1e1,
    const float* __restrict__ m2w0, const float* __restrict__ m2b0,
    float* stats, const float* __restrict__ A, float* __restrict__ Bb)
{
  __shared__ float scp[64], shp[64], sc2[64], sh2[64], ssum[64], sssq[64];
  int tid = threadIdx.x, lane = tid & 63;
  if (tid < 64){
    float s,h;
    bn_param(stats+2*256, tid, INV_R1, pig,  pie,  s, h); scp[tid]=s; shp[tid]=h;
    bn_param(stats+1*256, tid, INV_R1, m1g1, m1e1, s, h); sc2[tid]=s; sh2[tid]=h;
    ssum[tid]=0.f; sssq[tid]=0.f;
  }
  __syncthreads();
  int row = blockIdx.x*256 + tid;
  int p = row >> 5, b = p >> 12;
  int idx = idxq[row];
  const float* wx = wxyz + (size_t)p*3;
  const float* fx = f2_xyz + ((size_t)b*Nn + idx)*3;
  float x0=wx[0],x1=wx[1],x2=wx[2],x3=fx[0],x4=fx[1],x5=fx[2];
  float acc[64];
  #pragma unroll
  for (int d=0;d<64;d++) acc[d] = m2b0[d];
  for (int j=0;j<64;j++){
    const float* pw = piwT + j*6;
    float t = pib[j] + x0*pw[0]+x1*pw[1]+x2*pw[2]+x3*pw[3]+x4*pw[4]+x5*pw[5];
    t = leakyf(t*scp[j] + shp[j]);
    const float* wr = m2w0 + j*64;
    #pragma unroll
    for (int d=0;d<64;d++) acc[d] += t*wr[d];
  }
  const float4* Ar = (const float4*)(A + (size_t)row*64);
  for (int jg=0;jg<16;jg++){
    float4 q = Ar[jg];
    float t0 = leakyf(q.x*sc2[jg*4+0]+sh2[jg*4+0]);
    float t1 = leakyf(q.y*sc2[jg*4+1]+sh2[jg*4+1]);
    float t2 = leakyf(q.z*sc2[jg*4+2]+sh2[jg*4+2]);
    float t3 = leakyf(q.w*sc2[jg*4+3]+sh2[jg*4+3]);
    const float* w0r = m2w0 + (64+jg*4+0)*64;
    const float* w1r = m2w0 + (64+jg*4+1)*64;
    const float* w2r = m2w0 + (64+jg*4+2)*64;
    const float* w3r = m2w0 + (64+jg*4+3)*64;
    #pragma unroll
    for (int d=0;d<64;d++) acc[d] += t0*w0r[d]+t1*w1r[d]+t2*w2r[d]+t3*w3r[d];
  }
  float4* Br = (float4*)(Bb + (size_t)row*64);
  #pragma unroll
  for (int d=0;d<16;d++) Br[d] = make_float4(acc[4*d],acc[4*d+1],acc[4*d+2],acc[4*d+3]);
  #pragma unroll
  for (int d=0;d<64;d++){
    float s1 = wred64(acc[d]), s2 = wred64(acc[d]*acc[d]);
    if (lane==0){ atomicAdd(&ssum[d], s1); atomicAdd(&sssq[d], s2); }
  }
  __syncthreads();
  if (tid < 64){ atomicAdd(&stats[3*256+tid], ssum[tid]); atomicAdd(&stats[3*256+128+tid], sssq[tid]); }
}

// ---------------- generic in-place 64->64 conv (m2_1 and m3_1) ----------------
__global__ __launch_bounds__(256) void k_conv64(
    float* __restrict__ buf, const float* statsIn, float inv_n,
    const float* __restrict__ g, const float* __restrict__ e,
    const float* __restrict__ w, const float* __restrict__ bias,
    float* statsOut)
{
  __shared__ float sc[64], sh[64], ssum[64], sssq[64];
  int tid = threadIdx.x, lane = tid & 63;
  if (tid < 64){
    float s,h; bn_param(statsIn, tid, inv_n, g, e, s, h);
    sc[tid]=s; sh[tid]=h; ssum[tid]=0.f; sssq[tid]=0.f;
  }
  __syncthreads();
  size_t row = (size_t)blockIdx.x*256 + tid;
  float* r = buf + row*64;
  float acc[64];
  #pragma unroll
  for (int d=0;d<64;d++) acc[d] = bias[d];
  const float4* r4 = (const float4*)r;
  for (int jg=0;jg<16;jg++){
    float4 q = r4[jg];
    float t0 = leakyf(q.x*sc[jg*4+0]+sh[jg*4+0]);
    float t1 = leakyf(q.y*sc[jg*4+1]+sh[jg*4+1]);
    float t2 = leakyf(q.z*sc[jg*4+2]+sh[jg*4+2]);
    float t3 = leakyf(q.w*sc[jg*4+3]+sh[jg*4+3]);
    const float* w0r = w + (jg*4+0)*64;
    const float* w1r = w + (jg*4+1)*64;
    const float* w2r = w + (jg*4+2)*64;
    const float* w3r = w + (jg*4+3)*64;
    #pragma unroll
    for (int d=0;d<64;d++) acc[d] += t0*w0r[d]+t1*w1r[d]+t2*w2r[d]+t3*w3r[d];
  }
  float4* rw = (float4*)r;
  #pragma unroll
  for (int d=0;d<16;d++) rw[d] = make_float4(acc[4*d],acc[4*d+1],acc[4*d+2],acc[4*d+3]);
  #pragma unroll
  for (int d=0;d<64;d++){
    float s1 = wred64(acc[d]), s2 = wred64(acc[d]*acc[d]);
    if (lane==0){ atomicAdd(&ssum[d], s1); atomicAdd(&sssq[d], s2); }
  }
  __syncthreads();
  if (tid < 64){ atomicAdd(&statsOut[tid], ssum[tid]); atomicAdd(&statsOut[128+tid], sssq[tid]); }
}

// ---------------- stage-1 softmax over KQ, weighted sum of feat -> pi_feat1 ----------------
__global__ __launch_bounds__(256) void k_softmax1(
    const float* __restrict__ A, const float* __restrict__ Bb,
    const float* stats,
    const float* __restrict__ m1g1, const float* __restrict__ m1e1,
    const float* __restrict__ m2g1, const float* __restrict__ m2e1,
    float* __restrict__ pif1)
{
  int tid = threadIdx.x, lane = tid & 63;
  int p = blockIdx.x*4 + (tid >> 6);
  int d = lane;
  float sc2,sh2,sc4,sh4;
  bn_param(stats+1*256, d, INV_R1, m1g1, m1e1, sc2, sh2);
  bn_param(stats+4*256, d, INV_R1, m2g1, m2e1, sc4, sh4);
  size_t rb = (size_t)p*KQn;
  float v[32]; float mx = -1e30f;
  #pragma unroll
  for (int k=0;k<32;k++){
    float t = leakyf(Bb[(rb+k)*64 + d]*sc4 + sh4);
    v[k] = t; mx = fmaxf(mx, t);
  }
  float se = 0.f;
  #pragma unroll
  for (int k=0;k<32;k++){ float ev = __expf(v[k]-mx); v[k]=ev; se += ev; }
  float inv = 1.f/se, acc = 0.f;
  #pragma unroll
  for (int k=0;k<32;k++){
    float f = leakyf(A[(rb+k)*64 + d]*sc2 + sh2);
    acc += v[k]*f;
  }
  pif1[(size_t)p*64 + d] = acc*inv;
}

// ---------------- m3a: [pc_enc | warped_points | gathered pi_feat1] x m3w0 -> y5 ----------------
__global__ __launch_bounds__(256) void k_conv_m3a(
    const float* __restrict__ wxyz, const float* __restrict__ warped_points,
    const float* __restrict__ pif1, const int* __restrict__ idx2,
    const float* __restrict__ pcwT, const float* __restrict__ pcb,
    const float* __restrict__ pcg, const float* __restrict__ pce,
    const float* __restrict__ m3w0, const float* __restrict__ m3b0,
    float* stats, float* __restrict__ Y)
{
  __shared__ float scp[64], shp[64], ssum[64], sssq[64];
  int tid = threadIdx.x, lane = tid & 63;
  if (tid < 64){
    float s,h; bn_param(stats+5*256, tid, INV_R2, pcg, pce, s, h);
    scp[tid]=s; shp[tid]=h; ssum[tid]=0.f; sssq[tid]=0.f;
  }
  __syncthreads();
  int row = blockIdx.x*256 + tid;
  int p = row >> 4, b = p >> 12;
  int idx = idx2[row];
  float x[10];
  build_x10(row, wxyz, idx2, x);
  float acc[64];
  #pragma unroll
  for (int d=0;d<64;d++) acc[d] = m3b0[d];
  for (int j=0;j<64;j++){
    const float* pw = pcwT + j*10;
    float t = pcb[j];
    #pragma unroll
    for (int i=0;i<10;i++) t += x[i]*pw[i];
    t = leakyf(t*scp[j] + shp[j]);
    const float* wr = m3w0 + j*64;
    #pragma unroll
    for (int d=0;d<64;d++) acc[d] += t*wr[d];
  }
  const float4* wpr = (const float4*)(warped_points + (size_t)p*64);
  for (int jg=0;jg<16;jg++){
    float4 q = wpr[jg];
    const float* w0r = m3w0 + (64+jg*4+0)*64;
    const float* w1r = m3w0 + (64+jg*4+1)*64;
    const float* w2r = m3w0 + (64+jg*4+2)*64;
    const float* w3r = m3w0 + (64+jg*4+3)*64;
    #pragma unroll
    for (int d=0;d<64;d++) acc[d] += q.x*w0r[d]+q.y*w1r[d]+q.z*w2r[d]+q.w*w3r[d];
  }
  const float4* pgr = (const float4*)(pif1 + ((size_t)b*HWn + idx)*64);
  for (int jg=0;jg<16;jg++){
    float4 q = pgr[jg];
    const float* w0r = m3w0 + (128+jg*4+0)*64;
    const float* w1r = m3w0 + (128+jg*4+1)*64;
    const float* w2r = m3w0 + (128+jg*4+2)*64;
    const float* w3r = m3w0 + (128+jg*4+3)*64;
    #pragma unroll
    for (int d=0;d<64;d++) acc[d] += q.x*w0r[d]+q.y*w1r[d]+q.z*w2r[d]+q.w*w3r[d];
  }
  float4* Yr = (float4*)(Y + (size_t)row*64);
  #pragma unroll
  for (int d=0;d<16;d++) Yr[d] = make_float4(acc[4*d],acc[4*d+1],acc[4*d+2],acc[4*d+3]);
  #pragma unroll
  for (int d=0;d<64;d++){
    float s1 = wred64(acc[d]), s2 = wred64(acc[d]*acc[d]);
    if (lane==0){ atomicAdd(&ssum[d], s1); atomicAdd(&sssq[d], s2); }
  }
  __syncthreads();
  if (tid < 64){ atomicAdd(&stats[6*256+tid], ssum[tid]); atomicAdd(&stats[6*256+128+tid], sssq[tid]); }
}

// ---------------- stage-2 masked softmax over KN, weighted sum of gathered pi_feat1 ----------------
__global__ __launch_bounds__(256) void k_softmax2(
    const float* __restrict__ Y, const float* __restrict__ pif1,
    const int* __restrict__ idx2, const float* __restrict__ validf,
    const float* stats,
    const float* __restrict__ m3g1, const float* __restrict__ m3e1,
    float* __restrict__ out)
{
  int tid = threadIdx.x, lane = tid & 63;
  int p = blockIdx.x*4 + (tid >> 6);
  int b = p >> 12;
  int d = lane;
  float sc,sh; bn_param(stats+7*256, d, INV_R2, m3g1, m3e1, sc, sh);
  size_t rb = (size_t)p*KNn;
  float v[16]; float mx = -1e30f;
  #pragma unroll
  for (int k=0;k<16;k++){
    float t = leakyf(Y[(rb+k)*64 + d]*sc + sh);
    t = (validf[rb+k] > 0.5f) ? t : -1e10f;
    v[k] = t; mx = fmaxf(mx, t);
  }
  float se = 0.f;
  #pragma unroll
  for (int k=0;k<16;k++){ float ev = __expf(v[k]-mx); v[k]=ev; se += ev; }
  float inv = 1.f/se, acc = 0.f;
  #pragma unroll
  for (int k=0;k<16;k++){
    int idx = idx2[rb+k];
    acc += v[k]*pif1[((size_t)b*HWn + idx)*64 + d];
  }
  out[(size_t)p*64 + d] = acc*inv;
}

// ---------------- launcher ----------------
extern "C" void kernel_launch(void* const* d_in, const int* in_sizes, int n_in,
                              void* d_out, int out_size, void* d_ws, size_t ws_size,
                              hipStream_t stream)
{
  (void)in_sizes; (void)n_in; (void)out_size; (void)ws_size;
  const float* xyz_proj      = (const float*)d_in[0];
  const float* warped_xyz    = (const float*)d_in[1];
  const float* warped_points = (const float*)d_in[2];
  const float* f2_xyz        = (const float*)d_in[4];
  const float* f2_points     = (const float*)d_in[5];
  const float* lidar_z       = (const float*)d_in[6];
  const float* m1w0=(const float*)d_in[7],  *m1b0=(const float*)d_in[8],  *m1g0=(const float*)d_in[9],  *m1e0=(const float*)d_in[10];
  const float* m1w1=(const float*)d_in[11], *m1b1=(const float*)d_in[12], *m1g1=(const float*)d_in[13], *m1e1=(const float*)d_in[14];
  const float* piw =(const float*)d_in[15], *pib =(const float*)d_in[16], *pig =(const float*)d_in[17], *pie =(const float*)d_in[18];
  const float* m2w0=(const float*)d_in[19], *m2b0=(const float*)d_in[20], *m2g0=(const float*)d_in[21], *m2e0=(const float*)d_in[22];
  const float* m2w1=(const float*)d_in[23], *m2b1=(const float*)d_in[24], *m2g1=(const float*)d_in[25], *m2e1=(const float*)d_in[26];
  const float* pcw =(const float*)d_in[27], *pcb =(const float*)d_in[28], *pcg =(const float*)d_in[29], *pce =(const float*)d_in[30];
  const float* m3w0=(const float*)d_in[31], *m3b0=(const float*)d_in[32], *m3g0=(const float*)d_in[33], *m3e0=(const float*)d_in[34];
  const float* m3w1=(const float*)d_in[35], *m3b1=(const float*)d_in[36], *m3g1=(const float*)d_in[37], *m3e1=(const float*)d_in[38];
  float* out = (float*)d_out;

  float* ws     = (float*)d_ws;
  float* wxyz   = ws;                        // 24576
  float* normW  = wxyz   + 24576;            // 524288
  float* normF2 = normW  + 524288;           // 524288
  float* pif1   = normF2 + 524288;           // 524288
  float* w0t    = pif1   + 524288;           // 8960
  float* piwT   = w0t    + 8960;             // 384
  float* pcwT   = piwT   + 384;              // 640
  float* stats  = pcwT   + 640;              // 2048 (8 BNs x [sum128|ssq128])
  float* gram   = stats  + 2048;             // 128 (28 pi @0, 66 pc @32)
  int*   idxq   = (int*)(gram + 128);        // 262144
  int*   idx2   = idxq   + 262144;           // 131072
  float* validf = (float*)(idx2 + 131072);   // 131072
  float* Abuf   = validf + 131072;           // 16777216 (y2 / y5,y6)
  float* Bbuf   = Abuf   + 16777216;         // 16777216 (y3,y4)
  // X1 (f16, 262144x96 = 12582912 floats) aliases the start of Bbuf: it is
  // fully consumed by k_mfma_m1 before k_conv_m2a writes Bbuf.
  _Float16* X1  = (_Float16*)Bbuf;
  // f16 weights live in the tail of Bbuf (beyond X1), also dead before m2a.
  _Float16* w1h = (_Float16*)(Bbuf + 13631488);   // 12288 f16
  _Float16* w2h = w1h + 12288;                    // 8192 f16

  hipMemsetAsync(stats, 0, (2048+128)*sizeof(float), stream);
  k_prep<<<4311,256,0,stream>>>(warped_xyz, lidar_z, warped_points, f2_points,
                                m1w0, piw, pcw, m1w1,
                                wxyz, normW, normF2, w0t, piwT, pcwT, w1h, w2h);
  k_knn<32,false><<<8192,256,0,stream>>>(warped_xyz, f2_xyz, idxq, nullptr);
  k_knn<16,true ><<<8192,256,0,stream>>>(xyz_proj, xyz_proj, idx2, validf);
  k_buildX1<<<1024,256,0,stream>>>(wxyz, f2_xyz, normW, normF2, idxq, X1);
  k_gram<<<96,256,0,stream>>>(wxyz, f2_xyz, idxq, idx2, gram);
  k_gram_fin<<<1,128,0,stream>>>(gram, piw, pib, pcw, pcb, stats);
  k_mfma_stats1<<<4096,256,0,stream>>>(X1, w1h, stats);
  k_mfma_m1<<<4096,256,0,stream>>>(X1, w1h, w2h, m1g0, m1e0, stats, Abuf);
  k_conv_m2a<<<1024,256,0,stream>>>(wxyz, f2_xyz, idxq, piwT, pib, pig, pie,
                                    m1g1, m1e1, m2w0, m2b0, stats, Abuf, Bbuf);
  k_conv64<<<1024,256,0,stream>>>(Bbuf, stats+3*256, INV_R1, m2g0, m2e0, m2w1, m2b1, stats+4*256);
  k_softmax1<<<2048,256,0,stream>>>(Abuf, Bbuf, stats, m1g1, m1e1, m2g1, m2e1, pif1);
  k_conv_m3a<<<512,256,0,stream>>>(wxyz, warped_points, pif1, idx2, pcwT, pcb, pcg, pce,
                                   m3w0, m3b0, stats, Abuf);
  k_conv64<<<512,256,0,stream>>>(Abuf, stats+6*256, INV_R2, m3g0, m3e0, m3w1, m3b1, stats+7*256);
  k_softmax2<<<2048,256,0,stream>>>(Abuf, pif1, idx2, validf, stats, m3g1, m3e1, out);
}

// Round 4
// 982.371 us; speedup vs baseline: 1.5791x; 1.0482x over previous
//
#include <hip/hip_runtime.h>
#include <math.h>

// ---------------- problem constants ----------------
constexpr int Bn  = 2;
constexpr int HWn = 4096;     // H*W
constexpr int Nn  = 4096;
constexpr int KQn = 32;
constexpr int KNn = 16;
constexpr float INV_R1 = 1.0f/262144.0f;   // exact pow2
constexpr float INV_R2 = 1.0f/131072.0f;   // exact pow2

typedef _Float16 f16x8 __attribute__((ext_vector_type(8)));
typedef float    f32x4 __attribute__((ext_vector_type(4)));

__device__ __forceinline__ float wred64(float v){
  #pragma unroll
  for (int m = 32; m > 0; m >>= 1) v += __shfl_xor(v, m, 64);
  return v;
}
__device__ __forceinline__ float leakyf(float v){ return v > 0.f ? v : 0.1f*v; }

__device__ __forceinline__ void bn_param(const float* st, int c, float inv_n,
                                         const float* g, const float* e,
                                         float& sc, float& sh){
  float mu  = st[c]*inv_n;
  float var = st[128+c]*inv_n - mu*mu;
  float s   = g[c]*rsqrtf(var + 1e-5f);
  sc = s; sh = e[c] - mu*s;
}

// Build the 70-channel stage-1 input row: [wxyz(3), f2_xyz[idx](3), normW*normF2(64)]
__device__ __forceinline__ void build_x70(int row,
    const float* __restrict__ wxyz, const float* __restrict__ f2_xyz,
    const float* __restrict__ normW, const float* __restrict__ normF2,
    const int* __restrict__ idxq, float* x){
  int p = row >> 5;
  int b = p >> 12;
  int idx = idxq[row];
  const float* wx = wxyz + (size_t)p*3;
  const float* fx = f2_xyz + ((size_t)b*Nn + idx)*3;
  x[0]=wx[0]; x[1]=wx[1]; x[2]=wx[2];
  x[3]=fx[0]; x[4]=fx[1]; x[5]=fx[2];
  const float4* nw = (const float4*)(normW  + (size_t)p*64);
  const float4* nf = (const float4*)(normF2 + ((size_t)b*Nn + idx)*64);
  #pragma unroll
  for (int c=0;c<16;c++){
    float4 a = nw[c], q = nf[c];
    x[6+4*c+0]=a.x*q.x; x[6+4*c+1]=a.y*q.y; x[6+4*c+2]=a.z*q.z; x[6+4*c+3]=a.w*q.w;
  }
}

// Build the 10-channel stage-2 geometry row
__device__ __forceinline__ void build_x10(int row,
    const float* __restrict__ wxyz, const int* __restrict__ idx2, float* x){
  int p = row >> 4, b = p >> 12;
  int idx = idx2[row];
  const float* nw = wxyz + (size_t)p*3;
  const float* gw = wxyz + ((size_t)b*HWn + idx)*3;
  float n0=nw[0],n1=nw[1],n2=nw[2];
  float g0=gw[0],g1=gw[1],g2=gw[2];
  float d0=g0-n0, d1=g1-n1, d2=g2-n2;
  x[0]=n0;x[1]=n1;x[2]=n2; x[3]=g0;x[4]=g1;x[5]=g2;
  x[6]=d0;x[7]=d1;x[8]=d2; x[9]=sqrtf(d0*d0+d1*d1+d2*d2+1e-20f);
}

// ---------------- prep: norms, wxyz, weight transposes + f16 weights ----------------
__global__ __launch_bounds__(256) void k_prep(
    const float* __restrict__ warped_xyz, const float* __restrict__ lidar_z,
    const float* __restrict__ warped_points, const float* __restrict__ f2_points,
    const float* __restrict__ m1w0, const float* __restrict__ m1w1,
    const float* __restrict__ piw, const float* __restrict__ pcw,
    const float* __restrict__ m2w0, const float* __restrict__ m2w1,
    const float* __restrict__ m3w0, const float* __restrict__ m3w1,
    float* __restrict__ wxyz, float* __restrict__ normW, float* __restrict__ normF2,
    float* __restrict__ piwT, float* __restrict__ pcwT,
    _Float16* __restrict__ w1h, _Float16* __restrict__ w2h,
    _Float16* __restrict__ w3h, _Float16* __restrict__ w4h,
    _Float16* __restrict__ w5h, _Float16* __restrict__ w6h)
{
  int blk = blockIdx.x, tid = threadIdx.x;
  if (blk < 4096){
    int lane = tid & 63;
    int p = blk*4 + (tid >> 6);            // 0..16383
    const float* src; float* dst;
    if (p < Bn*HWn){ src = warped_points + (size_t)p*64; dst = normW + (size_t)p*64; }
    else { int q = p - Bn*HWn; src = f2_points + (size_t)q*64; dst = normF2 + (size_t)q*64; }
    float x = src[lane];
    float m = wred64(x) * (1.f/64.f);
    float d = x - m;
    float ss = wred64(d*d);
    float s = fmaxf(sqrtf(ss*(1.f/63.f)), 1e-12f);
    dst[lane] = d / s;
  } else if (blk < 4192){
    int e = (blk-4096)*256 + tid;          // < 24576
    wxyz[e] = warped_xyz[e] * lidar_z[e/3];
  } else if (blk < 4196){
    int e = (blk-4192)*256 + tid;          // < 1024
    if (e < 384){ piwT[(e & 63)*6  + (e >> 6)] = piw[e]; }
    else if (e < 1024){ int f = e-384; pcwT[(f & 63)*10 + (f >> 6)] = pcw[f]; }
  } else {
    int e = (blk-4196)*256 + tid;          // < 49152
    if (e < 12288){                        // w1h[j][k] : [128 out][96 in-pad]
      int j = e/96, k = e - j*96;
      w1h[e] = (k < 70) ? (_Float16)m1w0[k*128 + j] : (_Float16)0.f;
    } else if (e < 20480){                 // w2h[d][c] : [64][128]
      int f = e - 12288; int d = f >> 7, c = f & 127;
      w2h[f] = (_Float16)m1w1[c*64 + d];
    } else if (e < 28672){                 // w3h[d][c] : [64][128]
      int f = e - 20480; int d = f >> 7, c = f & 127;
      w3h[f] = (_Float16)m2w0[c*64 + d];
    } else if (e < 32768){                 // w4h[d][c] : [64][64]
      int f = e - 28672; int d = f >> 6, c = f & 63;
      w4h[f] = (_Float16)m2w1[c*64 + d];
    } else if (e < 45056){                 // w5h[d][c] : [64][192]
      int f = e - 32768; int d = f/192, c = f - 192*d;
      w5h[f] = (_Float16)m3w0[c*64 + d];
    } else {                               // w6h[d][c] : [64][64]
      int f = e - 45056; int d = f >> 6, c = f & 63;
      w6h[f] = (_Float16)m3w1[c*64 + d];
    }
  }
}

// ---------------- exact k-smallest via 8-bit radix select (parallel scan) ----------------
template<int K, bool WRITE_VALID>
__global__ __launch_bounds__(256) void k_knn(
    const float* __restrict__ qpts, const float* __restrict__ pts,
    int* __restrict__ oidx, float* __restrict__ ovalid)
{
  __shared__ unsigned int sd[Nn];
  __shared__ int hist[256];
  __shared__ int wsum[4];
  __shared__ unsigned int sh_prefix;
  __shared__ int sh_rem, cnt_lt, cnt_eq;
  int b = blockIdx.x >> 12;
  int qi = blockIdx.x & 4095;
  int tid = threadIdx.x;
  int lane = tid & 63, wv = tid >> 6;
  const float* qp = qpts + ((size_t)(b*HWn+qi))*3;
  float qx=qp[0], qy=qp[1], qz=qp[2];
  const float* pb = pts + (size_t)b*Nn*3;
  for (int t=tid; t<Nn; t+=256){
    float dx = __fsub_rn(qx, pb[t*3+0]);
    float dy = __fsub_rn(qy, pb[t*3+1]);
    float dz = __fsub_rn(qz, pb[t*3+2]);
    float d2 = __fadd_rn(__fadd_rn(__fmul_rn(dx,dx), __fmul_rn(dy,dy)), __fmul_rn(dz,dz));
    sd[t] = __float_as_uint(d2);
  }
  if (tid == 0){ cnt_lt = 0; cnt_eq = 0; }
  unsigned int prefix = 0; int rem = K;
  for (int shift = 24; shift >= 0; shift -= 8){
    __syncthreads();
    hist[tid] = 0;
    __syncthreads();
    unsigned int maskhi = (shift == 24) ? 0u : (0xFFFFFFFFu << (shift+8));
    for (int t=tid; t<Nn; t+=256){
      unsigned int v = sd[t];
      if ((v & maskhi) == prefix) atomicAdd(&hist[(v >> shift) & 255], 1);
    }
    __syncthreads();
    int h = hist[tid];
    int pref = h;
    #pragma unroll
    for (int m=1;m<64;m<<=1){ int t = __shfl_up(pref, m, 64); if (lane >= m) pref += t; }
    if (lane == 63) wsum[wv] = pref;
    __syncthreads();
    int off = 0;
    #pragma unroll
    for (int i=0;i<3;i++) if (i < wv) off += wsum[i];
    pref += off;
    if (pref >= rem && (pref - h) < rem){
      sh_prefix = prefix | ((unsigned int)tid << shift);
      sh_rem = rem - (pref - h);
    }
    __syncthreads();
    prefix = sh_prefix; rem = sh_rem;
  }
  unsigned int kth = prefix;
  int nless = K - rem;
  size_t obase = ((size_t)(b*HWn+qi))*K;
  const unsigned int U100 = __float_as_uint(100.0f);
  for (int t=tid; t<Nn; t+=256){
    unsigned int v = sd[t];
    if (v <= kth){
      int s;
      if (v < kth) s = atomicAdd(&cnt_lt, 1);
      else { s = atomicAdd(&cnt_eq, 1); if (s >= rem) continue; s += nless; }
      oidx[obase+s] = t;
      if constexpr (WRITE_VALID) ovalid[obase+s] = (v < U100) ? 1.f : 0.f;
    }
  }
}

// ---------------- build f16 X1 rows: [wxyz(3) f2xyz(3) prod(64) pad->96] ----------------
__global__ __launch_bounds__(256) void k_buildX1(
    const float* __restrict__ wxyz, const float* __restrict__ f2_xyz,
    const float* __restrict__ normW, const float* __restrict__ normF2,
    const int* __restrict__ idxq, _Float16* __restrict__ X1)
{
  int row = blockIdx.x*256 + threadIdx.x;
  float x[70];
  build_x70(row, wxyz, f2_xyz, normW, normF2, idxq, x);
  unsigned int* d32 = (unsigned int*)(X1 + (size_t)row*96);
  union { unsigned int u; _Float16 h[2]; } pk;
  #pragma unroll
  for (int c=0;c<35;c++){
    pk.h[0] = (_Float16)x[2*c]; pk.h[1] = (_Float16)x[2*c+1];
    d32[c] = pk.u;
  }
  #pragma unroll
  for (int c=35;c<48;c++) d32[c] = 0u;
}

// ---------------- Gram-matrix stats for pi_enc (7x7) and pc_enc (11x11) ----------------
__global__ __launch_bounds__(256) void k_gram(
    const float* __restrict__ wxyz, const float* __restrict__ f2_xyz,
    const int* __restrict__ idxq, const int* __restrict__ idx2,
    float* __restrict__ gram)
{
  __shared__ float sacc[66];
  int blk = blockIdx.x, tid = threadIdx.x, lane = tid & 63;
  if (blk < 64){
    float a[28];
    #pragma unroll
    for (int q=0;q<28;q++) a[q]=0.f;
    int g = blk*256 + tid;
    for (int s=0;s<16;s++){
      int row = g + s*16384;
      int p = row >> 5, b = p >> 12;
      int idx = idxq[row];
      const float* wx = wxyz + (size_t)p*3;
      const float* fx = f2_xyz + ((size_t)b*Nn + idx)*3;
      float xt[7] = {wx[0],wx[1],wx[2],fx[0],fx[1],fx[2],1.f};
      int q=0;
      #pragma unroll
      for (int i=0;i<7;i++)
        #pragma unroll
        for (int j=i;j<7;j++) a[q++] += xt[i]*xt[j];
    }
    if (tid < 28) sacc[tid]=0.f;
    __syncthreads();
    #pragma unroll
    for (int q=0;q<28;q++){
      float v = wred64(a[q]);
      if (lane==0) atomicAdd(&sacc[q], v);
    }
    __syncthreads();
    if (tid < 28) atomicAdd(&gram[tid], sacc[tid]);
  } else {
    float a[66];
    #pragma unroll
    for (int q=0;q<66;q++) a[q]=0.f;
    int g = (blk-64)*256 + tid;
    for (int s=0;s<16;s++){
      int row = g + s*8192;
      float x[10];
      build_x10(row, wxyz, idx2, x);
      float xt[11] = {x[0],x[1],x[2],x[3],x[4],x[5],x[6],x[7],x[8],x[9],1.f};
      int q=0;
      #pragma unroll
      for (int i=0;i<11;i++)
        #pragma unroll
        for (int j=i;j<11;j++) a[q++] += xt[i]*xt[j];
    }
    if (tid < 66) sacc[tid]=0.f;
    __syncthreads();
    #pragma unroll
    for (int q=0;q<66;q++){
      float v = wred64(a[q]);
      if (lane==0) atomicAdd(&sacc[q], v);
    }
    __syncthreads();
    if (tid < 66) atomicAdd(&gram[32+tid], sacc[tid]);
  }
}

__global__ __launch_bounds__(128) void k_gram_fin(
    const float* __restrict__ gram,
    const float* __restrict__ piw, const float* __restrict__ pib,
    const float* __restrict__ pcw, const float* __restrict__ pcb,
    float* stats)
{
  int tid = threadIdx.x;
  if (tid < 64){
    int c = tid;
    float wt[7];
    #pragma unroll
    for (int i=0;i<6;i++) wt[i] = piw[i*64+c];
    wt[6] = pib[c];
    const float* G = gram;
    float sum=0.f, ssq=0.f;
    #pragma unroll
    for (int i=0;i<7;i++){
      int offi = i*7 - (i*(i-1))/2;
      sum += wt[i]*G[offi + (6-i)];
      #pragma unroll
      for (int j=0;j<7;j++){
        int ii = i<j? i : j, jj = i<j? j : i;
        int o = ii*7 - (ii*(ii-1))/2 + (jj-ii);
        ssq += wt[i]*wt[j]*G[o];
      }
    }
    stats[2*256+c] = sum; stats[2*256+128+c] = ssq;
  } else {
    int c = tid-64;
    float wt[11];
    #pragma unroll
    for (int i=0;i<10;i++) wt[i] = pcw[i*64+c];
    wt[10] = pcb[c];
    const float* G = gram + 32;
    float sum=0.f, ssq=0.f;
    #pragma unroll
    for (int i=0;i<11;i++){
      int offi = i*11 - (i*(i-1))/2;
      sum += wt[i]*G[offi + (10-i)];
      #pragma unroll
      for (int j=0;j<11;j++){
        int ii = i<j? i : j, jj = i<j? j : i;
        int o = ii*11 - (ii*(ii-1))/2 + (jj-ii);
        ssq += wt[i]*wt[j]*G[o];
      }
    }
    stats[5*256+c] = sum; stats[5*256+128+c] = ssq;
  }
}

// ---------------- MFMA y1 stats (bias dropped: BN is shift-invariant) ----------------
__global__ __launch_bounds__(256) void k_mfma_stats1(
    const _Float16* __restrict__ X1, const _Float16* __restrict__ w1h,
    float* stats)
{
  __shared__ _Float16 sw[128*104];
  __shared__ float ssum[128], sssq[128];
  int tid = threadIdx.x;
  const unsigned int* wsrc = (const unsigned int*)w1h;
  for (int d = tid; d < 6144; d += 256){
    int row = d/48, col = d - row*48;
    ((unsigned int*)sw)[row*52 + col] = wsrc[d];
  }
  if (tid < 128){ ssum[tid]=0.f; sssq[tid]=0.f; }
  __syncthreads();
  int wave = tid >> 6, lane = tid & 63;
  int quad = lane >> 4, n16 = lane & 15;
  int m0 = blockIdx.x*64 + wave*16;
  const _Float16* xr = X1 + (size_t)(m0 + n16)*96 + quad*8;
  f16x8 a0 = *(const f16x8*)(xr);
  f16x8 a1 = *(const f16x8*)(xr + 32);
  f16x8 a2 = *(const f16x8*)(xr + 64);
  for (int nt = 0; nt < 8; nt++){
    const _Float16* wr = sw + (size_t)(nt*16 + n16)*104 + quad*8;
    f16x8 b0 = *(const f16x8*)(wr);
    f16x8 b1 = *(const f16x8*)(wr + 32);
    f16x8 b2 = *(const f16x8*)(wr + 64);
    f32x4 acc = {0.f,0.f,0.f,0.f};
    acc = __builtin_amdgcn_mfma_f32_16x16x32_f16(a0, b0, acc, 0,0,0);
    acc = __builtin_amdgcn_mfma_f32_16x16x32_f16(a1, b1, acc, 0,0,0);
    acc = __builtin_amdgcn_mfma_f32_16x16x32_f16(a2, b2, acc, 0,0,0);
    float s1 = acc[0]+acc[1]+acc[2]+acc[3];
    float s2 = acc[0]*acc[0]+acc[1]*acc[1]+acc[2]*acc[2]+acc[3]*acc[3];
    s1 += __shfl_xor(s1, 16, 64); s1 += __shfl_xor(s1, 32, 64);
    s2 += __shfl_xor(s2, 16, 64); s2 += __shfl_xor(s2, 32, 64);
    if (quad == 0){ atomicAdd(&ssum[nt*16+n16], s1); atomicAdd(&sssq[nt*16+n16], s2); }
  }
  __syncthreads();
  if (tid < 128){ atomicAdd(&stats[tid], ssum[tid]); atomicAdd(&stats[128+tid], sssq[tid]); }
}

// ---------------- MFMA m1: y1 -> BN/leaky -> t (LDS) -> x W2 -> y2 (f16) + stats ----------------
__global__ __launch_bounds__(256) void k_mfma_m1(
    const _Float16* __restrict__ X1, const _Float16* __restrict__ w1h,
    const _Float16* __restrict__ w2h,
    const float* __restrict__ m1g0, const float* __restrict__ m1e0,
    float* stats, _Float16* __restrict__ y2h)
{
  __shared__ _Float16 sw[128*104];
  __shared__ _Float16 sw2[64*136];
  __shared__ _Float16 st[64*136];
  __shared__ float sc1[128], sh1[128], ssum[64], sssq[64];
  int tid = threadIdx.x;
  const unsigned int* wsrc = (const unsigned int*)w1h;
  for (int d = tid; d < 6144; d += 256){
    int row = d/48, col = d - row*48;
    ((unsigned int*)sw)[row*52 + col] = wsrc[d];
  }
  const unsigned int* w2src = (const unsigned int*)w2h;
  for (int d = tid; d < 4096; d += 256){
    int row = d >> 6, col = d & 63;
    ((unsigned int*)sw2)[row*68 + col] = w2src[d];
  }
  if (tid < 128){
    float s,h; bn_param(stats, tid, INV_R1, m1g0, m1e0, s, h);
    sc1[tid]=s; sh1[tid]=h;
  }
  if (tid < 64){ ssum[tid]=0.f; sssq[tid]=0.f; }
  __syncthreads();
  int wave = tid >> 6, lane = tid & 63;
  int quad = lane >> 4, n16 = lane & 15;
  int m0 = blockIdx.x*64 + wave*16;
  const _Float16* xr = X1 + (size_t)(m0 + n16)*96 + quad*8;
  f16x8 a0 = *(const f16x8*)(xr);
  f16x8 a1 = *(const f16x8*)(xr + 32);
  f16x8 a2 = *(const f16x8*)(xr + 64);
  for (int nt = 0; nt < 8; nt++){
    const _Float16* wr = sw + (size_t)(nt*16 + n16)*104 + quad*8;
    f16x8 b0 = *(const f16x8*)(wr);
    f16x8 b1 = *(const f16x8*)(wr + 32);
    f16x8 b2 = *(const f16x8*)(wr + 64);
    f32x4 acc = {0.f,0.f,0.f,0.f};
    acc = __builtin_amdgcn_mfma_f32_16x16x32_f16(a0, b0, acc, 0,0,0);
    acc = __builtin_amdgcn_mfma_f32_16x16x32_f16(a1, b1, acc, 0,0,0);
    acc = __builtin_amdgcn_mfma_f32_16x16x32_f16(a2, b2, acc, 0,0,0);
    int ch = nt*16 + n16;
    float sc = sc1[ch], sh = sh1[ch];
    #pragma unroll
    for (int r=0;r<4;r++){
      float v = leakyf(acc[r]*sc + sh);
      st[(size_t)(wave*16 + quad*4 + r)*136 + ch] = (_Float16)v;
    }
  }
  __syncthreads();
  const _Float16* tr = st + (size_t)(wave*16 + n16)*136 + quad*8;
  f16x8 t0 = *(const f16x8*)(tr);
  f16x8 t1 = *(const f16x8*)(tr + 32);
  f16x8 t2 = *(const f16x8*)(tr + 64);
  f16x8 t3 = *(const f16x8*)(tr + 96);
  for (int nt = 0; nt < 4; nt++){
    const _Float16* wr = sw2 + (size_t)(nt*16 + n16)*136 + quad*8;
    f16x8 b0 = *(const f16x8*)(wr);
    f16x8 b1 = *(const f16x8*)(wr + 32);
    f16x8 b2 = *(const f16x8*)(wr + 64);
    f16x8 b3 = *(const f16x8*)(wr + 96);
    f32x4 acc = {0.f,0.f,0.f,0.f};
    acc = __builtin_amdgcn_mfma_f32_16x16x32_f16(t0, b0, acc, 0,0,0);
    acc = __builtin_amdgcn_mfma_f32_16x16x32_f16(t1, b1, acc, 0,0,0);
    acc = __builtin_amdgcn_mfma_f32_16x16x32_f16(t2, b2, acc, 0,0,0);
    acc = __builtin_amdgcn_mfma_f32_16x16x32_f16(t3, b3, acc, 0,0,0);
    int ch = nt*16 + n16;
    #pragma unroll
    for (int r=0;r<4;r++){
      int rowg = blockIdx.x*64 + wave*16 + quad*4 + r;
      y2h[(size_t)rowg*64 + ch] = (_Float16)acc[r];
    }
    float s1 = acc[0]+acc[1]+acc[2]+acc[3];
    float s2 = acc[0]*acc[0]+acc[1]*acc[1]+acc[2]*acc[2]+acc[3]*acc[3];
    s1 += __shfl_xor(s1, 16, 64); s1 += __shfl_xor(s1, 32, 64);
    s2 += __shfl_xor(s2, 16, 64); s2 += __shfl_xor(s2, 32, 64);
    if (quad == 0){ atomicAdd(&ssum[ch], s1); atomicAdd(&sssq[ch], s2); }
  }
  __syncthreads();
  if (tid < 64){ atomicAdd(&stats[1*256+tid], ssum[tid]); atomicAdd(&stats[1*256+128+tid], sssq[tid]); }
}

// ---------------- MFMA m2a: build u=[pi_enc|feat] in LDS, y3 = u x W3 (K=128) ----------------
__global__ __launch_bounds__(256) void k_mfma_m2a(
    const float* __restrict__ wxyz, const float* __restrict__ f2_xyz,
    const int* __restrict__ idxq,
    const float* __restrict__ piwT, const float* __restrict__ pib,
    const float* __restrict__ pig, const float* __restrict__ pie,
    const float* __restrict__ m1g1, const float* __restrict__ m1e1,
    const _Float16* __restrict__ y2h, const _Float16* __restrict__ w3h,
    float* stats, _Float16* __restrict__ y3h)
{
  __shared__ _Float16 su[64*136];
  __shared__ _Float16 sw3[64*136];
  __shared__ float spw[384];
  __shared__ float scp[64], shp[64], sc2[64], sh2[64], ssum[64], sssq[64];
  int tid = threadIdx.x;
  const unsigned int* w3src = (const unsigned int*)w3h;
  for (int d = tid; d < 4096; d += 256){
    int row = d >> 6, col = d & 63;
    ((unsigned int*)sw3)[row*68 + col] = w3src[d];
  }
  for (int d = tid; d < 384; d += 256) spw[d] = piwT[d];
  if (tid < 64){
    float s,h;
    bn_param(stats+2*256, tid, INV_R1, pig,  pie,  s, h); scp[tid]=s; shp[tid]=h;
    bn_param(stats+1*256, tid, INV_R1, m1g1, m1e1, s, h); sc2[tid]=s; sh2[tid]=h;
    ssum[tid]=0.f; sssq[tid]=0.f;
  }
  __syncthreads();
  int r = tid & 63, cg = tid >> 6;
  int rowg = blockIdx.x*64 + r;
  {
    int p = rowg >> 5, b = p >> 12;
    int idx = idxq[rowg];
    const float* wx = wxyz + (size_t)p*3;
    const float* fx = f2_xyz + ((size_t)b*Nn + idx)*3;
    float x0=wx[0],x1=wx[1],x2=wx[2],x3=fx[0],x4=fx[1],x5=fx[2];
    #pragma unroll
    for (int jj=0;jj<16;jj++){
      int j = cg*16 + jj;
      const float* pw = spw + j*6;
      float e = pib[j] + x0*pw[0]+x1*pw[1]+x2*pw[2]+x3*pw[3]+x4*pw[4]+x5*pw[5];
      su[r*136 + j] = (_Float16)leakyf(e*scp[j] + shp[j]);
    }
    const f16x8* yr = (const f16x8*)(y2h + (size_t)rowg*64 + cg*16);
    f16x8 q0 = yr[0], q1 = yr[1];
    #pragma unroll
    for (int jj=0;jj<8;jj++){
      int c = cg*16 + jj;
      su[r*136 + 64 + c] = (_Float16)leakyf((float)q0[jj]*sc2[c] + sh2[c]);
    }
    #pragma unroll
    for (int jj=0;jj<8;jj++){
      int c = cg*16 + 8 + jj;
      su[r*136 + 64 + c] = (_Float16)leakyf((float)q1[jj]*sc2[c] + sh2[c]);
    }
  }
  __syncthreads();
  int wave = tid >> 6, lane = tid & 63, quad = lane >> 4, n16 = lane & 15;
  const _Float16* ur = su + (size_t)(wave*16 + n16)*136 + quad*8;
  f16x8 a0 = *(const f16x8*)(ur);
  f16x8 a1 = *(const f16x8*)(ur + 32);
  f16x8 a2 = *(const f16x8*)(ur + 64);
  f16x8 a3 = *(const f16x8*)(ur + 96);
  for (int nt = 0; nt < 4; nt++){
    const _Float16* wr = sw3 + (size_t)(nt*16 + n16)*136 + quad*8;
    f16x8 b0 = *(const f16x8*)(wr);
    f16x8 b1 = *(const f16x8*)(wr + 32);
    f16x8 b2 = *(const f16x8*)(wr + 64);
    f16x8 b3 = *(const f16x8*)(wr + 96);
    f32x4 acc = {0.f,0.f,0.f,0.f};
    acc = __builtin_amdgcn_mfma_f32_16x16x32_f16(a0, b0, acc, 0,0,0);
    acc = __builtin_amdgcn_mfma_f32_16x16x32_f16(a1, b1, acc, 0,0,0);
    acc = __builtin_amdgcn_mfma_f32_16x16x32_f16(a2, b2, acc, 0,0,0);
    acc = __builtin_amdgcn_mfma_f32_16x16x32_f16(a3, b3, acc, 0,0,0);
    int ch = nt*16 + n16;
    #pragma unroll
    for (int rr=0;rr<4;rr++){
      int rg = blockIdx.x*64 + wave*16 + quad*4 + rr;
      y3h[(size_t)rg*64 + ch] = (_Float16)acc[rr];
    }
    float s1 = acc[0]+acc[1]+acc[2]+acc[3];
    float s2 = acc[0]*acc[0]+acc[1]*acc[1]+acc[2]*acc[2]+acc[3]*acc[3];
    s1 += __shfl_xor(s1, 16, 64); s1 += __shfl_xor(s1, 32, 64);
    s2 += __shfl_xor(s2, 16, 64); s2 += __shfl_xor(s2, 32, 64);
    if (quad == 0){ atomicAdd(&ssum[ch], s1); atomicAdd(&sssq[ch], s2); }
  }
  __syncthreads();
  if (tid < 64){ atomicAdd(&stats[3*256+tid], ssum[tid]); atomicAdd(&stats[3*256+128+tid], sssq[tid]); }
}

// ---------------- generic MFMA pointwise 64->64: t=act(bn(yin)), yout = t x W (K=64) ----------------
__global__ __launch_bounds__(256) void k_mfma_pw64(
    const _Float16* __restrict__ yin, const _Float16* __restrict__ wh,
    const float* __restrict__ g, const float* __restrict__ e,
    const float* statsIn, float* statsOut, float inv_n,
    _Float16* __restrict__ yout)
{
  __shared__ _Float16 stt[64*72];
  __shared__ _Float16 sw[64*72];
  __shared__ float sc[64], sh[64], ssum[64], sssq[64];
  int tid = threadIdx.x;
  const unsigned int* wsrc = (const unsigned int*)wh;
  for (int d = tid; d < 2048; d += 256){
    int row = d >> 5, col = d & 31;
    ((unsigned int*)sw)[row*36 + col] = wsrc[d];
  }
  if (tid < 64){
    float s,h; bn_param(statsIn, tid, inv_n, g, e, s, h);
    sc[tid]=s; sh[tid]=h; ssum[tid]=0.f; sssq[tid]=0.f;
  }
  __syncthreads();
  int r = tid & 63, cg = tid >> 6;
  int rowg = blockIdx.x*64 + r;
  const f16x8* yr = (const f16x8*)(yin + (size_t)rowg*64 + cg*16);
  f16x8 q0 = yr[0], q1 = yr[1];
  #pragma unroll
  for (int jj=0;jj<8;jj++){
    int c = cg*16 + jj;
    stt[r*72 + c] = (_Float16)leakyf((float)q0[jj]*sc[c] + sh[c]);
  }
  #pragma unroll
  for (int jj=0;jj<8;jj++){
    int c = cg*16 + 8 + jj;
    stt[r*72 + c] = (_Float16)leakyf((float)q1[jj]*sc[c] + sh[c]);
  }
  __syncthreads();
  int wave = tid >> 6, lane = tid & 63, quad = lane >> 4, n16 = lane & 15;
  const _Float16* tr = stt + (size_t)(wave*16 + n16)*72 + quad*8;
  f16x8 a0 = *(const f16x8*)(tr);
  f16x8 a1 = *(const f16x8*)(tr + 32);
  for (int nt = 0; nt < 4; nt++){
    const _Float16* wr = sw + (size_t)(nt*16 + n16)*72 + quad*8;
    f16x8 b0 = *(const f16x8*)(wr);
    f16x8 b1 = *(const f16x8*)(wr + 32);
    f32x4 acc = {0.f,0.f,0.f,0.f};
    acc = __builtin_amdgcn_mfma_f32_16x16x32_f16(a0, b0, acc, 0,0,0);
    acc = __builtin_amdgcn_mfma_f32_16x16x32_f16(a1, b1, acc, 0,0,0);
    int ch = nt*16 + n16;
    #pragma unroll
    for (int rr=0;rr<4;rr++){
      int rg = blockIdx.x*64 + wave*16 + quad*4 + rr;
      yout[(size_t)rg*64 + ch] = (_Float16)acc[rr];
    }
    float s1 = acc[0]+acc[1]+acc[2]+acc[3];
    float s2 = acc[0]*acc[0]+acc[1]*acc[1]+acc[2]*acc[2]+acc[3]*acc[3];
    s1 += __shfl_xor(s1, 16, 64); s1 += __shfl_xor(s1, 32, 64);
    s2 += __shfl_xor(s2, 16, 64); s2 += __shfl_xor(s2, 32, 64);
    if (quad == 0){ atomicAdd(&ssum[ch], s1); atomicAdd(&sssq[ch], s2); }
  }
  __syncthreads();
  if (tid < 64){ atomicAdd(&statsOut[tid], ssum[tid]); atomicAdd(&statsOut[128+tid], sssq[tid]); }
}

// ---------------- MFMA m3a: build v=[pc_enc|wp|pif1_g] (192ch), y5 = v x W5 ----------------
__global__ __launch_bounds__(256) void k_mfma_m3a(
    const float* __restrict__ wxyz, const float* __restrict__ warped_points,
    const _Float16* __restrict__ pif1h, const int* __restrict__ idx2,
    const float* __restrict__ pcwT, const float* __restrict__ pcb,
    const float* __restrict__ pcg, const float* __restrict__ pce,
    const _Float16* __restrict__ w5h,
    float* stats, _Float16* __restrict__ y5h)
{
  __shared__ _Float16 sv[64*200];
  __shared__ _Float16 sw5[64*200];
  __shared__ float spw[640];
  __shared__ float scp[64], shp[64], ssum[64], sssq[64];
  int tid = threadIdx.x;
  const unsigned int* w5src = (const unsigned int*)w5h;
  for (int d = tid; d < 6144; d += 256){
    int row = d/96, col = d - row*96;
    ((unsigned int*)sw5)[row*100 + col] = w5src[d];
  }
  for (int d = tid; d < 640; d += 256) spw[d] = pcwT[d];
  if (tid < 64){
    float s,h; bn_param(stats+5*256, tid, INV_R2, pcg, pce, s, h);
    scp[tid]=s; shp[tid]=h; ssum[tid]=0.f; sssq[tid]=0.f;
  }
  __syncthreads();
  int r = tid & 63, cg = tid >> 6;
  int rowg = blockIdx.x*64 + r;
  {
    int p = rowg >> 4, b = p >> 12;
    int idx = idx2[rowg];
    float x[10];
    build_x10(rowg, wxyz, idx2, x);
    #pragma unroll
    for (int jj=0;jj<16;jj++){
      int j = cg*16 + jj;
      const float* pw = spw + j*10;
      float e = pcb[j];
      #pragma unroll
      for (int i=0;i<10;i++) e += x[i]*pw[i];
      sv[r*200 + j] = (_Float16)leakyf(e*scp[j] + shp[j]);
    }
    const float4* wp = (const float4*)(warped_points + (size_t)p*64 + cg*16);
    #pragma unroll
    for (int v4=0; v4<4; v4++){
      float4 q = wp[v4];
      int c = 64 + cg*16 + v4*4;
      sv[r*200 + c + 0] = (_Float16)q.x;
      sv[r*200 + c + 1] = (_Float16)q.y;
      sv[r*200 + c + 2] = (_Float16)q.z;
      sv[r*200 + c + 3] = (_Float16)q.w;
    }
    const f16x8* pg = (const f16x8*)(pif1h + ((size_t)(b*HWn) + idx)*64 + cg*16);
    f16x8 g0 = pg[0], g1 = pg[1];
    #pragma unroll
    for (int jj=0;jj<8;jj++) sv[r*200 + 128 + cg*16 + jj] = g0[jj];
    #pragma unroll
    for (int jj=0;jj<8;jj++) sv[r*200 + 136 + cg*16 + jj] = g1[jj];
  }
  __syncthreads();
  int wave = tid >> 6, lane = tid & 63, quad = lane >> 4, n16 = lane & 15;
  const _Float16* vr = sv + (size_t)(wave*16 + n16)*200 + quad*8;
  f16x8 a0 = *(const f16x8*)(vr);
  f16x8 a1 = *(const f16x8*)(vr + 32);
  f16x8 a2 = *(const f16x8*)(vr + 64);
  f16x8 a3 = *(const f16x8*)(vr + 96);
  f16x8 a4 = *(const f16x8*)(vr + 128);
  f16x8 a5 = *(const f16x8*)(vr + 160);
  for (int nt = 0; nt < 4; nt++){
    const _Float16* wr = sw5 + (size_t)(nt*16 + n16)*200 + quad*8;
    f32x4 acc = {0.f,0.f,0.f,0.f};
    acc = __builtin_amdgcn_mfma_f32_16x16x32_f16(a0, *(const f16x8*)(wr),       acc, 0,0,0);
    acc = __builtin_amdgcn_mfma_f32_16x16x32_f16(a1, *(const f16x8*)(wr + 32),  acc, 0,0,0);
    acc = __builtin_amdgcn_mfma_f32_16x16x32_f16(a2, *(const f16x8*)(wr + 64),  acc, 0,0,0);
    acc = __builtin_amdgcn_mfma_f32_16x16x32_f16(a3, *(const f16x8*)(wr + 96),  acc, 0,0,0);
    acc = __builtin_amdgcn_mfma_f32_16x16x32_f16(a4, *(const f16x8*)(wr + 128), acc, 0,0,0);
    acc = __builtin_amdgcn_mfma_f32_16x16x32_f16(a5, *(const f16x8*)(wr + 160), acc, 0,0,0);
    int ch = nt*16 + n16;
    #pragma unroll
    for (int rr=0;rr<4;rr++){
      int rg = blockIdx.x*64 + wave*16 + quad*4 + rr;
      y5h[(size_t)rg*64 + ch] = (_Float16)acc[rr];
    }
    float s1 = acc[0]+acc[1]+acc[2]+acc[3];
    float s2 = acc[0]*acc[0]+acc[1]*acc[1]+acc[2]*acc[2]+acc[3]*acc[3];
    s1 += __shfl_xor(s1, 16, 64); s1 += __shfl_xor(s1, 32, 64);
    s2 += __shfl_xor(s2, 16, 64); s2 += __shfl_xor(s2, 32, 64);
    if (quad == 0){ atomicAdd(&ssum[ch], s1); atomicAdd(&sssq[ch], s2); }
  }
  __syncthreads();
  if (tid < 64){ atomicAdd(&stats[6*256+tid], ssum[tid]); atomicAdd(&stats[6*256+128+tid], sssq[tid]); }
}

// ---------------- stage-1 softmax over KQ, weighted sum of feat -> pif1 (f16) ----------------
__global__ __launch_bounds__(256) void k_softmax1(
    const _Float16* __restrict__ y2h, const _Float16* __restrict__ y4h,
    const float* stats,
    const float* __restrict__ m1g1, const float* __restrict__ m1e1,
    const float* __restrict__ m2g1, const float* __restrict__ m2e1,
    _Float16* __restrict__ pif1h)
{
  int tid = threadIdx.x, lane = tid & 63;
  int p = blockIdx.x*4 + (tid >> 6);
  int d = lane;
  float sc2,sh2,sc4,sh4;
  bn_param(stats+1*256, d, INV_R1, m1g1, m1e1, sc2, sh2);
  bn_param(stats+4*256, d, INV_R1, m2g1, m2e1, sc4, sh4);
  size_t rb = (size_t)p*KQn;
  float v[32]; float mx = -1e30f;
  #pragma unroll
  for (int k=0;k<32;k++){
    float t = leakyf((float)y4h[(rb+k)*64 + d]*sc4 + sh4);
    v[k] = t; mx = fmaxf(mx, t);
  }
  float se = 0.f;
  #pragma unroll
  for (int k=0;k<32;k++){ float ev = __expf(v[k]-mx); v[k]=ev; se += ev; }
  float inv = 1.f/se, acc = 0.f;
  #pragma unroll
  for (int k=0;k<32;k++){
    float f = leakyf((float)y2h[(rb+k)*64 + d]*sc2 + sh2);
    acc += v[k]*f;
  }
  pif1h[(size_t)p*64 + d] = (_Float16)(acc*inv);
}

// ---------------- stage-2 masked softmax over KN, weighted sum of gathered pif1 ----------------
__global__ __launch_bounds__(256) void k_softmax2(
    const _Float16* __restrict__ y6h, const _Float16* __restrict__ pif1h,
    const int* __restrict__ idx2, const float* __restrict__ validf,
    const float* stats,
    const float* __restrict__ m3g1, const float* __restrict__ m3e1,
    float* __restrict__ out)
{
  int tid = threadIdx.x, lane = tid & 63;
  int p = blockIdx.x*4 + (tid >> 6);
  int b = p >> 12;
  int d = lane;
  float sc,sh; bn_param(stats+7*256, d, INV_R2, m3g1, m3e1, sc, sh);
  size_t rb = (size_t)p*KNn;
  float v[16]; float mx = -1e30f;
  #pragma unroll
  for (int k=0;k<16;k++){
    float t = leakyf((float)y6h[(rb+k)*64 + d]*sc + sh);
    t = (validf[rb+k] > 0.5f) ? t : -1e10f;
    v[k] = t; mx = fmaxf(mx, t);
  }
  float se = 0.f;
  #pragma unroll
  for (int k=0;k<16;k++){ float ev = __expf(v[k]-mx); v[k]=ev; se += ev; }
  float inv = 1.f/se, acc = 0.f;
  #pragma unroll
  for (int k=0;k<16;k++){
    int idx = idx2[rb+k];
    acc += v[k]*(float)pif1h[((size_t)(b*HWn) + idx)*64 + d];
  }
  out[(size_t)p*64 + d] = acc*inv;
}

// ---------------- launcher ----------------
extern "C" void kernel_launch(void* const* d_in, const int* in_sizes, int n_in,
                              void* d_out, int out_size, void* d_ws, size_t ws_size,
                              hipStream_t stream)
{
  (void)in_sizes; (void)n_in; (void)out_size; (void)ws_size;
  const float* xyz_proj      = (const float*)d_in[0];
  const float* warped_xyz    = (const float*)d_in[1];
  const float* warped_points = (const float*)d_in[2];
  const float* f2_xyz        = (const float*)d_in[4];
  const float* f2_points     = (const float*)d_in[5];
  const float* lidar_z       = (const float*)d_in[6];
  const float* m1w0=(const float*)d_in[7],  *m1g0=(const float*)d_in[9],  *m1e0=(const float*)d_in[10];
  const float* m1w1=(const float*)d_in[11], *m1g1=(const float*)d_in[13], *m1e1=(const float*)d_in[14];
  const float* piw =(const float*)d_in[15], *pib =(const float*)d_in[16], *pig =(const float*)d_in[17], *pie =(const float*)d_in[18];
  const float* m2w0=(const float*)d_in[19], *m2g0=(const float*)d_in[21], *m2e0=(const float*)d_in[22];
  const float* m2w1=(const float*)d_in[23], *m2g1=(const float*)d_in[25], *m2e1=(const float*)d_in[26];
  const float* pcw =(const float*)d_in[27], *pcb =(const float*)d_in[28], *pcg =(const float*)d_in[29], *pce =(const float*)d_in[30];
  const float* m3w0=(const float*)d_in[31], *m3g0=(const float*)d_in[33], *m3e0=(const float*)d_in[34];
  const float* m3w1=(const float*)d_in[35], *m3g1=(const float*)d_in[37], *m3e1=(const float*)d_in[38];
  float* out = (float*)d_out;

  float* ws     = (float*)d_ws;
  float* wxyz   = ws;                        // 24576
  float* normW  = wxyz   + 24576;            // 524288
  float* normF2 = normW  + 524288;           // 524288
  float* piwT   = normF2 + 524288;           // 384
  float* pcwT   = piwT   + 384;              // 640
  float* stats  = pcwT   + 640;              // 2048
  float* gram   = stats  + 2048;             // 128
  int*   idxq   = (int*)(gram + 128);        // 262144
  int*   idx2   = idxq   + 262144;           // 131072
  float* validf = (float*)(idx2 + 131072);   // 131072
  _Float16* pif1h = (_Float16*)(validf + 131072);   // 1048576 f16 = 524288 floats
  float* X1f    = validf + 131072 + 524288;
  _Float16* X1  = (_Float16*)X1f;            // 25165824 f16 = 12582912 floats
  float* y2f    = X1f + 12582912;
  _Float16* y2h = (_Float16*)y2f;            // 16777216 f16 = 8388608 floats
  float* y3f    = y2f + 8388608;
  _Float16* y3h = (_Float16*)y3f;            // 8388608 floats
  float* whb    = y3f + 8388608;             // f16 weights: 49152 f16 = 24576 floats
  _Float16* w1h = (_Float16*)whb;            // 12288
  _Float16* w2h = w1h + 12288;               // 8192
  _Float16* w3h = w2h + 8192;                // 8192
  _Float16* w4h = w3h + 8192;                // 4096
  _Float16* w5h = w4h + 4096;                // 12288
  _Float16* w6h = w5h + 12288;               // 4096
  // aliases (regions dead by the time they're overwritten):
  _Float16* y4h = (_Float16*)X1f;            // X1 dead after k_mfma_m1
  _Float16* y5h = (_Float16*)(X1f + 8388608);
  _Float16* y6h = y3h;                       // y3 dead after first k_mfma_pw64
  // total ~126 MB

  hipMemsetAsync(stats, 0, (2048+128)*sizeof(float), stream);
  k_prep<<<4388,256,0,stream>>>(warped_xyz, lidar_z, warped_points, f2_points,
                                m1w0, m1w1, piw, pcw, m2w0, m2w1, m3w0, m3w1,
                                wxyz, normW, normF2, piwT, pcwT,
                                w1h, w2h, w3h, w4h, w5h, w6h);
  k_knn<32,false><<<8192,256,0,stream>>>(warped_xyz, f2_xyz, idxq, nullptr);
  k_knn<16,true ><<<8192,256,0,stream>>>(xyz_proj, xyz_proj, idx2, validf);
  k_buildX1<<<1024,256,0,stream>>>(wxyz, f2_xyz, normW, normF2, idxq, X1);
  k_gram<<<96,256,0,stream>>>(wxyz, f2_xyz, idxq, idx2, gram);
  k_gram_fin<<<1,128,0,stream>>>(gram, piw, pib, pcw, pcb, stats);
  k_mfma_stats1<<<4096,256,0,stream>>>(X1, w1h, stats);
  k_mfma_m1<<<4096,256,0,stream>>>(X1, w1h, w2h, m1g0, m1e0, stats, y2h);
  k_mfma_m2a<<<4096,256,0,stream>>>(wxyz, f2_xyz, idxq, piwT, pib, pig, pie,
                                    m1g1, m1e1, y2h, w3h, stats, y3h);
  k_mfma_pw64<<<4096,256,0,stream>>>(y3h, w4h, m2g0, m2e0,
                                     stats+3*256, stats+4*256, INV_R1, y4h);
  k_softmax1<<<2048,256,0,stream>>>(y2h, y4h, stats, m1g1, m1e1, m2g1, m2e1, pif1h);
  k_mfma_m3a<<<2048,256,0,stream>>>(wxyz, warped_points, pif1h, idx2,
                                    pcwT, pcb, pcg, pce, w5h, stats, y5h);
  k_mfma_pw64<<<2048,256,0,stream>>>(y5h, w6h, m3g0, m3e0,
                                     stats+6*256, stats+7*256, INV_R2, y6h);
  k_softmax2<<<2048,256,0,stream>>>(y6h, pif1h, idx2, validf, stats, m3g1, m3e1, out);
}

// Round 5
// 667.462 us; speedup vs baseline: 2.3241x; 1.4718x over previous
//
#include <hip/hip_runtime.h>
#include <math.h>

// ---------------- problem constants ----------------
constexpr int Bn  = 2;
constexpr int HWn = 4096;     // H*W
constexpr int Nn  = 4096;
constexpr int KQn = 32;
constexpr int KNn = 16;
constexpr float INV_R1 = 1.0f/262144.0f;   // exact pow2
constexpr float INV_R2 = 1.0f/131072.0f;   // exact pow2

typedef _Float16 f16x8 __attribute__((ext_vector_type(8)));
typedef float    f32x4 __attribute__((ext_vector_type(4)));

__device__ __forceinline__ float wred64(float v){
  #pragma unroll
  for (int m = 32; m > 0; m >>= 1) v += __shfl_xor(v, m, 64);
  return v;
}
__device__ __forceinline__ float leakyf(float v){ return v > 0.f ? v : 0.1f*v; }

__device__ __forceinline__ void bn_param(const float* st, int c, float inv_n,
                                         const float* g, const float* e,
                                         float& sc, float& sh){
  float mu  = st[c]*inv_n;
  float var = st[128+c]*inv_n - mu*mu;
  float s   = g[c]*rsqrtf(var + 1e-5f);
  sc = s; sh = e[c] - mu*s;
}

// Build the 70-channel stage-1 input row: [wxyz(3), f2_xyz[idx](3), normW*normF2(64)]
__device__ __forceinline__ void build_x70(int row,
    const float* __restrict__ wxyz, const float* __restrict__ f2_xyz,
    const float* __restrict__ normW, const float* __restrict__ normF2,
    const int* __restrict__ idxq, float* x){
  int p = row >> 5;
  int b = p >> 12;
  int idx = idxq[row];
  const float* wx = wxyz + (size_t)p*3;
  const float* fx = f2_xyz + ((size_t)b*Nn + idx)*3;
  x[0]=wx[0]; x[1]=wx[1]; x[2]=wx[2];
  x[3]=fx[0]; x[4]=fx[1]; x[5]=fx[2];
  const float4* nw = (const float4*)(normW  + (size_t)p*64);
  const float4* nf = (const float4*)(normF2 + ((size_t)b*Nn + idx)*64);
  #pragma unroll
  for (int c=0;c<16;c++){
    float4 a = nw[c], q = nf[c];
    x[6+4*c+0]=a.x*q.x; x[6+4*c+1]=a.y*q.y; x[6+4*c+2]=a.z*q.z; x[6+4*c+3]=a.w*q.w;
  }
}

// Build the 10-channel stage-2 geometry row
__device__ __forceinline__ void build_x10(int row,
    const float* __restrict__ wxyz, const int* __restrict__ idx2, float* x){
  int p = row >> 4, b = p >> 12;
  int idx = idx2[row];
  const float* nw = wxyz + (size_t)p*3;
  const float* gw = wxyz + ((size_t)b*HWn + idx)*3;
  float n0=nw[0],n1=nw[1],n2=nw[2];
  float g0=gw[0],g1=gw[1],g2=gw[2];
  float d0=g0-n0, d1=g1-n1, d2=g2-n2;
  x[0]=n0;x[1]=n1;x[2]=n2; x[3]=g0;x[4]=g1;x[5]=g2;
  x[6]=d0;x[7]=d1;x[8]=d2; x[9]=sqrtf(d0*d0+d1*d1+d2*d2+1e-20f);
}

// ---------------- prep: norms, wxyz, weight transposes + f16 weights ----------------
__global__ __launch_bounds__(256) void k_prep(
    const float* __restrict__ warped_xyz, const float* __restrict__ lidar_z,
    const float* __restrict__ warped_points, const float* __restrict__ f2_points,
    const float* __restrict__ m1w0, const float* __restrict__ m1w1,
    const float* __restrict__ piw, const float* __restrict__ pcw,
    const float* __restrict__ m2w0, const float* __restrict__ m2w1,
    const float* __restrict__ m3w0, const float* __restrict__ m3w1,
    float* __restrict__ wxyz, float* __restrict__ normW, float* __restrict__ normF2,
    float* __restrict__ piwT, float* __restrict__ pcwT,
    _Float16* __restrict__ w1h, _Float16* __restrict__ w2h,
    _Float16* __restrict__ w3h, _Float16* __restrict__ w4h,
    _Float16* __restrict__ w5h, _Float16* __restrict__ w6h)
{
  int blk = blockIdx.x, tid = threadIdx.x;
  if (blk < 4096){
    int lane = tid & 63;
    int p = blk*4 + (tid >> 6);            // 0..16383
    const float* src; float* dst;
    if (p < Bn*HWn){ src = warped_points + (size_t)p*64; dst = normW + (size_t)p*64; }
    else { int q = p - Bn*HWn; src = f2_points + (size_t)q*64; dst = normF2 + (size_t)q*64; }
    float x = src[lane];
    float m = wred64(x) * (1.f/64.f);
    float d = x - m;
    float ss = wred64(d*d);
    float s = fmaxf(sqrtf(ss*(1.f/63.f)), 1e-12f);
    dst[lane] = d / s;
  } else if (blk < 4192){
    int e = (blk-4096)*256 + tid;          // < 24576
    wxyz[e] = warped_xyz[e] * lidar_z[e/3];
  } else if (blk < 4196){
    int e = (blk-4192)*256 + tid;          // < 1024
    if (e < 384){ piwT[(e & 63)*6  + (e >> 6)] = piw[e]; }
    else if (e < 1024){ int f = e-384; pcwT[(f & 63)*10 + (f >> 6)] = pcw[f]; }
  } else {
    int e = (blk-4196)*256 + tid;          // < 49152
    if (e < 12288){                        // w1h[j][k] : [128 out][96 in-pad]
      int j = e/96, k = e - j*96;
      w1h[e] = (k < 70) ? (_Float16)m1w0[k*128 + j] : (_Float16)0.f;
    } else if (e < 20480){                 // w2h[d][c] : [64][128]
      int f = e - 12288; int d = f >> 7, c = f & 127;
      w2h[f] = (_Float16)m1w1[c*64 + d];
    } else if (e < 28672){                 // w3h[d][c] : [64][128]
      int f = e - 20480; int d = f >> 7, c = f & 127;
      w3h[f] = (_Float16)m2w0[c*64 + d];
    } else if (e < 32768){                 // w4h[d][c] : [64][64]
      int f = e - 28672; int d = f >> 6, c = f & 63;
      w4h[f] = (_Float16)m2w1[c*64 + d];
    } else if (e < 45056){                 // w5h[d][c] : [64][192]
      int f = e - 32768; int d = f/192, c = f - 192*d;
      w5h[f] = (_Float16)m3w0[c*64 + d];
    } else {                               // w6h[d][c] : [64][64]
      int f = e - 45056; int d = f >> 6, c = f & 63;
      w6h[f] = (_Float16)m3w1[c*64 + d];
    }
  }
}

// ---------------- exact k-smallest via 8-bit radix select (parallel scan) ----------------
template<int K, bool WRITE_VALID>
__global__ __launch_bounds__(256) void k_knn(
    const float* __restrict__ qpts, const float* __restrict__ pts,
    int* __restrict__ oidx, float* __restrict__ ovalid)
{
  __shared__ unsigned int sd[Nn];
  __shared__ int hist[256];
  __shared__ int wsum[4];
  __shared__ unsigned int sh_prefix;
  __shared__ int sh_rem, cnt_lt, cnt_eq;
  int b = blockIdx.x >> 12;
  int qi = blockIdx.x & 4095;
  int tid = threadIdx.x;
  int lane = tid & 63, wv = tid >> 6;
  const float* qp = qpts + ((size_t)(b*HWn+qi))*3;
  float qx=qp[0], qy=qp[1], qz=qp[2];
  const float* pb = pts + (size_t)b*Nn*3;
  for (int t=tid; t<Nn; t+=256){
    float dx = __fsub_rn(qx, pb[t*3+0]);
    float dy = __fsub_rn(qy, pb[t*3+1]);
    float dz = __fsub_rn(qz, pb[t*3+2]);
    float d2 = __fadd_rn(__fadd_rn(__fmul_rn(dx,dx), __fmul_rn(dy,dy)), __fmul_rn(dz,dz));
    sd[t] = __float_as_uint(d2);
  }
  if (tid == 0){ cnt_lt = 0; cnt_eq = 0; }
  unsigned int prefix = 0; int rem = K;
  for (int shift = 24; shift >= 0; shift -= 8){
    __syncthreads();
    hist[tid] = 0;
    __syncthreads();
    unsigned int maskhi = (shift == 24) ? 0u : (0xFFFFFFFFu << (shift+8));
    for (int t=tid; t<Nn; t+=256){
      unsigned int v = sd[t];
      if ((v & maskhi) == prefix) atomicAdd(&hist[(v >> shift) & 255], 1);
    }
    __syncthreads();
    int h = hist[tid];
    int pref = h;
    #pragma unroll
    for (int m=1;m<64;m<<=1){ int t = __shfl_up(pref, m, 64); if (lane >= m) pref += t; }
    if (lane == 63) wsum[wv] = pref;
    __syncthreads();
    int off = 0;
    #pragma unroll
    for (int i=0;i<3;i++) if (i < wv) off += wsum[i];
    pref += off;
    if (pref >= rem && (pref - h) < rem){
      sh_prefix = prefix | ((unsigned int)tid << shift);
      sh_rem = rem - (pref - h);
    }
    __syncthreads();
    prefix = sh_prefix; rem = sh_rem;
  }
  unsigned int kth = prefix;
  int nless = K - rem;
  size_t obase = ((size_t)(b*HWn+qi))*K;
  const unsigned int U100 = __float_as_uint(100.0f);
  for (int t=tid; t<Nn; t+=256){
    unsigned int v = sd[t];
    if (v <= kth){
      int s;
      if (v < kth) s = atomicAdd(&cnt_lt, 1);
      else { s = atomicAdd(&cnt_eq, 1); if (s >= rem) continue; s += nless; }
      oidx[obase+s] = t;
      if constexpr (WRITE_VALID) ovalid[obase+s] = (v < U100) ? 1.f : 0.f;
    }
  }
}

// ---------------- build f16 X1 rows: [wxyz(3) f2xyz(3) prod(64) pad->96] ----------------
__global__ __launch_bounds__(256) void k_buildX1(
    const float* __restrict__ wxyz, const float* __restrict__ f2_xyz,
    const float* __restrict__ normW, const float* __restrict__ normF2,
    const int* __restrict__ idxq, _Float16* __restrict__ X1)
{
  int row = blockIdx.x*256 + threadIdx.x;
  float x[70];
  build_x70(row, wxyz, f2_xyz, normW, normF2, idxq, x);
  unsigned int* d32 = (unsigned int*)(X1 + (size_t)row*96);
  union { unsigned int u; _Float16 h[2]; } pk;
  #pragma unroll
  for (int c=0;c<35;c++){
    pk.h[0] = (_Float16)x[2*c]; pk.h[1] = (_Float16)x[2*c+1];
    d32[c] = pk.u;
  }
  #pragma unroll
  for (int c=35;c<48;c++) d32[c] = 0u;
}

// ---------------- Gram-matrix stats for pi_enc (7x7) and pc_enc (11x11) ----------------
__global__ __launch_bounds__(256) void k_gram(
    const float* __restrict__ wxyz, const float* __restrict__ f2_xyz,
    const int* __restrict__ idxq, const int* __restrict__ idx2,
    float* __restrict__ gram)
{
  __shared__ float sacc[66];
  int blk = blockIdx.x, tid = threadIdx.x, lane = tid & 63;
  if (blk < 64){
    float a[28];
    #pragma unroll
    for (int q=0;q<28;q++) a[q]=0.f;
    int g = blk*256 + tid;
    for (int s=0;s<16;s++){
      int row = g + s*16384;
      int p = row >> 5, b = p >> 12;
      int idx = idxq[row];
      const float* wx = wxyz + (size_t)p*3;
      const float* fx = f2_xyz + ((size_t)b*Nn + idx)*3;
      float xt[7] = {wx[0],wx[1],wx[2],fx[0],fx[1],fx[2],1.f};
      int q=0;
      #pragma unroll
      for (int i=0;i<7;i++)
        #pragma unroll
        for (int j=i;j<7;j++) a[q++] += xt[i]*xt[j];
    }
    if (tid < 28) sacc[tid]=0.f;
    __syncthreads();
    #pragma unroll
    for (int q=0;q<28;q++){
      float v = wred64(a[q]);
      if (lane==0) atomicAdd(&sacc[q], v);
    }
    __syncthreads();
    if (tid < 28) atomicAdd(&gram[tid], sacc[tid]);
  } else {
    float a[66];
    #pragma unroll
    for (int q=0;q<66;q++) a[q]=0.f;
    int g = (blk-64)*256 + tid;
    for (int s=0;s<16;s++){
      int row = g + s*8192;
      float x[10];
      build_x10(row, wxyz, idx2, x);
      float xt[11] = {x[0],x[1],x[2],x[3],x[4],x[5],x[6],x[7],x[8],x[9],1.f};
      int q=0;
      #pragma unroll
      for (int i=0;i<11;i++)
        #pragma unroll
        for (int j=i;j<11;j++) a[q++] += xt[i]*xt[j];
    }
    if (tid < 66) sacc[tid]=0.f;
    __syncthreads();
    #pragma unroll
    for (int q=0;q<66;q++){
      float v = wred64(a[q]);
      if (lane==0) atomicAdd(&sacc[q], v);
    }
    __syncthreads();
    if (tid < 66) atomicAdd(&gram[32+tid], sacc[tid]);
  }
}

__global__ __launch_bounds__(128) void k_gram_fin(
    const float* __restrict__ gram,
    const float* __restrict__ piw, const float* __restrict__ pib,
    const float* __restrict__ pcw, const float* __restrict__ pcb,
    float* stats)
{
  int tid = threadIdx.x;
  if (tid < 64){
    int c = tid;
    float wt[7];
    #pragma unroll
    for (int i=0;i<6;i++) wt[i] = piw[i*64+c];
    wt[6] = pib[c];
    const float* G = gram;
    float sum=0.f, ssq=0.f;
    #pragma unroll
    for (int i=0;i<7;i++){
      int offi = i*7 - (i*(i-1))/2;
      sum += wt[i]*G[offi + (6-i)];
      #pragma unroll
      for (int j=0;j<7;j++){
        int ii = i<j? i : j, jj = i<j? j : i;
        int o = ii*7 - (ii*(ii-1))/2 + (jj-ii);
        ssq += wt[i]*wt[j]*G[o];
      }
    }
    stats[2*256+c] = sum; stats[2*256+128+c] = ssq;
  } else {
    int c = tid-64;
    float wt[11];
    #pragma unroll
    for (int i=0;i<10;i++) wt[i] = pcw[i*64+c];
    wt[10] = pcb[c];
    const float* G = gram + 32;
    float sum=0.f, ssq=0.f;
    #pragma unroll
    for (int i=0;i<11;i++){
      int offi = i*11 - (i*(i-1))/2;
      sum += wt[i]*G[offi + (10-i)];
      #pragma unroll
      for (int j=0;j<11;j++){
        int ii = i<j? i : j, jj = i<j? j : i;
        int o = ii*11 - (ii*(ii-1))/2 + (jj-ii);
        ssq += wt[i]*wt[j]*G[o];
      }
    }
    stats[5*256+c] = sum; stats[5*256+128+c] = ssq;
  }
}

// ---------------- MFMA y1 stats: 4x64-row tiles/block, weights direct from global ----------------
__global__ __launch_bounds__(256) void k_mfma_stats1(
    const _Float16* __restrict__ X1, const _Float16* __restrict__ w1h,
    float* stats)
{
  __shared__ float ssum[128], sssq[128];
  int tid = threadIdx.x;
  if (tid < 128){ ssum[tid]=0.f; sssq[tid]=0.f; }
  __syncthreads();
  int wave = tid >> 6, lane = tid & 63;
  int quad = lane >> 4, n16 = lane & 15;
  float r1[8], r2[8];
  #pragma unroll
  for (int i=0;i<8;i++){ r1[i]=0.f; r2[i]=0.f; }
  for (int t=0;t<4;t++){
    int m0 = blockIdx.x*256 + t*64 + wave*16;
    const _Float16* xr = X1 + (size_t)(m0 + n16)*96 + quad*8;
    f16x8 a0 = *(const f16x8*)(xr);
    f16x8 a1 = *(const f16x8*)(xr + 32);
    f16x8 a2 = *(const f16x8*)(xr + 64);
    #pragma unroll
    for (int nt = 0; nt < 8; nt++){
      const _Float16* wr = w1h + (size_t)(nt*16 + n16)*96 + quad*8;
      f16x8 b0 = *(const f16x8*)(wr);
      f16x8 b1 = *(const f16x8*)(wr + 32);
      f16x8 b2 = *(const f16x8*)(wr + 64);
      f32x4 acc = {0.f,0.f,0.f,0.f};
      acc = __builtin_amdgcn_mfma_f32_16x16x32_f16(a0, b0, acc, 0,0,0);
      acc = __builtin_amdgcn_mfma_f32_16x16x32_f16(a1, b1, acc, 0,0,0);
      acc = __builtin_amdgcn_mfma_f32_16x16x32_f16(a2, b2, acc, 0,0,0);
      float s1 = acc[0]+acc[1]+acc[2]+acc[3];
      float s2 = acc[0]*acc[0]+acc[1]*acc[1]+acc[2]*acc[2]+acc[3]*acc[3];
      s1 += __shfl_xor(s1, 16, 64); s1 += __shfl_xor(s1, 32, 64);
      s2 += __shfl_xor(s2, 16, 64); s2 += __shfl_xor(s2, 32, 64);
      r1[nt] += s1; r2[nt] += s2;
    }
  }
  if (quad == 0){
    #pragma unroll
    for (int nt=0;nt<8;nt++){
      atomicAdd(&ssum[nt*16+n16], r1[nt]); atomicAdd(&sssq[nt*16+n16], r2[nt]);
    }
  }
  __syncthreads();
  if (tid < 128){ atomicAdd(&stats[tid], ssum[tid]); atomicAdd(&stats[128+tid], sssq[tid]); }
}

// ---------------- MFMA m1: 4 tiles/block; y1 -> BN/leaky -> t (LDS) -> x W2 -> y2 ----------------
__global__ __launch_bounds__(256) void k_mfma_m1(
    const _Float16* __restrict__ X1, const _Float16* __restrict__ w1h,
    const _Float16* __restrict__ w2h,
    const float* __restrict__ m1g0, const float* __restrict__ m1e0,
    float* stats, _Float16* __restrict__ y2h)
{
  __shared__ _Float16 st[64*136];
  __shared__ float sc1[128], sh1[128], ssum[64], sssq[64];
  int tid = threadIdx.x;
  if (tid < 128){
    float s,h; bn_param(stats, tid, INV_R1, m1g0, m1e0, s, h);
    sc1[tid]=s; sh1[tid]=h;
  }
  if (tid < 64){ ssum[tid]=0.f; sssq[tid]=0.f; }
  __syncthreads();
  int wave = tid >> 6, lane = tid & 63;
  int quad = lane >> 4, n16 = lane & 15;
  float r1[4], r2[4];
  #pragma unroll
  for (int i=0;i<4;i++){ r1[i]=0.f; r2[i]=0.f; }
  for (int t=0;t<4;t++){
    int m0 = blockIdx.x*256 + t*64 + wave*16;
    const _Float16* xr = X1 + (size_t)(m0 + n16)*96 + quad*8;
    f16x8 a0 = *(const f16x8*)(xr);
    f16x8 a1 = *(const f16x8*)(xr + 32);
    f16x8 a2 = *(const f16x8*)(xr + 64);
    #pragma unroll
    for (int nt = 0; nt < 8; nt++){
      const _Float16* wr = w1h + (size_t)(nt*16 + n16)*96 + quad*8;
      f16x8 b0 = *(const f16x8*)(wr);
      f16x8 b1 = *(const f16x8*)(wr + 32);
      f16x8 b2 = *(const f16x8*)(wr + 64);
      f32x4 acc = {0.f,0.f,0.f,0.f};
      acc = __builtin_amdgcn_mfma_f32_16x16x32_f16(a0, b0, acc, 0,0,0);
      acc = __builtin_amdgcn_mfma_f32_16x16x32_f16(a1, b1, acc, 0,0,0);
      acc = __builtin_amdgcn_mfma_f32_16x16x32_f16(a2, b2, acc, 0,0,0);
      int ch = nt*16 + n16;
      float sc = sc1[ch], sh = sh1[ch];
      #pragma unroll
      for (int r=0;r<4;r++){
        float v = leakyf(acc[r]*sc + sh);
        st[(size_t)(wave*16 + quad*4 + r)*136 + ch] = (_Float16)v;
      }
    }
    __syncthreads();
    const _Float16* tr = st + (size_t)(wave*16 + n16)*136 + quad*8;
    f16x8 t0 = *(const f16x8*)(tr);
    f16x8 t1 = *(const f16x8*)(tr + 32);
    f16x8 t2 = *(const f16x8*)(tr + 64);
    f16x8 t3 = *(const f16x8*)(tr + 96);
    #pragma unroll
    for (int nt = 0; nt < 4; nt++){
      const _Float16* wr = w2h + (size_t)(nt*16 + n16)*128 + quad*8;
      f16x8 b0 = *(const f16x8*)(wr);
      f16x8 b1 = *(const f16x8*)(wr + 32);
      f16x8 b2 = *(const f16x8*)(wr + 64);
      f16x8 b3 = *(const f16x8*)(wr + 96);
      f32x4 acc = {0.f,0.f,0.f,0.f};
      acc = __builtin_amdgcn_mfma_f32_16x16x32_f16(t0, b0, acc, 0,0,0);
      acc = __builtin_amdgcn_mfma_f32_16x16x32_f16(t1, b1, acc, 0,0,0);
      acc = __builtin_amdgcn_mfma_f32_16x16x32_f16(t2, b2, acc, 0,0,0);
      acc = __builtin_amdgcn_mfma_f32_16x16x32_f16(t3, b3, acc, 0,0,0);
      int ch = nt*16 + n16;
      #pragma unroll
      for (int r=0;r<4;r++){
        int rowg = blockIdx.x*256 + t*64 + wave*16 + quad*4 + r;
        y2h[(size_t)rowg*64 + ch] = (_Float16)acc[r];
      }
      float s1 = acc[0]+acc[1]+acc[2]+acc[3];
      float s2 = acc[0]*acc[0]+acc[1]*acc[1]+acc[2]*acc[2]+acc[3]*acc[3];
      s1 += __shfl_xor(s1, 16, 64); s1 += __shfl_xor(s1, 32, 64);
      s2 += __shfl_xor(s2, 16, 64); s2 += __shfl_xor(s2, 32, 64);
      r1[nt] += s1; r2[nt] += s2;
    }
    __syncthreads();
  }
  if (quad == 0){
    #pragma unroll
    for (int nt=0;nt<4;nt++){
      atomicAdd(&ssum[nt*16+n16], r1[nt]); atomicAdd(&sssq[nt*16+n16], r2[nt]);
    }
  }
  __syncthreads();
  if (tid < 64){ atomicAdd(&stats[1*256+tid], ssum[tid]); atomicAdd(&stats[1*256+128+tid], sssq[tid]); }
}

// ---------------- MFMA m2a: 4 tiles/block; u=[pi_enc|feat] in LDS, y3 = u x W3 ----------------
__global__ __launch_bounds__(256) void k_mfma_m2a(
    const float* __restrict__ wxyz, const float* __restrict__ f2_xyz,
    const int* __restrict__ idxq,
    const float* __restrict__ piwT, const float* __restrict__ pib,
    const float* __restrict__ pig, const float* __restrict__ pie,
    const float* __restrict__ m1g1, const float* __restrict__ m1e1,
    const _Float16* __restrict__ y2h, const _Float16* __restrict__ w3h,
    float* stats, _Float16* __restrict__ y3h)
{
  __shared__ _Float16 su[64*136];
  __shared__ float spw[384];
  __shared__ float scp[64], shp[64], sc2[64], sh2[64], ssum[64], sssq[64];
  int tid = threadIdx.x;
  for (int d = tid; d < 384; d += 256) spw[d] = piwT[d];
  if (tid < 64){
    float s,h;
    bn_param(stats+2*256, tid, INV_R1, pig,  pie,  s, h); scp[tid]=s; shp[tid]=h;
    bn_param(stats+1*256, tid, INV_R1, m1g1, m1e1, s, h); sc2[tid]=s; sh2[tid]=h;
    ssum[tid]=0.f; sssq[tid]=0.f;
  }
  __syncthreads();
  int r = tid & 63, cg = tid >> 6;
  int wave = tid >> 6, lane = tid & 63, quad = lane >> 4, n16 = lane & 15;
  float r1[4], r2[4];
  #pragma unroll
  for (int i=0;i<4;i++){ r1[i]=0.f; r2[i]=0.f; }
  for (int t=0;t<4;t++){
    int rowg = blockIdx.x*256 + t*64 + r;
    {
      int p = rowg >> 5, b = p >> 12;
      int idx = idxq[rowg];
      const float* wx = wxyz + (size_t)p*3;
      const float* fx = f2_xyz + ((size_t)b*Nn + idx)*3;
      float x0=wx[0],x1=wx[1],x2=wx[2],x3=fx[0],x4=fx[1],x5=fx[2];
      #pragma unroll
      for (int jj=0;jj<16;jj++){
        int j = cg*16 + jj;
        const float* pw = spw + j*6;
        float e = pib[j] + x0*pw[0]+x1*pw[1]+x2*pw[2]+x3*pw[3]+x4*pw[4]+x5*pw[5];
        su[r*136 + j] = (_Float16)leakyf(e*scp[j] + shp[j]);
      }
      const f16x8* yr = (const f16x8*)(y2h + (size_t)rowg*64 + cg*16);
      f16x8 q0 = yr[0], q1 = yr[1];
      #pragma unroll
      for (int jj=0;jj<8;jj++){
        int c = cg*16 + jj;
        su[r*136 + 64 + c] = (_Float16)leakyf((float)q0[jj]*sc2[c] + sh2[c]);
      }
      #pragma unroll
      for (int jj=0;jj<8;jj++){
        int c = cg*16 + 8 + jj;
        su[r*136 + 64 + c] = (_Float16)leakyf((float)q1[jj]*sc2[c] + sh2[c]);
      }
    }
    __syncthreads();
    const _Float16* ur = su + (size_t)(wave*16 + n16)*136 + quad*8;
    f16x8 a0 = *(const f16x8*)(ur);
    f16x8 a1 = *(const f16x8*)(ur + 32);
    f16x8 a2 = *(const f16x8*)(ur + 64);
    f16x8 a3 = *(const f16x8*)(ur + 96);
    #pragma unroll
    for (int nt = 0; nt < 4; nt++){
      const _Float16* wr = w3h + (size_t)(nt*16 + n16)*128 + quad*8;
      f16x8 b0 = *(const f16x8*)(wr);
      f16x8 b1 = *(const f16x8*)(wr + 32);
      f16x8 b2 = *(const f16x8*)(wr + 64);
      f16x8 b3 = *(const f16x8*)(wr + 96);
      f32x4 acc = {0.f,0.f,0.f,0.f};
      acc = __builtin_amdgcn_mfma_f32_16x16x32_f16(a0, b0, acc, 0,0,0);
      acc = __builtin_amdgcn_mfma_f32_16x16x32_f16(a1, b1, acc, 0,0,0);
      acc = __builtin_amdgcn_mfma_f32_16x16x32_f16(a2, b2, acc, 0,0,0);
      acc = __builtin_amdgcn_mfma_f32_16x16x32_f16(a3, b3, acc, 0,0,0);
      int ch = nt*16 + n16;
      #pragma unroll
      for (int rr=0;rr<4;rr++){
        int rg = blockIdx.x*256 + t*64 + wave*16 + quad*4 + rr;
        y3h[(size_t)rg*64 + ch] = (_Float16)acc[rr];
      }
      float s1 = acc[0]+acc[1]+acc[2]+acc[3];
      float s2 = acc[0]*acc[0]+acc[1]*acc[1]+acc[2]*acc[2]+acc[3]*acc[3];
      s1 += __shfl_xor(s1, 16, 64); s1 += __shfl_xor(s1, 32, 64);
      s2 += __shfl_xor(s2, 16, 64); s2 += __shfl_xor(s2, 32, 64);
      r1[nt] += s1; r2[nt] += s2;
    }
    __syncthreads();
  }
  if (quad == 0){
    #pragma unroll
    for (int nt=0;nt<4;nt++){
      atomicAdd(&ssum[nt*16+n16], r1[nt]); atomicAdd(&sssq[nt*16+n16], r2[nt]);
    }
  }
  __syncthreads();
  if (tid < 64){ atomicAdd(&stats[3*256+tid], ssum[tid]); atomicAdd(&stats[3*256+128+tid], sssq[tid]); }
}

// ---------------- generic MFMA pointwise 64->64, 4 tiles/block ----------------
__global__ __launch_bounds__(256) void k_mfma_pw64(
    const _Float16* __restrict__ yin, const _Float16* __restrict__ wh,
    const float* __restrict__ g, const float* __restrict__ e,
    const float* statsIn, float* statsOut, float inv_n,
    _Float16* __restrict__ yout)
{
  __shared__ _Float16 stt[64*72];
  __shared__ float sc[64], sh[64], ssum[64], sssq[64];
  int tid = threadIdx.x;
  if (tid < 64){
    float s,h; bn_param(statsIn, tid, inv_n, g, e, s, h);
    sc[tid]=s; sh[tid]=h; ssum[tid]=0.f; sssq[tid]=0.f;
  }
  __syncthreads();
  int r = tid & 63, cg = tid >> 6;
  int wave = tid >> 6, lane = tid & 63, quad = lane >> 4, n16 = lane & 15;
  float r1[4], r2[4];
  #pragma unroll
  for (int i=0;i<4;i++){ r1[i]=0.f; r2[i]=0.f; }
  for (int t=0;t<4;t++){
    int rowg = blockIdx.x*256 + t*64 + r;
    const f16x8* yr = (const f16x8*)(yin + (size_t)rowg*64 + cg*16);
    f16x8 q0 = yr[0], q1 = yr[1];
    #pragma unroll
    for (int jj=0;jj<8;jj++){
      int c = cg*16 + jj;
      stt[r*72 + c] = (_Float16)leakyf((float)q0[jj]*sc[c] + sh[c]);
    }
    #pragma unroll
    for (int jj=0;jj<8;jj++){
      int c = cg*16 + 8 + jj;
      stt[r*72 + c] = (_Float16)leakyf((float)q1[jj]*sc[c] + sh[c]);
    }
    __syncthreads();
    const _Float16* tr = stt + (size_t)(wave*16 + n16)*72 + quad*8;
    f16x8 a0 = *(const f16x8*)(tr);
    f16x8 a1 = *(const f16x8*)(tr + 32);
    #pragma unroll
    for (int nt = 0; nt < 4; nt++){
      const _Float16* wr = wh + (size_t)(nt*16 + n16)*64 + quad*8;
      f16x8 b0 = *(const f16x8*)(wr);
      f16x8 b1 = *(const f16x8*)(wr + 32);
      f32x4 acc = {0.f,0.f,0.f,0.f};
      acc = __builtin_amdgcn_mfma_f32_16x16x32_f16(a0, b0, acc, 0,0,0);
      acc = __builtin_amdgcn_mfma_f32_16x16x32_f16(a1, b1, acc, 0,0,0);
      int ch = nt*16 + n16;
      #pragma unroll
      for (int rr=0;rr<4;rr++){
        int rg = blockIdx.x*256 + t*64 + wave*16 + quad*4 + rr;
        yout[(size_t)rg*64 + ch] = (_Float16)acc[rr];
      }
      float s1 = acc[0]+acc[1]+acc[2]+acc[3];
      float s2 = acc[0]*acc[0]+acc[1]*acc[1]+acc[2]*acc[2]+acc[3]*acc[3];
      s1 += __shfl_xor(s1, 16, 64); s1 += __shfl_xor(s1, 32, 64);
      s2 += __shfl_xor(s2, 16, 64); s2 += __shfl_xor(s2, 32, 64);
      r1[nt] += s1; r2[nt] += s2;
    }
    __syncthreads();
  }
  if (quad == 0){
    #pragma unroll
    for (int nt=0;nt<4;nt++){
      atomicAdd(&ssum[nt*16+n16], r1[nt]); atomicAdd(&sssq[nt*16+n16], r2[nt]);
    }
  }
  __syncthreads();
  if (tid < 64){ atomicAdd(&statsOut[tid], ssum[tid]); atomicAdd(&statsOut[128+tid], sssq[tid]); }
}

// ---------------- MFMA m3a: 4 tiles/block; v=[pc_enc|wp|pif1_g] (192ch), y5 = v x W5 ----------------
__global__ __launch_bounds__(256) void k_mfma_m3a(
    const float* __restrict__ wxyz, const float* __restrict__ warped_points,
    const _Float16* __restrict__ pif1h, const int* __restrict__ idx2,
    const float* __restrict__ pcwT, const float* __restrict__ pcb,
    const float* __restrict__ pcg, const float* __restrict__ pce,
    const _Float16* __restrict__ w5h,
    float* stats, _Float16* __restrict__ y5h)
{
  __shared__ _Float16 sv[64*200];
  __shared__ float spw[640];
  __shared__ float scp[64], shp[64], ssum[64], sssq[64];
  int tid = threadIdx.x;
  for (int d = tid; d < 640; d += 256) spw[d] = pcwT[d];
  if (tid < 64){
    float s,h; bn_param(stats+5*256, tid, INV_R2, pcg, pce, s, h);
    scp[tid]=s; shp[tid]=h; ssum[tid]=0.f; sssq[tid]=0.f;
  }
  __syncthreads();
  int r = tid & 63, cg = tid >> 6;
  int wave = tid >> 6, lane = tid & 63, quad = lane >> 4, n16 = lane & 15;
  float r1[4], r2[4];
  #pragma unroll
  for (int i=0;i<4;i++){ r1[i]=0.f; r2[i]=0.f; }
  for (int t=0;t<4;t++){
    int rowg = blockIdx.x*256 + t*64 + r;
    {
      int p = rowg >> 4, b = p >> 12;
      int idx = idx2[rowg];
      float x[10];
      build_x10(rowg, wxyz, idx2, x);
      #pragma unroll
      for (int jj=0;jj<16;jj++){
        int j = cg*16 + jj;
        const float* pw = spw + j*10;
        float e = pcb[j];
        #pragma unroll
        for (int i=0;i<10;i++) e += x[i]*pw[i];
        sv[r*200 + j] = (_Float16)leakyf(e*scp[j] + shp[j]);
      }
      const float4* wp = (const float4*)(warped_points + (size_t)p*64 + cg*16);
      #pragma unroll
      for (int v4=0; v4<4; v4++){
        float4 q = wp[v4];
        int c = 64 + cg*16 + v4*4;
        sv[r*200 + c + 0] = (_Float16)q.x;
        sv[r*200 + c + 1] = (_Float16)q.y;
        sv[r*200 + c + 2] = (_Float16)q.z;
        sv[r*200 + c + 3] = (_Float16)q.w;
      }
      const f16x8* pg = (const f16x8*)(pif1h + ((size_t)(b*HWn) + idx)*64 + cg*16);
      f16x8 g0 = pg[0], g1 = pg[1];
      #pragma unroll
      for (int jj=0;jj<8;jj++) sv[r*200 + 128 + cg*16 + jj] = g0[jj];
      #pragma unroll
      for (int jj=0;jj<8;jj++) sv[r*200 + 136 + cg*16 + jj] = g1[jj];
    }
    __syncthreads();
    const _Float16* vr = sv + (size_t)(wave*16 + n16)*200 + quad*8;
    f16x8 a0 = *(const f16x8*)(vr);
    f16x8 a1 = *(const f16x8*)(vr + 32);
    f16x8 a2 = *(const f16x8*)(vr + 64);
    f16x8 a3 = *(const f16x8*)(vr + 96);
    f16x8 a4 = *(const f16x8*)(vr + 128);
    f16x8 a5 = *(const f16x8*)(vr + 160);
    #pragma unroll
    for (int nt = 0; nt < 4; nt++){
      const _Float16* wr = w5h + (size_t)(nt*16 + n16)*192 + quad*8;
      f32x4 acc = {0.f,0.f,0.f,0.f};
      acc = __builtin_amdgcn_mfma_f32_16x16x32_f16(a0, *(const f16x8*)(wr),       acc, 0,0,0);
      acc = __builtin_amdgcn_mfma_f32_16x16x32_f16(a1, *(const f16x8*)(wr + 32),  acc, 0,0,0);
      acc = __builtin_amdgcn_mfma_f32_16x16x32_f16(a2, *(const f16x8*)(wr + 64),  acc, 0,0,0);
      acc = __builtin_amdgcn_mfma_f32_16x16x32_f16(a3, *(const f16x8*)(wr + 96),  acc, 0,0,0);
      acc = __builtin_amdgcn_mfma_f32_16x16x32_f16(a4, *(const f16x8*)(wr + 128), acc, 0,0,0);
      acc = __builtin_amdgcn_mfma_f32_16x16x32_f16(a5, *(const f16x8*)(wr + 160), acc, 0,0,0);
      int ch = nt*16 + n16;
      #pragma unroll
      for (int rr=0;rr<4;rr++){
        int rg = blockIdx.x*256 + t*64 + wave*16 + quad*4 + rr;
        y5h[(size_t)rg*64 + ch] = (_Float16)acc[rr];
      }
      float s1 = acc[0]+acc[1]+acc[2]+acc[3];
      float s2 = acc[0]*acc[0]+acc[1]*acc[1]+acc[2]*acc[2]+acc[3]*acc[3];
      s1 += __shfl_xor(s1, 16, 64); s1 += __shfl_xor(s1, 32, 64);
      s2 += __shfl_xor(s2, 16, 64); s2 += __shfl_xor(s2, 32, 64);
      r1[nt] += s1; r2[nt] += s2;
    }
    __syncthreads();
  }
  if (quad == 0){
    #pragma unroll
    for (int nt=0;nt<4;nt++){
      atomicAdd(&ssum[nt*16+n16], r1[nt]); atomicAdd(&sssq[nt*16+n16], r2[nt]);
    }
  }
  __syncthreads();
  if (tid < 64){ atomicAdd(&stats[6*256+tid], ssum[tid]); atomicAdd(&stats[6*256+128+tid], sssq[tid]); }
}

// ---------------- stage-1 softmax over KQ, weighted sum of feat -> pif1 (f16) ----------------
__global__ __launch_bounds__(256) void k_softmax1(
    const _Float16* __restrict__ y2h, const _Float16* __restrict__ y4h,
    const float* stats,
    const float* __restrict__ m1g1, const float* __restrict__ m1e1,
    const float* __restrict__ m2g1, const float* __restrict__ m2e1,
    _Float16* __restrict__ pif1h)
{
  int tid = threadIdx.x, lane = tid & 63;
  int p = blockIdx.x*4 + (tid >> 6);
  int d = lane;
  float sc2,sh2,sc4,sh4;
  bn_param(stats+1*256, d, INV_R1, m1g1, m1e1, sc2, sh2);
  bn_param(stats+4*256, d, INV_R1, m2g1, m2e1, sc4, sh4);
  size_t rb = (size_t)p*KQn;
  float v[32]; float mx = -1e30f;
  #pragma unroll
  for (int k=0;k<32;k++){
    float t = leakyf((float)y4h[(rb+k)*64 + d]*sc4 + sh4);
    v[k] = t; mx = fmaxf(mx, t);
  }
  float se = 0.f;
  #pragma unroll
  for (int k=0;k<32;k++){ float ev = __expf(v[k]-mx); v[k]=ev; se += ev; }
  float inv = 1.f/se, acc = 0.f;
  #pragma unroll
  for (int k=0;k<32;k++){
    float f = leakyf((float)y2h[(rb+k)*64 + d]*sc2 + sh2);
    acc += v[k]*f;
  }
  pif1h[(size_t)p*64 + d] = (_Float16)(acc*inv);
}

// ---------------- stage-2 masked softmax over KN, weighted sum of gathered pif1 ----------------
__global__ __launch_bounds__(256) void k_softmax2(
    const _Float16* __restrict__ y6h, const _Float16* __restrict__ pif1h,
    const int* __restrict__ idx2, const float* __restrict__ validf,
    const float* stats,
    const float* __restrict__ m3g1, const float* __restrict__ m3e1,
    float* __restrict__ out)
{
  int tid = threadIdx.x, lane = tid & 63;
  int p = blockIdx.x*4 + (tid >> 6);
  int b = p >> 12;
  int d = lane;
  float sc,sh; bn_param(stats+7*256, d, INV_R2, m3g1, m3e1, sc, sh);
  size_t rb = (size_t)p*KNn;
  float v[16]; float mx = -1e30f;
  #pragma unroll
  for (int k=0;k<16;k++){
    float t = leakyf((float)y6h[(rb+k)*64 + d]*sc + sh);
    t = (validf[rb+k] > 0.5f) ? t : -1e10f;
    v[k] = t; mx = fmaxf(mx, t);
  }
  float se = 0.f;
  #pragma unroll
  for (int k=0;k<16;k++){ float ev = __expf(v[k]-mx); v[k]=ev; se += ev; }
  float inv = 1.f/se, acc = 0.f;
  #pragma unroll
  for (int k=0;k<16;k++){
    int idx = idx2[rb+k];
    acc += v[k]*(float)pif1h[((size_t)(b*HWn) + idx)*64 + d];
  }
  out[(size_t)p*64 + d] = acc*inv;
}

// ---------------- launcher ----------------
extern "C" void kernel_launch(void* const* d_in, const int* in_sizes, int n_in,
                              void* d_out, int out_size, void* d_ws, size_t ws_size,
                              hipStream_t stream)
{
  (void)in_sizes; (void)n_in; (void)out_size; (void)ws_size;
  const float* xyz_proj      = (const float*)d_in[0];
  const float* warped_xyz    = (const float*)d_in[1];
  const float* warped_points = (const float*)d_in[2];
  const float* f2_xyz        = (const float*)d_in[4];
  const float* f2_points     = (const float*)d_in[5];
  const float* lidar_z       = (const float*)d_in[6];
  const float* m1w0=(const float*)d_in[7],  *m1g0=(const float*)d_in[9],  *m1e0=(const float*)d_in[10];
  const float* m1w1=(const float*)d_in[11], *m1g1=(const float*)d_in[13], *m1e1=(const float*)d_in[14];
  const float* piw =(const float*)d_in[15], *pib =(const float*)d_in[16], *pig =(const float*)d_in[17], *pie =(const float*)d_in[18];
  const float* m2w0=(const float*)d_in[19], *m2g0=(const float*)d_in[21], *m2e0=(const float*)d_in[22];
  const float* m2w1=(const float*)d_in[23], *m2g1=(const float*)d_in[25], *m2e1=(const float*)d_in[26];
  const float* pcw =(const float*)d_in[27], *pcb =(const float*)d_in[28], *pcg =(const float*)d_in[29], *pce =(const float*)d_in[30];
  const float* m3w0=(const float*)d_in[31], *m3g0=(const float*)d_in[33], *m3e0=(const float*)d_in[34];
  const float* m3w1=(const float*)d_in[35], *m3g1=(const float*)d_in[37], *m3e1=(const float*)d_in[38];
  float* out = (float*)d_out;

  float* ws     = (float*)d_ws;
  float* wxyz   = ws;                        // 24576
  float* normW  = wxyz   + 24576;            // 524288
  float* normF2 = normW  + 524288;           // 524288
  float* piwT   = normF2 + 524288;           // 384
  float* pcwT   = piwT   + 384;              // 640
  float* stats  = pcwT   + 640;              // 2048
  float* gram   = stats  + 2048;             // 128
  int*   idxq   = (int*)(gram + 128);        // 262144
  int*   idx2   = idxq   + 262144;           // 131072
  float* validf = (float*)(idx2 + 131072);   // 131072
  _Float16* pif1h = (_Float16*)(validf + 131072);   // 1048576 f16 = 524288 floats
  float* X1f    = validf + 131072 + 524288;
  _Float16* X1  = (_Float16*)X1f;            // 25165824 f16 = 12582912 floats
  float* y2f    = X1f + 12582912;
  _Float16* y2h = (_Float16*)y2f;            // 16777216 f16 = 8388608 floats
  float* y3f    = y2f + 8388608;
  _Float16* y3h = (_Float16*)y3f;            // 8388608 floats
  float* whb    = y3f + 8388608;             // f16 weights: 49152 f16 = 24576 floats
  _Float16* w1h = (_Float16*)whb;            // 12288
  _Float16* w2h = w1h + 12288;               // 8192
  _Float16* w3h = w2h + 8192;                // 8192
  _Float16* w4h = w3h + 8192;                // 4096
  _Float16* w5h = w4h + 4096;                // 12288
  _Float16* w6h = w5h + 12288;               // 4096
  // aliases (regions dead by the time they're overwritten):
  _Float16* y4h = (_Float16*)X1f;            // X1 dead after k_mfma_m1
  _Float16* y5h = (_Float16*)(X1f + 8388608);
  _Float16* y6h = y3h;                       // y3 dead after first k_mfma_pw64

  hipMemsetAsync(stats, 0, (2048+128)*sizeof(float), stream);
  k_prep<<<4388,256,0,stream>>>(warped_xyz, lidar_z, warped_points, f2_points,
                                m1w0, m1w1, piw, pcw, m2w0, m2w1, m3w0, m3w1,
                                wxyz, normW, normF2, piwT, pcwT,
                                w1h, w2h, w3h, w4h, w5h, w6h);
  k_knn<32,false><<<8192,256,0,stream>>>(warped_xyz, f2_xyz, idxq, nullptr);
  k_knn<16,true ><<<8192,256,0,stream>>>(xyz_proj, xyz_proj, idx2, validf);
  k_buildX1<<<1024,256,0,stream>>>(wxyz, f2_xyz, normW, normF2, idxq, X1);
  k_gram<<<96,256,0,stream>>>(wxyz, f2_xyz, idxq, idx2, gram);
  k_gram_fin<<<1,128,0,stream>>>(gram, piw, pib, pcw, pcb, stats);
  k_mfma_stats1<<<1024,256,0,stream>>>(X1, w1h, stats);
  k_mfma_m1<<<1024,256,0,stream>>>(X1, w1h, w2h, m1g0, m1e0, stats, y2h);
  k_mfma_m2a<<<1024,256,0,stream>>>(wxyz, f2_xyz, idxq, piwT, pib, pig, pie,
                                    m1g1, m1e1, y2h, w3h, stats, y3h);
  k_mfma_pw64<<<1024,256,0,stream>>>(y3h, w4h, m2g0, m2e0,
                                     stats+3*256, stats+4*256, INV_R1, y4h);
  k_softmax1<<<2048,256,0,stream>>>(y2h, y4h, stats, m1g1, m1e1, m2g1, m2e1, pif1h);
  k_mfma_m3a<<<512,256,0,stream>>>(wxyz, warped_points, pif1h, idx2,
                                   pcwT, pcb, pcg, pce, w5h, stats, y5h);
  k_mfma_pw64<<<512,256,0,stream>>>(y5h, w6h, m3g0, m3e0,
                                    stats+6*256, stats+7*256, INV_R2, y6h);
  k_softmax2<<<2048,256,0,stream>>>(y6h, pif1h, idx2, validf, stats, m3g1, m3e1, out);
}

// Round 6
// 659.366 us; speedup vs baseline: 2.3526x; 1.0123x over previous
//
#include <hip/hip_runtime.h>
#include <math.h>

// ---------------- problem constants ----------------
constexpr int Bn  = 2;
constexpr int HWn = 4096;     // H*W
constexpr int Nn  = 4096;
constexpr int KQn = 32;
constexpr int KNn = 16;
constexpr float INV_R1 = 1.0f/262144.0f;   // exact pow2
constexpr float INV_R2 = 1.0f/131072.0f;   // exact pow2

typedef _Float16 f16x8 __attribute__((ext_vector_type(8)));
typedef float    f32x4 __attribute__((ext_vector_type(4)));

__device__ __forceinline__ float wred64(float v){
  #pragma unroll
  for (int m = 32; m > 0; m >>= 1) v += __shfl_xor(v, m, 64);
  return v;
}
__device__ __forceinline__ float leakyf(float v){ return v > 0.f ? v : 0.1f*v; }

__device__ __forceinline__ void bn_param(const float* st, int c, float inv_n,
                                         const float* g, const float* e,
                                         float& sc, float& sh){
  float mu  = st[c]*inv_n;
  float var = st[128+c]*inv_n - mu*mu;
  float s   = g[c]*rsqrtf(var + 1e-5f);
  sc = s; sh = e[c] - mu*s;
}

// Build the 70-channel stage-1 input row: [wxyz(3), f2_xyz[idx](3), normW*normF2(64)]
__device__ __forceinline__ void build_x70(int row,
    const float* __restrict__ wxyz, const float* __restrict__ f2_xyz,
    const float* __restrict__ normW, const float* __restrict__ normF2,
    const int* __restrict__ idxq, float* x){
  int p = row >> 5;
  int b = p >> 12;
  int idx = idxq[row];
  const float* wx = wxyz + (size_t)p*3;
  const float* fx = f2_xyz + ((size_t)b*Nn + idx)*3;
  x[0]=wx[0]; x[1]=wx[1]; x[2]=wx[2];
  x[3]=fx[0]; x[4]=fx[1]; x[5]=fx[2];
  const float4* nw = (const float4*)(normW  + (size_t)p*64);
  const float4* nf = (const float4*)(normF2 + ((size_t)b*Nn + idx)*64);
  #pragma unroll
  for (int c=0;c<16;c++){
    float4 a = nw[c], q = nf[c];
    x[6+4*c+0]=a.x*q.x; x[6+4*c+1]=a.y*q.y; x[6+4*c+2]=a.z*q.z; x[6+4*c+3]=a.w*q.w;
  }
}

// Build the 10-channel stage-2 geometry row
__device__ __forceinline__ void build_x10(int row,
    const float* __restrict__ wxyz, const int* __restrict__ idx2, float* x){
  int p = row >> 4, b = p >> 12;
  int idx = idx2[row];
  const float* nw = wxyz + (size_t)p*3;
  const float* gw = wxyz + ((size_t)b*HWn + idx)*3;
  float n0=nw[0],n1=nw[1],n2=nw[2];
  float g0=gw[0],g1=gw[1],g2=gw[2];
  float d0=g0-n0, d1=g1-n1, d2=g2-n2;
  x[0]=n0;x[1]=n1;x[2]=n2; x[3]=g0;x[4]=g1;x[5]=g2;
  x[6]=d0;x[7]=d1;x[8]=d2; x[9]=sqrtf(d0*d0+d1*d1+d2*d2+1e-20f);
}

// ---------------- prep: norms, wxyz, weight transposes + f16 weights ----------------
__global__ __launch_bounds__(256) void k_prep(
    const float* __restrict__ warped_xyz, const float* __restrict__ lidar_z,
    const float* __restrict__ warped_points, const float* __restrict__ f2_points,
    const float* __restrict__ m1w0, const float* __restrict__ m1w1,
    const float* __restrict__ piw, const float* __restrict__ pcw,
    const float* __restrict__ m2w0, const float* __restrict__ m2w1,
    const float* __restrict__ m3w0, const float* __restrict__ m3w1,
    float* __restrict__ wxyz, float* __restrict__ normW, float* __restrict__ normF2,
    float* __restrict__ piwT, float* __restrict__ pcwT,
    _Float16* __restrict__ w1h, _Float16* __restrict__ w2h,
    _Float16* __restrict__ w3h, _Float16* __restrict__ w4h,
    _Float16* __restrict__ w5h, _Float16* __restrict__ w6h)
{
  int blk = blockIdx.x, tid = threadIdx.x;
  if (blk < 4096){
    int lane = tid & 63;
    int p = blk*4 + (tid >> 6);            // 0..16383
    const float* src; float* dst;
    if (p < Bn*HWn){ src = warped_points + (size_t)p*64; dst = normW + (size_t)p*64; }
    else { int q = p - Bn*HWn; src = f2_points + (size_t)q*64; dst = normF2 + (size_t)q*64; }
    float x = src[lane];
    float m = wred64(x) * (1.f/64.f);
    float d = x - m;
    float ss = wred64(d*d);
    float s = fmaxf(sqrtf(ss*(1.f/63.f)), 1e-12f);
    dst[lane] = d / s;
  } else if (blk < 4192){
    int e = (blk-4096)*256 + tid;          // < 24576
    wxyz[e] = warped_xyz[e] * lidar_z[e/3];
  } else if (blk < 4196){
    int e = (blk-4192)*256 + tid;          // < 1024
    if (e < 384){ piwT[(e & 63)*6  + (e >> 6)] = piw[e]; }
    else if (e < 1024){ int f = e-384; pcwT[(f & 63)*10 + (f >> 6)] = pcw[f]; }
  } else {
    int e = (blk-4196)*256 + tid;          // < 49152
    if (e < 12288){                        // w1h[j][k] : [128 out][96 in-pad]
      int j = e/96, k = e - j*96;
      w1h[e] = (k < 70) ? (_Float16)m1w0[k*128 + j] : (_Float16)0.f;
    } else if (e < 20480){                 // w2h[d][c] : [64][128]
      int f = e - 12288; int d = f >> 7, c = f & 127;
      w2h[f] = (_Float16)m1w1[c*64 + d];
    } else if (e < 28672){                 // w3h[d][c] : [64][128]
      int f = e - 20480; int d = f >> 7, c = f & 127;
      w3h[f] = (_Float16)m2w0[c*64 + d];
    } else if (e < 32768){                 // w4h[d][c] : [64][64]
      int f = e - 28672; int d = f >> 6, c = f & 63;
      w4h[f] = (_Float16)m2w1[c*64 + d];
    } else if (e < 45056){                 // w5h[d][c] : [64][192]
      int f = e - 32768; int d = f/192, c = f - 192*d;
      w5h[f] = (_Float16)m3w0[c*64 + d];
    } else {                               // w6h[d][c] : [64][64]
      int f = e - 45056; int d = f >> 6, c = f & 63;
      w6h[f] = (_Float16)m3w1[c*64 + d];
    }
  }
}

// ---------------- exact k-smallest: register-resident keys, per-wave hists ----------------
template<int K, bool WRITE_VALID>
__global__ __launch_bounds__(256) void k_knn(
    const float* __restrict__ qpts, const float* __restrict__ pts,
    int* __restrict__ oidx, float* __restrict__ ovalid)
{
  __shared__ int hist[4*256];
  __shared__ int wsum[4];
  __shared__ unsigned int sh_prefix;
  __shared__ int sh_rem, cnt_lt, cnt_eq;
  int b = blockIdx.x >> 12;
  int qi = blockIdx.x & 4095;
  int tid = threadIdx.x;
  int lane = tid & 63, wv = tid >> 6;
  const float* qp = qpts + ((size_t)(b*HWn+qi))*3;
  float qx=qp[0], qy=qp[1], qz=qp[2];
  const float* pb = pts + (size_t)b*Nn*3;
  unsigned int key[16];
  #pragma unroll
  for (int i=0;i<16;i++){
    int t = tid + i*256;
    float dx = __fsub_rn(qx, pb[t*3+0]);
    float dy = __fsub_rn(qy, pb[t*3+1]);
    float dz = __fsub_rn(qz, pb[t*3+2]);
    float d2 = __fadd_rn(__fadd_rn(__fmul_rn(dx,dx), __fmul_rn(dy,dy)), __fmul_rn(dz,dz));
    key[i] = __float_as_uint(d2);          // nonneg floats: uint order == float order
  }
  if (tid == 0){ cnt_lt = 0; cnt_eq = 0; }
  unsigned int active = 0xFFFFu;           // per-value prefix-match bit
  unsigned int prefix = 0; int rem = K;
  for (int shift = 24; shift >= 0; shift -= 8){
    __syncthreads();                       // hist reuse guard
    #pragma unroll
    for (int j=0;j<4;j++) hist[j*256 + tid] = 0;
    __syncthreads();
    #pragma unroll
    for (int i=0;i<16;i++){
      if (active & (1u<<i))
        atomicAdd(&hist[wv*256 + ((key[i] >> shift) & 255)], 1);
    }
    __syncthreads();
    int h = hist[tid] + hist[256+tid] + hist[512+tid] + hist[768+tid];
    int pref = h;
    #pragma unroll
    for (int m=1;m<64;m<<=1){ int t = __shfl_up(pref, m, 64); if (lane >= m) pref += t; }
    if (lane == 63) wsum[wv] = pref;
    __syncthreads();
    int off = 0;
    #pragma unroll
    for (int i=0;i<3;i++) if (i < wv) off += wsum[i];
    pref += off;                           // inclusive prefix over buckets 0..tid
    if (pref >= rem && (pref - h) < rem){
      sh_prefix = prefix | ((unsigned int)tid << shift);
      sh_rem = rem - (pref - h);
    }
    __syncthreads();
    prefix = sh_prefix; rem = sh_rem;
    unsigned int sel = (prefix >> shift) & 255;
    #pragma unroll
    for (int i=0;i<16;i++){
      if (((key[i] >> shift) & 255) != sel) active &= ~(1u<<i);
    }
  }
  unsigned int kth = prefix;               // exact k-th smallest key
  int nless = K - rem;                     // # strictly smaller
  size_t obase = ((size_t)(b*HWn+qi))*K;
  const unsigned int U100 = __float_as_uint(100.0f);  // DIST*DIST
  #pragma unroll
  for (int i=0;i<16;i++){
    unsigned int v = key[i];
    if (v <= kth){
      int s;
      if (v < kth) s = atomicAdd(&cnt_lt, 1);
      else { s = atomicAdd(&cnt_eq, 1); if (s >= rem) continue; s += nless; }
      oidx[obase+s] = tid + i*256;
      if constexpr (WRITE_VALID) ovalid[obase+s] = (v < U100) ? 1.f : 0.f;
    }
  }
}

// ---------------- build f16 X1 rows: [wxyz(3) f2xyz(3) prod(64) pad->96] ----------------
__global__ __launch_bounds__(256) void k_buildX1(
    const float* __restrict__ wxyz, const float* __restrict__ f2_xyz,
    const float* __restrict__ normW, const float* __restrict__ normF2,
    const int* __restrict__ idxq, _Float16* __restrict__ X1)
{
  int row = blockIdx.x*256 + threadIdx.x;
  float x[70];
  build_x70(row, wxyz, f2_xyz, normW, normF2, idxq, x);
  unsigned int* d32 = (unsigned int*)(X1 + (size_t)row*96);
  union { unsigned int u; _Float16 h[2]; } pk;
  #pragma unroll
  for (int c=0;c<35;c++){
    pk.h[0] = (_Float16)x[2*c]; pk.h[1] = (_Float16)x[2*c+1];
    d32[c] = pk.u;
  }
  #pragma unroll
  for (int c=35;c<48;c++) d32[c] = 0u;
}

// ---------------- Gram-matrix stats for pi_enc (7x7) and pc_enc (11x11) ----------------
__global__ __launch_bounds__(256) void k_gram(
    const float* __restrict__ wxyz, const float* __restrict__ f2_xyz,
    const int* __restrict__ idxq, const int* __restrict__ idx2,
    float* __restrict__ gram)
{
  __shared__ float sacc[66];
  int blk = blockIdx.x, tid = threadIdx.x, lane = tid & 63;
  if (blk < 64){
    float a[28];
    #pragma unroll
    for (int q=0;q<28;q++) a[q]=0.f;
    int g = blk*256 + tid;
    for (int s=0;s<16;s++){
      int row = g + s*16384;
      int p = row >> 5, b = p >> 12;
      int idx = idxq[row];
      const float* wx = wxyz + (size_t)p*3;
      const float* fx = f2_xyz + ((size_t)b*Nn + idx)*3;
      float xt[7] = {wx[0],wx[1],wx[2],fx[0],fx[1],fx[2],1.f};
      int q=0;
      #pragma unroll
      for (int i=0;i<7;i++)
        #pragma unroll
        for (int j=i;j<7;j++) a[q++] += xt[i]*xt[j];
    }
    if (tid < 28) sacc[tid]=0.f;
    __syncthreads();
    #pragma unroll
    for (int q=0;q<28;q++){
      float v = wred64(a[q]);
      if (lane==0) atomicAdd(&sacc[q], v);
    }
    __syncthreads();
    if (tid < 28) atomicAdd(&gram[tid], sacc[tid]);
  } else {
    float a[66];
    #pragma unroll
    for (int q=0;q<66;q++) a[q]=0.f;
    int g = (blk-64)*256 + tid;
    for (int s=0;s<16;s++){
      int row = g + s*8192;
      float x[10];
      build_x10(row, wxyz, idx2, x);
      float xt[11] = {x[0],x[1],x[2],x[3],x[4],x[5],x[6],x[7],x[8],x[9],1.f};
      int q=0;
      #pragma unroll
      for (int i=0;i<11;i++)
        #pragma unroll
        for (int j=i;j<11;j++) a[q++] += xt[i]*xt[j];
    }
    if (tid < 66) sacc[tid]=0.f;
    __syncthreads();
    #pragma unroll
    for (int q=0;q<66;q++){
      float v = wred64(a[q]);
      if (lane==0) atomicAdd(&sacc[q], v);
    }
    __syncthreads();
    if (tid < 66) atomicAdd(&gram[32+tid], sacc[tid]);
  }
}

__global__ __launch_bounds__(128) void k_gram_fin(
    const float* __restrict__ gram,
    const float* __restrict__ piw, const float* __restrict__ pib,
    const float* __restrict__ pcw, const float* __restrict__ pcb,
    float* stats)
{
  int tid = threadIdx.x;
  if (tid < 64){
    int c = tid;
    float wt[7];
    #pragma unroll
    for (int i=0;i<6;i++) wt[i] = piw[i*64+c];
    wt[6] = pib[c];
    const float* G = gram;
    float sum=0.f, ssq=0.f;
    #pragma unroll
    for (int i=0;i<7;i++){
      int offi = i*7 - (i*(i-1))/2;
      sum += wt[i]*G[offi + (6-i)];
      #pragma unroll
      for (int j=0;j<7;j++){
        int ii = i<j? i : j, jj = i<j? j : i;
        int o = ii*7 - (ii*(ii-1))/2 + (jj-ii);
        ssq += wt[i]*wt[j]*G[o];
      }
    }
    stats[2*256+c] = sum; stats[2*256+128+c] = ssq;
  } else {
    int c = tid-64;
    float wt[11];
    #pragma unroll
    for (int i=0;i<10;i++) wt[i] = pcw[i*64+c];
    wt[10] = pcb[c];
    const float* G = gram + 32;
    float sum=0.f, ssq=0.f;
    #pragma unroll
    for (int i=0;i<11;i++){
      int offi = i*11 - (i*(i-1))/2;
      sum += wt[i]*G[offi + (10-i)];
      #pragma unroll
      for (int j=0;j<11;j++){
        int ii = i<j? i : j, jj = i<j? j : i;
        int o = ii*11 - (ii*(ii-1))/2 + (jj-ii);
        ssq += wt[i]*wt[j]*G[o];
      }
    }
    stats[5*256+c] = sum; stats[5*256+128+c] = ssq;
  }
}

// ---------------- MFMA y1 stats: 4x64-row tiles/block, weights direct from global ----------------
__global__ __launch_bounds__(256) void k_mfma_stats1(
    const _Float16* __restrict__ X1, const _Float16* __restrict__ w1h,
    float* stats)
{
  __shared__ float ssum[128], sssq[128];
  int tid = threadIdx.x;
  if (tid < 128){ ssum[tid]=0.f; sssq[tid]=0.f; }
  __syncthreads();
  int wave = tid >> 6, lane = tid & 63;
  int quad = lane >> 4, n16 = lane & 15;
  float r1[8], r2[8];
  #pragma unroll
  for (int i=0;i<8;i++){ r1[i]=0.f; r2[i]=0.f; }
  for (int t=0;t<4;t++){
    int m0 = blockIdx.x*256 + t*64 + wave*16;
    const _Float16* xr = X1 + (size_t)(m0 + n16)*96 + quad*8;
    f16x8 a0 = *(const f16x8*)(xr);
    f16x8 a1 = *(const f16x8*)(xr + 32);
    f16x8 a2 = *(const f16x8*)(xr + 64);
    #pragma unroll
    for (int nt = 0; nt < 8; nt++){
      const _Float16* wr = w1h + (size_t)(nt*16 + n16)*96 + quad*8;
      f16x8 b0 = *(const f16x8*)(wr);
      f16x8 b1 = *(const f16x8*)(wr + 32);
      f16x8 b2 = *(const f16x8*)(wr + 64);
      f32x4 acc = {0.f,0.f,0.f,0.f};
      acc = __builtin_amdgcn_mfma_f32_16x16x32_f16(a0, b0, acc, 0,0,0);
      acc = __builtin_amdgcn_mfma_f32_16x16x32_f16(a1, b1, acc, 0,0,0);
      acc = __builtin_amdgcn_mfma_f32_16x16x32_f16(a2, b2, acc, 0,0,0);
      float s1 = acc[0]+acc[1]+acc[2]+acc[3];
      float s2 = acc[0]*acc[0]+acc[1]*acc[1]+acc[2]*acc[2]+acc[3]*acc[3];
      s1 += __shfl_xor(s1, 16, 64); s1 += __shfl_xor(s1, 32, 64);
      s2 += __shfl_xor(s2, 16, 64); s2 += __shfl_xor(s2, 32, 64);
      r1[nt] += s1; r2[nt] += s2;
    }
  }
  if (quad == 0){
    #pragma unroll
    for (int nt=0;nt<8;nt++){
      atomicAdd(&ssum[nt*16+n16], r1[nt]); atomicAdd(&sssq[nt*16+n16], r2[nt]);
    }
  }
  __syncthreads();
  if (tid < 128){ atomicAdd(&stats[tid], ssum[tid]); atomicAdd(&stats[128+tid], sssq[tid]); }
}

// ---------------- MFMA m1: 4 tiles/block; y1 -> BN/leaky -> t (LDS) -> x W2 -> y2 ----------------
__global__ __launch_bounds__(256) void k_mfma_m1(
    const _Float16* __restrict__ X1, const _Float16* __restrict__ w1h,
    const _Float16* __restrict__ w2h,
    const float* __restrict__ m1g0, const float* __restrict__ m1e0,
    float* stats, _Float16* __restrict__ y2h)
{
  __shared__ _Float16 st[64*136];
  __shared__ float sc1[128], sh1[128], ssum[64], sssq[64];
  int tid = threadIdx.x;
  if (tid < 128){
    float s,h; bn_param(stats, tid, INV_R1, m1g0, m1e0, s, h);
    sc1[tid]=s; sh1[tid]=h;
  }
  if (tid < 64){ ssum[tid]=0.f; sssq[tid]=0.f; }
  __syncthreads();
  int wave = tid >> 6, lane = tid & 63;
  int quad = lane >> 4, n16 = lane & 15;
  float r1[4], r2[4];
  #pragma unroll
  for (int i=0;i<4;i++){ r1[i]=0.f; r2[i]=0.f; }
  for (int t=0;t<4;t++){
    int m0 = blockIdx.x*256 + t*64 + wave*16;
    const _Float16* xr = X1 + (size_t)(m0 + n16)*96 + quad*8;
    f16x8 a0 = *(const f16x8*)(xr);
    f16x8 a1 = *(const f16x8*)(xr + 32);
    f16x8 a2 = *(const f16x8*)(xr + 64);
    #pragma unroll
    for (int nt = 0; nt < 8; nt++){
      const _Float16* wr = w1h + (size_t)(nt*16 + n16)*96 + quad*8;
      f16x8 b0 = *(const f16x8*)(wr);
      f16x8 b1 = *(const f16x8*)(wr + 32);
      f16x8 b2 = *(const f16x8*)(wr + 64);
      f32x4 acc = {0.f,0.f,0.f,0.f};
      acc = __builtin_amdgcn_mfma_f32_16x16x32_f16(a0, b0, acc, 0,0,0);
      acc = __builtin_amdgcn_mfma_f32_16x16x32_f16(a1, b1, acc, 0,0,0);
      acc = __builtin_amdgcn_mfma_f32_16x16x32_f16(a2, b2, acc, 0,0,0);
      int ch = nt*16 + n16;
      float sc = sc1[ch], sh = sh1[ch];
      #pragma unroll
      for (int r=0;r<4;r++){
        float v = leakyf(acc[r]*sc + sh);
        st[(size_t)(wave*16 + quad*4 + r)*136 + ch] = (_Float16)v;
      }
    }
    __syncthreads();
    const _Float16* tr = st + (size_t)(wave*16 + n16)*136 + quad*8;
    f16x8 t0 = *(const f16x8*)(tr);
    f16x8 t1 = *(const f16x8*)(tr + 32);
    f16x8 t2 = *(const f16x8*)(tr + 64);
    f16x8 t3 = *(const f16x8*)(tr + 96);
    #pragma unroll
    for (int nt = 0; nt < 4; nt++){
      const _Float16* wr = w2h + (size_t)(nt*16 + n16)*128 + quad*8;
      f16x8 b0 = *(const f16x8*)(wr);
      f16x8 b1 = *(const f16x8*)(wr + 32);
      f16x8 b2 = *(const f16x8*)(wr + 64);
      f16x8 b3 = *(const f16x8*)(wr + 96);
      f32x4 acc = {0.f,0.f,0.f,0.f};
      acc = __builtin_amdgcn_mfma_f32_16x16x32_f16(t0, b0, acc, 0,0,0);
      acc = __builtin_amdgcn_mfma_f32_16x16x32_f16(t1, b1, acc, 0,0,0);
      acc = __builtin_amdgcn_mfma_f32_16x16x32_f16(t2, b2, acc, 0,0,0);
      acc = __builtin_amdgcn_mfma_f32_16x16x32_f16(t3, b3, acc, 0,0,0);
      int ch = nt*16 + n16;
      #pragma unroll
      for (int r=0;r<4;r++){
        int rowg = blockIdx.x*256 + t*64 + wave*16 + quad*4 + r;
        y2h[(size_t)rowg*64 + ch] = (_Float16)acc[r];
      }
      float s1 = acc[0]+acc[1]+acc[2]+acc[3];
      float s2 = acc[0]*acc[0]+acc[1]*acc[1]+acc[2]*acc[2]+acc[3]*acc[3];
      s1 += __shfl_xor(s1, 16, 64); s1 += __shfl_xor(s1, 32, 64);
      s2 += __shfl_xor(s2, 16, 64); s2 += __shfl_xor(s2, 32, 64);
      r1[nt] += s1; r2[nt] += s2;
    }
    __syncthreads();
  }
  if (quad == 0){
    #pragma unroll
    for (int nt=0;nt<4;nt++){
      atomicAdd(&ssum[nt*16+n16], r1[nt]); atomicAdd(&sssq[nt*16+n16], r2[nt]);
    }
  }
  __syncthreads();
  if (tid < 64){ atomicAdd(&stats[1*256+tid], ssum[tid]); atomicAdd(&stats[1*256+128+tid], sssq[tid]); }
}

// ---------------- MFMA m2a: 4 tiles/block; u=[pi_enc|feat] in LDS, y3 = u x W3 ----------------
__global__ __launch_bounds__(256) void k_mfma_m2a(
    const float* __restrict__ wxyz, const float* __restrict__ f2_xyz,
    const int* __restrict__ idxq,
    const float* __restrict__ piwT, const float* __restrict__ pib,
    const float* __restrict__ pig, const float* __restrict__ pie,
    const float* __restrict__ m1g1, const float* __restrict__ m1e1,
    const _Float16* __restrict__ y2h, const _Float16* __restrict__ w3h,
    float* stats, _Float16* __restrict__ y3h)
{
  __shared__ _Float16 su[64*136];
  __shared__ float spw[384];
  __shared__ float scp[64], shp[64], sc2[64], sh2[64], ssum[64], sssq[64];
  int tid = threadIdx.x;
  for (int d = tid; d < 384; d += 256) spw[d] = piwT[d];
  if (tid < 64){
    float s,h;
    bn_param(stats+2*256, tid, INV_R1, pig,  pie,  s, h); scp[tid]=s; shp[tid]=h;
    bn_param(stats+1*256, tid, INV_R1, m1g1, m1e1, s, h); sc2[tid]=s; sh2[tid]=h;
    ssum[tid]=0.f; sssq[tid]=0.f;
  }
  __syncthreads();
  int r = tid & 63, cg = tid >> 6;
  int wave = tid >> 6, lane = tid & 63, quad = lane >> 4, n16 = lane & 15;
  float r1[4], r2[4];
  #pragma unroll
  for (int i=0;i<4;i++){ r1[i]=0.f; r2[i]=0.f; }
  for (int t=0;t<4;t++){
    int rowg = blockIdx.x*256 + t*64 + r;
    {
      int p = rowg >> 5, b = p >> 12;
      int idx = idxq[rowg];
      const float* wx = wxyz + (size_t)p*3;
      const float* fx = f2_xyz + ((size_t)b*Nn + idx)*3;
      float x0=wx[0],x1=wx[1],x2=wx[2],x3=fx[0],x4=fx[1],x5=fx[2];
      #pragma unroll
      for (int jj=0;jj<16;jj++){
        int j = cg*16 + jj;
        const float* pw = spw + j*6;
        float e = pib[j] + x0*pw[0]+x1*pw[1]+x2*pw[2]+x3*pw[3]+x4*pw[4]+x5*pw[5];
        su[r*136 + j] = (_Float16)leakyf(e*scp[j] + shp[j]);
      }
      const f16x8* yr = (const f16x8*)(y2h + (size_t)rowg*64 + cg*16);
      f16x8 q0 = yr[0], q1 = yr[1];
      #pragma unroll
      for (int jj=0;jj<8;jj++){
        int c = cg*16 + jj;
        su[r*136 + 64 + c] = (_Float16)leakyf((float)q0[jj]*sc2[c] + sh2[c]);
      }
      #pragma unroll
      for (int jj=0;jj<8;jj++){
        int c = cg*16 + 8 + jj;
        su[r*136 + 64 + c] = (_Float16)leakyf((float)q1[jj]*sc2[c] + sh2[c]);
      }
    }
    __syncthreads();
    const _Float16* ur = su + (size_t)(wave*16 + n16)*136 + quad*8;
    f16x8 a0 = *(const f16x8*)(ur);
    f16x8 a1 = *(const f16x8*)(ur + 32);
    f16x8 a2 = *(const f16x8*)(ur + 64);
    f16x8 a3 = *(const f16x8*)(ur + 96);
    #pragma unroll
    for (int nt = 0; nt < 4; nt++){
      const _Float16* wr = w3h + (size_t)(nt*16 + n16)*128 + quad*8;
      f16x8 b0 = *(const f16x8*)(wr);
      f16x8 b1 = *(const f16x8*)(wr + 32);
      f16x8 b2 = *(const f16x8*)(wr + 64);
      f16x8 b3 = *(const f16x8*)(wr + 96);
      f32x4 acc = {0.f,0.f,0.f,0.f};
      acc = __builtin_amdgcn_mfma_f32_16x16x32_f16(a0, b0, acc, 0,0,0);
      acc = __builtin_amdgcn_mfma_f32_16x16x32_f16(a1, b1, acc, 0,0,0);
      acc = __builtin_amdgcn_mfma_f32_16x16x32_f16(a2, b2, acc, 0,0,0);
      acc = __builtin_amdgcn_mfma_f32_16x16x32_f16(a3, b3, acc, 0,0,0);
      int ch = nt*16 + n16;
      #pragma unroll
      for (int rr=0;rr<4;rr++){
        int rg = blockIdx.x*256 + t*64 + wave*16 + quad*4 + rr;
        y3h[(size_t)rg*64 + ch] = (_Float16)acc[rr];
      }
      float s1 = acc[0]+acc[1]+acc[2]+acc[3];
      float s2 = acc[0]*acc[0]+acc[1]*acc[1]+acc[2]*acc[2]+acc[3]*acc[3];
      s1 += __shfl_xor(s1, 16, 64); s1 += __shfl_xor(s1, 32, 64);
      s2 += __shfl_xor(s2, 16, 64); s2 += __shfl_xor(s2, 32, 64);
      r1[nt] += s1; r2[nt] += s2;
    }
    __syncthreads();
  }
  if (quad == 0){
    #pragma unroll
    for (int nt=0;nt<4;nt++){
      atomicAdd(&ssum[nt*16+n16], r1[nt]); atomicAdd(&sssq[nt*16+n16], r2[nt]);
    }
  }
  __syncthreads();
  if (tid < 64){ atomicAdd(&stats[3*256+tid], ssum[tid]); atomicAdd(&stats[3*256+128+tid], sssq[tid]); }
}

// ---------------- generic MFMA pointwise 64->64, 4 tiles/block ----------------
__global__ __launch_bounds__(256) void k_mfma_pw64(
    const _Float16* __restrict__ yin, const _Float16* __restrict__ wh,
    const float* __restrict__ g, const float* __restrict__ e,
    const float* statsIn, float* statsOut, float inv_n,
    _Float16* __restrict__ yout)
{
  __shared__ _Float16 stt[64*72];
  __shared__ float sc[64], sh[64], ssum[64], sssq[64];
  int tid = threadIdx.x;
  if (tid < 64){
    float s,h; bn_param(statsIn, tid, inv_n, g, e, s, h);
    sc[tid]=s; sh[tid]=h; ssum[tid]=0.f; sssq[tid]=0.f;
  }
  __syncthreads();
  int r = tid & 63, cg = tid >> 6;
  int wave = tid >> 6, lane = tid & 63, quad = lane >> 4, n16 = lane & 15;
  float r1[4], r2[4];
  #pragma unroll
  for (int i=0;i<4;i++){ r1[i]=0.f; r2[i]=0.f; }
  for (int t=0;t<4;t++){
    int rowg = blockIdx.x*256 + t*64 + r;
    const f16x8* yr = (const f16x8*)(yin + (size_t)rowg*64 + cg*16);
    f16x8 q0 = yr[0], q1 = yr[1];
    #pragma unroll
    for (int jj=0;jj<8;jj++){
      int c = cg*16 + jj;
      stt[r*72 + c] = (_Float16)leakyf((float)q0[jj]*sc[c] + sh[c]);
    }
    #pragma unroll
    for (int jj=0;jj<8;jj++){
      int c = cg*16 + 8 + jj;
      stt[r*72 + c] = (_Float16)leakyf((float)q1[jj]*sc[c] + sh[c]);
    }
    __syncthreads();
    const _Float16* tr = stt + (size_t)(wave*16 + n16)*72 + quad*8;
    f16x8 a0 = *(const f16x8*)(tr);
    f16x8 a1 = *(const f16x8*)(tr + 32);
    #pragma unroll
    for (int nt = 0; nt < 4; nt++){
      const _Float16* wr = wh + (size_t)(nt*16 + n16)*64 + quad*8;
      f16x8 b0 = *(const f16x8*)(wr);
      f16x8 b1 = *(const f16x8*)(wr + 32);
      f32x4 acc = {0.f,0.f,0.f,0.f};
      acc = __builtin_amdgcn_mfma_f32_16x16x32_f16(a0, b0, acc, 0,0,0);
      acc = __builtin_amdgcn_mfma_f32_16x16x32_f16(a1, b1, acc, 0,0,0);
      int ch = nt*16 + n16;
      #pragma unroll
      for (int rr=0;rr<4;rr++){
        int rg = blockIdx.x*256 + t*64 + wave*16 + quad*4 + rr;
        yout[(size_t)rg*64 + ch] = (_Float16)acc[rr];
      }
      float s1 = acc[0]+acc[1]+acc[2]+acc[3];
      float s2 = acc[0]*acc[0]+acc[1]*acc[1]+acc[2]*acc[2]+acc[3]*acc[3];
      s1 += __shfl_xor(s1, 16, 64); s1 += __shfl_xor(s1, 32, 64);
      s2 += __shfl_xor(s2, 16, 64); s2 += __shfl_xor(s2, 32, 64);
      r1[nt] += s1; r2[nt] += s2;
    }
    __syncthreads();
  }
  if (quad == 0){
    #pragma unroll
    for (int nt=0;nt<4;nt++){
      atomicAdd(&ssum[nt*16+n16], r1[nt]); atomicAdd(&sssq[nt*16+n16], r2[nt]);
    }
  }
  __syncthreads();
  if (tid < 64){ atomicAdd(&statsOut[tid], ssum[tid]); atomicAdd(&statsOut[128+tid], sssq[tid]); }
}

// ---------------- MFMA m3a: 4 tiles/block; v=[pc_enc|wp|pif1_g] (192ch), y5 = v x W5 ----------------
__global__ __launch_bounds__(256) void k_mfma_m3a(
    const float* __restrict__ wxyz, const float* __restrict__ warped_points,
    const _Float16* __restrict__ pif1h, const int* __restrict__ idx2,
    const float* __restrict__ pcwT, const float* __restrict__ pcb,
    const float* __restrict__ pcg, const float* __restrict__ pce,
    const _Float16* __restrict__ w5h,
    float* stats, _Float16* __restrict__ y5h)
{
  __shared__ _Float16 sv[64*200];
  __shared__ float spw[640];
  __shared__ float scp[64], shp[64], ssum[64], sssq[64];
  int tid = threadIdx.x;
  for (int d = tid; d < 640; d += 256) spw[d] = pcwT[d];
  if (tid < 64){
    float s,h; bn_param(stats+5*256, tid, INV_R2, pcg, pce, s, h);
    scp[tid]=s; shp[tid]=h; ssum[tid]=0.f; sssq[tid]=0.f;
  }
  __syncthreads();
  int r = tid & 63, cg = tid >> 6;
  int wave = tid >> 6, lane = tid & 63, quad = lane >> 4, n16 = lane & 15;
  float r1[4], r2[4];
  #pragma unroll
  for (int i=0;i<4;i++){ r1[i]=0.f; r2[i]=0.f; }
  for (int t=0;t<4;t++){
    int rowg = blockIdx.x*256 + t*64 + r;
    {
      int p = rowg >> 4, b = p >> 12;
      int idx = idx2[rowg];
      float x[10];
      build_x10(rowg, wxyz, idx2, x);
      #pragma unroll
      for (int jj=0;jj<16;jj++){
        int j = cg*16 + jj;
        const float* pw = spw + j*10;
        float e = pcb[j];
        #pragma unroll
        for (int i=0;i<10;i++) e += x[i]*pw[i];
        sv[r*200 + j] = (_Float16)leakyf(e*scp[j] + shp[j]);
      }
      const float4* wp = (const float4*)(warped_points + (size_t)p*64 + cg*16);
      #pragma unroll
      for (int v4=0; v4<4; v4++){
        float4 q = wp[v4];
        int c = 64 + cg*16 + v4*4;
        sv[r*200 + c + 0] = (_Float16)q.x;
        sv[r*200 + c + 1] = (_Float16)q.y;
        sv[r*200 + c + 2] = (_Float16)q.z;
        sv[r*200 + c + 3] = (_Float16)q.w;
      }
      const f16x8* pg = (const f16x8*)(pif1h + ((size_t)(b*HWn) + idx)*64 + cg*16);
      f16x8 g0 = pg[0], g1 = pg[1];
      #pragma unroll
      for (int jj=0;jj<8;jj++) sv[r*200 + 128 + cg*16 + jj] = g0[jj];
      #pragma unroll
      for (int jj=0;jj<8;jj++) sv[r*200 + 136 + cg*16 + jj] = g1[jj];
    }
    __syncthreads();
    const _Float16* vr = sv + (size_t)(wave*16 + n16)*200 + quad*8;
    f16x8 a0 = *(const f16x8*)(vr);
    f16x8 a1 = *(const f16x8*)(vr + 32);
    f16x8 a2 = *(const f16x8*)(vr + 64);
    f16x8 a3 = *(const f16x8*)(vr + 96);
    f16x8 a4 = *(const f16x8*)(vr + 128);
    f16x8 a5 = *(const f16x8*)(vr + 160);
    #pragma unroll
    for (int nt = 0; nt < 4; nt++){
      const _Float16* wr = w5h + (size_t)(nt*16 + n16)*192 + quad*8;
      f32x4 acc = {0.f,0.f,0.f,0.f};
      acc = __builtin_amdgcn_mfma_f32_16x16x32_f16(a0, *(const f16x8*)(wr),       acc, 0,0,0);
      acc = __builtin_amdgcn_mfma_f32_16x16x32_f16(a1, *(const f16x8*)(wr + 32),  acc, 0,0,0);
      acc = __builtin_amdgcn_mfma_f32_16x16x32_f16(a2, *(const f16x8*)(wr + 64),  acc, 0,0,0);
      acc = __builtin_amdgcn_mfma_f32_16x16x32_f16(a3, *(const f16x8*)(wr + 96),  acc, 0,0,0);
      acc = __builtin_amdgcn_mfma_f32_16x16x32_f16(a4, *(const f16x8*)(wr + 128), acc, 0,0,0);
      acc = __builtin_amdgcn_mfma_f32_16x16x32_f16(a5, *(const f16x8*)(wr + 160), acc, 0,0,0);
      int ch = nt*16 + n16;
      #pragma unroll
      for (int rr=0;rr<4;rr++){
        int rg = blockIdx.x*256 + t*64 + wave*16 + quad*4 + rr;
        y5h[(size_t)rg*64 + ch] = (_Float16)acc[rr];
      }
      float s1 = acc[0]+acc[1]+acc[2]+acc[3];
      float s2 = acc[0]*acc[0]+acc[1]*acc[1]+acc[2]*acc[2]+acc[3]*acc[3];
      s1 += __shfl_xor(s1, 16, 64); s1 += __shfl_xor(s1, 32, 64);
      s2 += __shfl_xor(s2, 16, 64); s2 += __shfl_xor(s2, 32, 64);
      r1[nt] += s1; r2[nt] += s2;
    }
    __syncthreads();
  }
  if (quad == 0){
    #pragma unroll
    for (int nt=0;nt<4;nt++){
      atomicAdd(&ssum[nt*16+n16], r1[nt]); atomicAdd(&sssq[nt*16+n16], r2[nt]);
    }
  }
  __syncthreads();
  if (tid < 64){ atomicAdd(&stats[6*256+tid], ssum[tid]); atomicAdd(&stats[6*256+128+tid], sssq[tid]); }
}

// ---------------- stage-1 softmax over KQ, weighted sum of feat -> pif1 (f16) ----------------
__global__ __launch_bounds__(256) void k_softmax1(
    const _Float16* __restrict__ y2h, const _Float16* __restrict__ y4h,
    const float* stats,
    const float* __restrict__ m1g1, const float* __restrict__ m1e1,
    const float* __restrict__ m2g1, const float* __restrict__ m2e1,
    _Float16* __restrict__ pif1h)
{
  int tid = threadIdx.x, lane = tid & 63;
  int p = blockIdx.x*4 + (tid >> 6);
  int d = lane;
  float sc2,sh2,sc4,sh4;
  bn_param(stats+1*256, d, INV_R1, m1g1, m1e1, sc2, sh2);
  bn_param(stats+4*256, d, INV_R1, m2g1, m2e1, sc4, sh4);
  size_t rb = (size_t)p*KQn;
  float v[32]; float mx = -1e30f;
  #pragma unroll
  for (int k=0;k<32;k++){
    float t = leakyf((float)y4h[(rb+k)*64 + d]*sc4 + sh4);
    v[k] = t; mx = fmaxf(mx, t);
  }
  float se = 0.f;
  #pragma unroll
  for (int k=0;k<32;k++){ float ev = __expf(v[k]-mx); v[k]=ev; se += ev; }
  float inv = 1.f/se, acc = 0.f;
  #pragma unroll
  for (int k=0;k<32;k++){
    float f = leakyf((float)y2h[(rb+k)*64 + d]*sc2 + sh2);
    acc += v[k]*f;
  }
  pif1h[(size_t)p*64 + d] = (_Float16)(acc*inv);
}

// ---------------- stage-2 masked softmax over KN, weighted sum of gathered pif1 ----------------
__global__ __launch_bounds__(256) void k_softmax2(
    const _Float16* __restrict__ y6h, const _Float16* __restrict__ pif1h,
    const int* __restrict__ idx2, const float* __restrict__ validf,
    const float* stats,
    const float* __restrict__ m3g1, const float* __restrict__ m3e1,
    float* __restrict__ out)
{
  int tid = threadIdx.x, lane = tid & 63;
  int p = blockIdx.x*4 + (tid >> 6);
  int b = p >> 12;
  int d = lane;
  float sc,sh; bn_param(stats+7*256, d, INV_R2, m3g1, m3e1, sc, sh);
  size_t rb = (size_t)p*KNn;
  float v[16]; float mx = -1e30f;
  #pragma unroll
  for (int k=0;k<16;k++){
    float t = leakyf((float)y6h[(rb+k)*64 + d]*sc + sh);
    t = (validf[rb+k] > 0.5f) ? t : -1e10f;
    v[k] = t; mx = fmaxf(mx, t);
  }
  float se = 0.f;
  #pragma unroll
  for (int k=0;k<16;k++){ float ev = __expf(v[k]-mx); v[k]=ev; se += ev; }
  float inv = 1.f/se, acc = 0.f;
  #pragma unroll
  for (int k=0;k<16;k++){
    int idx = idx2[rb+k];
    acc += v[k]*(float)pif1h[((size_t)(b*HWn) + idx)*64 + d];
  }
  out[(size_t)p*64 + d] = acc*inv;
}

// ---------------- launcher ----------------
extern "C" void kernel_launch(void* const* d_in, const int* in_sizes, int n_in,
                              void* d_out, int out_size, void* d_ws, size_t ws_size,
                              hipStream_t stream)
{
  (void)in_sizes; (void)n_in; (void)out_size; (void)ws_size;
  const float* xyz_proj      = (const float*)d_in[0];
  const float* warped_xyz    = (const float*)d_in[1];
  const float* warped_points = (const float*)d_in[2];
  const float* f2_xyz        = (const float*)d_in[4];
  const float* f2_points     = (const float*)d_in[5];
  const float* lidar_z       = (const float*)d_in[6];
  const float* m1w0=(const float*)d_in[7],  *m1g0=(const float*)d_in[9],  *m1e0=(const float*)d_in[10];
  const float* m1w1=(const float*)d_in[11], *m1g1=(const float*)d_in[13], *m1e1=(const float*)d_in[14];
  const float* piw =(const float*)d_in[15], *pib =(const float*)d_in[16], *pig =(const float*)d_in[17], *pie =(const float*)d_in[18];
  const float* m2w0=(const float*)d_in[19], *m2g0=(const float*)d_in[21], *m2e0=(const float*)d_in[22];
  const float* m2w1=(const float*)d_in[23], *m2g1=(const float*)d_in[25], *m2e1=(const float*)d_in[26];
  const float* pcw =(const float*)d_in[27], *pcb =(const float*)d_in[28], *pcg =(const float*)d_in[29], *pce =(const float*)d_in[30];
  const float* m3w0=(const float*)d_in[31], *m3g0=(const float*)d_in[33], *m3e0=(const float*)d_in[34];
  const float* m3w1=(const float*)d_in[35], *m3g1=(const float*)d_in[37], *m3e1=(const float*)d_in[38];
  float* out = (float*)d_out;

  float* ws     = (float*)d_ws;
  float* wxyz   = ws;                        // 24576
  float* normW  = wxyz   + 24576;            // 524288
  float* normF2 = normW  + 524288;           // 524288
  float* piwT   = normF2 + 524288;           // 384
  float* pcwT   = piwT   + 384;              // 640
  float* stats  = pcwT   + 640;              // 2048
  float* gram   = stats  + 2048;             // 128
  int*   idxq   = (int*)(gram + 128);        // 262144
  int*   idx2   = idxq   + 262144;           // 131072
  float* validf = (float*)(idx2 + 131072);   // 131072
  _Float16* pif1h = (_Float16*)(validf + 131072);   // 1048576 f16 = 524288 floats
  float* X1f    = validf + 131072 + 524288;
  _Float16* X1  = (_Float16*)X1f;            // 25165824 f16 = 12582912 floats
  float* y2f    = X1f + 12582912;
  _Float16* y2h = (_Float16*)y2f;            // 16777216 f16 = 8388608 floats
  float* y3f    = y2f + 8388608;
  _Float16* y3h = (_Float16*)y3f;            // 8388608 floats
  float* whb    = y3f + 8388608;             // f16 weights: 49152 f16 = 24576 floats
  _Float16* w1h = (_Float16*)whb;            // 12288
  _Float16* w2h = w1h + 12288;               // 8192
  _Float16* w3h = w2h + 8192;                // 8192
  _Float16* w4h = w3h + 8192;                // 4096
  _Float16* w5h = w4h + 4096;                // 12288
  _Float16* w6h = w5h + 12288;               // 4096
  // aliases (regions dead by the time they're overwritten):
  _Float16* y4h = (_Float16*)X1f;            // X1 dead after k_mfma_m1
  _Float16* y5h = (_Float16*)(X1f + 8388608);
  _Float16* y6h = y3h;                       // y3 dead after first k_mfma_pw64

  hipMemsetAsync(stats, 0, (2048+128)*sizeof(float), stream);
  k_prep<<<4388,256,0,stream>>>(warped_xyz, lidar_z, warped_points, f2_points,
                                m1w0, m1w1, piw, pcw, m2w0, m2w1, m3w0, m3w1,
                                wxyz, normW, normF2, piwT, pcwT,
                                w1h, w2h, w3h, w4h, w5h, w6h);
  k_knn<32,false><<<8192,256,0,stream>>>(warped_xyz, f2_xyz, idxq, nullptr);
  k_knn<16,true ><<<8192,256,0,stream>>>(xyz_proj, xyz_proj, idx2, validf);
  k_buildX1<<<1024,256,0,stream>>>(wxyz, f2_xyz, normW, normF2, idxq, X1);
  k_gram<<<96,256,0,stream>>>(wxyz, f2_xyz, idxq, idx2, gram);
  k_gram_fin<<<1,128,0,stream>>>(gram, piw, pib, pcw, pcb, stats);
  k_mfma_stats1<<<1024,256,0,stream>>>(X1, w1h, stats);
  k_mfma_m1<<<1024,256,0,stream>>>(X1, w1h, w2h, m1g0, m1e0, stats, y2h);
  k_mfma_m2a<<<1024,256,0,stream>>>(wxyz, f2_xyz, idxq, piwT, pib, pig, pie,
                                    m1g1, m1e1, y2h, w3h, stats, y3h);
  k_mfma_pw64<<<1024,256,0,stream>>>(y3h, w4h, m2g0, m2e0,
                                     stats+3*256, stats+4*256, INV_R1, y4h);
  k_softmax1<<<2048,256,0,stream>>>(y2h, y4h, stats, m1g1, m1e1, m2g1, m2e1, pif1h);
  k_mfma_m3a<<<512,256,0,stream>>>(wxyz, warped_points, pif1h, idx2,
                                   pcwT, pcb, pcg, pce, w5h, stats, y5h);
  k_mfma_pw64<<<512,256,0,stream>>>(y5h, w6h, m3g0, m3e0,
                                    stats+6*256, stats+7*256, INV_R2, y6h);
  k_softmax2<<<2048,256,0,stream>>>(y6h, pif1h, idx2, validf, stats, m3g1, m3e1, out);
}

// Round 7
// 576.385 us; speedup vs baseline: 2.6913x; 1.1440x over previous
//
#include <hip/hip_runtime.h>
#include <math.h>

// ---------------- problem constants ----------------
constexpr int Bn  = 2;
constexpr int HWn = 4096;     // H*W
constexpr int Nn  = 4096;
constexpr int KQn = 32;
constexpr int KNn = 16;
constexpr float INV_R1 = 1.0f/262144.0f;   // exact pow2
constexpr float INV_R2 = 1.0f/131072.0f;   // exact pow2

typedef _Float16 f16x8 __attribute__((ext_vector_type(8)));
typedef float    f32x4 __attribute__((ext_vector_type(4)));

__device__ __forceinline__ float wred64(float v){
  #pragma unroll
  for (int m = 32; m > 0; m >>= 1) v += __shfl_xor(v, m, 64);
  return v;
}
__device__ __forceinline__ float leakyf(float v){ return v > 0.f ? v : 0.1f*v; }

__device__ __forceinline__ void bn_param(const float* st, int c, float inv_n,
                                         const float* g, const float* e,
                                         float& sc, float& sh){
  float mu  = st[c]*inv_n;
  float var = st[128+c]*inv_n - mu*mu;
  float s   = g[c]*rsqrtf(var + 1e-5f);
  sc = s; sh = e[c] - mu*s;
}

// Build the 70-channel stage-1 input row: [wxyz(3), f2_xyz[idx](3), normW*normF2(64)]
__device__ __forceinline__ void build_x70(int row,
    const float* __restrict__ wxyz, const float* __restrict__ f2_xyz,
    const float* __restrict__ normW, const float* __restrict__ normF2,
    const int* __restrict__ idxq, float* x){
  int p = row >> 5;
  int b = p >> 12;
  int idx = idxq[row];
  const float* wx = wxyz + (size_t)p*3;
  const float* fx = f2_xyz + ((size_t)b*Nn + idx)*3;
  x[0]=wx[0]; x[1]=wx[1]; x[2]=wx[2];
  x[3]=fx[0]; x[4]=fx[1]; x[5]=fx[2];
  const float4* nw = (const float4*)(normW  + (size_t)p*64);
  const float4* nf = (const float4*)(normF2 + ((size_t)b*Nn + idx)*64);
  #pragma unroll
  for (int c=0;c<16;c++){
    float4 a = nw[c], q = nf[c];
    x[6+4*c+0]=a.x*q.x; x[6+4*c+1]=a.y*q.y; x[6+4*c+2]=a.z*q.z; x[6+4*c+3]=a.w*q.w;
  }
}

// Build the 10-channel stage-2 geometry row
__device__ __forceinline__ void build_x10(int row,
    const float* __restrict__ wxyz, const int* __restrict__ idx2, float* x){
  int p = row >> 4, b = p >> 12;
  int idx = idx2[row];
  const float* nw = wxyz + (size_t)p*3;
  const float* gw = wxyz + ((size_t)b*HWn + idx)*3;
  float n0=nw[0],n1=nw[1],n2=nw[2];
  float g0=gw[0],g1=gw[1],g2=gw[2];
  float d0=g0-n0, d1=g1-n1, d2=g2-n2;
  x[0]=n0;x[1]=n1;x[2]=n2; x[3]=g0;x[4]=g1;x[5]=g2;
  x[6]=d0;x[7]=d1;x[8]=d2; x[9]=sqrtf(d0*d0+d1*d1+d2*d2+1e-20f);
}

// ---------------- prep: norms, wxyz, weight transposes + f16 weights ----------------
__global__ __launch_bounds__(256) void k_prep(
    const float* __restrict__ warped_xyz, const float* __restrict__ lidar_z,
    const float* __restrict__ warped_points, const float* __restrict__ f2_points,
    const float* __restrict__ m1w0, const float* __restrict__ m1w1,
    const float* __restrict__ piw, const float* __restrict__ pcw,
    const float* __restrict__ m2w0, const float* __restrict__ m2w1,
    const float* __restrict__ m3w0, const float* __restrict__ m3w1,
    float* __restrict__ wxyz, float* __restrict__ normW, float* __restrict__ normF2,
    float* __restrict__ piwT, float* __restrict__ pcwT,
    _Float16* __restrict__ w1h, _Float16* __restrict__ w2h,
    _Float16* __restrict__ w3h, _Float16* __restrict__ w4h,
    _Float16* __restrict__ w5h, _Float16* __restrict__ w6h)
{
  int blk = blockIdx.x, tid = threadIdx.x;
  if (blk < 4096){
    int lane = tid & 63;
    int p = blk*4 + (tid >> 6);            // 0..16383
    const float* src; float* dst;
    if (p < Bn*HWn){ src = warped_points + (size_t)p*64; dst = normW + (size_t)p*64; }
    else { int q = p - Bn*HWn; src = f2_points + (size_t)q*64; dst = normF2 + (size_t)q*64; }
    float x = src[lane];
    float m = wred64(x) * (1.f/64.f);
    float d = x - m;
    float ss = wred64(d*d);
    float s = fmaxf(sqrtf(ss*(1.f/63.f)), 1e-12f);
    dst[lane] = d / s;
  } else if (blk < 4192){
    int e = (blk-4096)*256 + tid;          // < 24576
    wxyz[e] = warped_xyz[e] * lidar_z[e/3];
  } else if (blk < 4196){
    int e = (blk-4192)*256 + tid;          // < 1024
    if (e < 384){ piwT[(e & 63)*6  + (e >> 6)] = piw[e]; }
    else if (e < 1024){ int f = e-384; pcwT[(f & 63)*10 + (f >> 6)] = pcw[f]; }
  } else {
    int e = (blk-4196)*256 + tid;          // < 49152
    if (e < 12288){                        // w1h[j][k] : [128 out][96 in-pad]
      int j = e/96, k = e - j*96;
      w1h[e] = (k < 70) ? (_Float16)m1w0[k*128 + j] : (_Float16)0.f;
    } else if (e < 20480){                 // w2h[d][c] : [64][128]
      int f = e - 12288; int d = f >> 7, c = f & 127;
      w2h[f] = (_Float16)m1w1[c*64 + d];
    } else if (e < 28672){                 // w3h[d][c] : [64][128]
      int f = e - 20480; int d = f >> 7, c = f & 127;
      w3h[f] = (_Float16)m2w0[c*64 + d];
    } else if (e < 32768){                 // w4h[d][c] : [64][64]
      int f = e - 28672; int d = f >> 6, c = f & 63;
      w4h[f] = (_Float16)m2w1[c*64 + d];
    } else if (e < 45056){                 // w5h[d][c] : [64][192]
      int f = e - 32768; int d = f/192, c = f - 192*d;
      w5h[f] = (_Float16)m3w0[c*64 + d];
    } else {                               // w6h[d][c] : [64][64]
      int f = e - 45056; int d = f >> 6, c = f & 63;
      w6h[f] = (_Float16)m3w1[c*64 + d];
    }
  }
}

// ---------------- exact k-smallest radix select on informative bits ----------------
// Keys are biased by block-min; first digit starts at msb(max-min), so pass-1
// buckets spread over the data range (kills same-bucket atomic serialization).
// below/active bitmasks track the selected set; early exit when class==rem.
template<int K, bool WRITE_VALID>
__global__ __launch_bounds__(256) void k_knn(
    const float* __restrict__ qpts, const float* __restrict__ pts,
    int* __restrict__ oidx, float* __restrict__ ovalid)
{
  __shared__ int hist[4*256];
  __shared__ int wsum[4];
  __shared__ unsigned int redm[4], redM[4];
  __shared__ unsigned int sh_sel;
  __shared__ int sh_rem, sh_cls, cnt_lt, cnt_eq;
  int b = blockIdx.x >> 12;
  int qi = blockIdx.x & 4095;
  int tid = threadIdx.x;
  int lane = tid & 63, wv = tid >> 6;
  const float* qp = qpts + ((size_t)(b*HWn+qi))*3;
  float qx=qp[0], qy=qp[1], qz=qp[2];
  const float* pb = pts + (size_t)b*Nn*3;
  unsigned int key[16];
  #pragma unroll
  for (int i=0;i<16;i++){
    int t = tid + i*256;
    float dx = __fsub_rn(qx, pb[t*3+0]);
    float dy = __fsub_rn(qy, pb[t*3+1]);
    float dz = __fsub_rn(qz, pb[t*3+2]);
    float d2 = __fadd_rn(__fadd_rn(__fmul_rn(dx,dx), __fmul_rn(dy,dy)), __fmul_rn(dz,dz));
    key[i] = __float_as_uint(d2);          // nonneg floats: uint order == float order
  }
  // block min/max of keys
  unsigned int mn = key[0], mx = key[0];
  #pragma unroll
  for (int i=1;i<16;i++){ mn = min(mn, key[i]); mx = max(mx, key[i]); }
  #pragma unroll
  for (int m=32;m>0;m>>=1){
    mn = min(mn, (unsigned int)__shfl_xor((int)mn, m, 64));
    mx = max(mx, (unsigned int)__shfl_xor((int)mx, m, 64));
  }
  if (lane == 0){ redm[wv] = mn; redM[wv] = mx; }
  if (tid == 0){ cnt_lt = 0; cnt_eq = 0; }
  __syncthreads();
  mn = min(min(redm[0],redm[1]), min(redm[2],redm[3]));
  mx = max(max(redM[0],redM[1]), max(redM[2],redM[3]));
  unsigned int R = mx - mn;
  int L = (R == 0u) ? 0 : (31 - __clz(R));
  int shift = (L > 7) ? (L - 7) : 0;
  unsigned int dmask = 255u;

  unsigned int active = 0xFFFFu, below = 0u;
  int rem = K;
  for (;;){
    __syncthreads();                       // guard hist reuse
    #pragma unroll
    for (int j=0;j<4;j++) hist[j*256 + tid] = 0;
    __syncthreads();
    #pragma unroll
    for (int i=0;i<16;i++){
      if (active & (1u<<i))
        atomicAdd(&hist[wv*256 + (int)(((key[i]-mn) >> shift) & dmask)], 1);
    }
    __syncthreads();
    int h = hist[tid] + hist[256+tid] + hist[512+tid] + hist[768+tid];
    int pref = h;
    #pragma unroll
    for (int m=1;m<64;m<<=1){ int t = __shfl_up(pref, m, 64); if (lane >= m) pref += t; }
    if (lane == 63) wsum[wv] = pref;
    __syncthreads();
    int off = 0;
    #pragma unroll
    for (int i=0;i<3;i++) if (i < wv) off += wsum[i];
    pref += off;                           // inclusive prefix over buckets 0..tid
    if (pref >= rem && (pref - h) < rem){
      sh_sel = (unsigned int)tid;
      sh_rem = rem - (pref - h);
      sh_cls = h;
    }
    __syncthreads();
    unsigned int sel = sh_sel; rem = sh_rem; int cls = sh_cls;
    #pragma unroll
    for (int i=0;i<16;i++){
      if (active & (1u<<i)){
        unsigned int d = ((key[i]-mn) >> shift) & dmask;
        if (d < sel) below |= (1u<<i);
        if (d != sel) active &= ~(1u<<i);
      }
    }
    if (cls == rem || shift == 0) break;
    int w = (shift < 8) ? shift : 8;
    shift -= w;
    dmask = (w == 8) ? 255u : ((1u<<w) - 1u);
  }
  // output: all 'below' + rem of the final equal-class
  size_t obase = ((size_t)(b*HWn+qi))*K;
  int nless = K - rem;
  const unsigned int U100 = __float_as_uint(100.0f);  // DIST*DIST
  #pragma unroll
  for (int i=0;i<16;i++){
    if (below & (1u<<i)){
      int s = atomicAdd(&cnt_lt, 1);
      oidx[obase+s] = tid + i*256;
      if constexpr (WRITE_VALID) ovalid[obase+s] = (key[i] < U100) ? 1.f : 0.f;
    } else if (active & (1u<<i)){
      int s = atomicAdd(&cnt_eq, 1);
      if (s < rem){
        oidx[obase+nless+s] = tid + i*256;
        if constexpr (WRITE_VALID) ovalid[obase+nless+s] = (key[i] < U100) ? 1.f : 0.f;
      }
    }
  }
}

// ---------------- build f16 X1 rows: [wxyz(3) f2xyz(3) prod(64) pad->96] ----------------
__global__ __launch_bounds__(256) void k_buildX1(
    const float* __restrict__ wxyz, const float* __restrict__ f2_xyz,
    const float* __restrict__ normW, const float* __restrict__ normF2,
    const int* __restrict__ idxq, _Float16* __restrict__ X1)
{
  int row = blockIdx.x*256 + threadIdx.x;
  float x[70];
  build_x70(row, wxyz, f2_xyz, normW, normF2, idxq, x);
  unsigned int* d32 = (unsigned int*)(X1 + (size_t)row*96);
  union { unsigned int u; _Float16 h[2]; } pk;
  #pragma unroll
  for (int c=0;c<35;c++){
    pk.h[0] = (_Float16)x[2*c]; pk.h[1] = (_Float16)x[2*c+1];
    d32[c] = pk.u;
  }
  #pragma unroll
  for (int c=35;c<48;c++) d32[c] = 0u;
}

// ---------------- Gram-matrix stats for pi_enc (7x7) and pc_enc (11x11) ----------------
__global__ __launch_bounds__(256) void k_gram(
    const float* __restrict__ wxyz, const float* __restrict__ f2_xyz,
    const int* __restrict__ idxq, const int* __restrict__ idx2,
    float* __restrict__ gram)
{
  __shared__ float sacc[66];
  int blk = blockIdx.x, tid = threadIdx.x, lane = tid & 63;
  if (blk < 64){
    float a[28];
    #pragma unroll
    for (int q=0;q<28;q++) a[q]=0.f;
    int g = blk*256 + tid;
    for (int s=0;s<16;s++){
      int row = g + s*16384;
      int p = row >> 5, b = p >> 12;
      int idx = idxq[row];
      const float* wx = wxyz + (size_t)p*3;
      const float* fx = f2_xyz + ((size_t)b*Nn + idx)*3;
      float xt[7] = {wx[0],wx[1],wx[2],fx[0],fx[1],fx[2],1.f};
      int q=0;
      #pragma unroll
      for (int i=0;i<7;i++)
        #pragma unroll
        for (int j=i;j<7;j++) a[q++] += xt[i]*xt[j];
    }
    if (tid < 28) sacc[tid]=0.f;
    __syncthreads();
    #pragma unroll
    for (int q=0;q<28;q++){
      float v = wred64(a[q]);
      if (lane==0) atomicAdd(&sacc[q], v);
    }
    __syncthreads();
    if (tid < 28) atomicAdd(&gram[tid], sacc[tid]);
  } else {
    float a[66];
    #pragma unroll
    for (int q=0;q<66;q++) a[q]=0.f;
    int g = (blk-64)*256 + tid;
    for (int s=0;s<16;s++){
      int row = g + s*8192;
      float x[10];
      build_x10(row, wxyz, idx2, x);
      float xt[11] = {x[0],x[1],x[2],x[3],x[4],x[5],x[6],x[7],x[8],x[9],1.f};
      int q=0;
      #pragma unroll
      for (int i=0;i<11;i++)
        #pragma unroll
        for (int j=i;j<11;j++) a[q++] += xt[i]*xt[j];
    }
    if (tid < 66) sacc[tid]=0.f;
    __syncthreads();
    #pragma unroll
    for (int q=0;q<66;q++){
      float v = wred64(a[q]);
      if (lane==0) atomicAdd(&sacc[q], v);
    }
    __syncthreads();
    if (tid < 66) atomicAdd(&gram[32+tid], sacc[tid]);
  }
}

__global__ __launch_bounds__(128) void k_gram_fin(
    const float* __restrict__ gram,
    const float* __restrict__ piw, const float* __restrict__ pib,
    const float* __restrict__ pcw, const float* __restrict__ pcb,
    float* stats)
{
  int tid = threadIdx.x;
  if (tid < 64){
    int c = tid;
    float wt[7];
    #pragma unroll
    for (int i=0;i<6;i++) wt[i] = piw[i*64+c];
    wt[6] = pib[c];
    const float* G = gram;
    float sum=0.f, ssq=0.f;
    #pragma unroll
    for (int i=0;i<7;i++){
      int offi = i*7 - (i*(i-1))/2;
      sum += wt[i]*G[offi + (6-i)];
      #pragma unroll
      for (int j=0;j<7;j++){
        int ii = i<j? i : j, jj = i<j? j : i;
        int o = ii*7 - (ii*(ii-1))/2 + (jj-ii);
        ssq += wt[i]*wt[j]*G[o];
      }
    }
    stats[2*256+c] = sum; stats[2*256+128+c] = ssq;
  } else {
    int c = tid-64;
    float wt[11];
    #pragma unroll
    for (int i=0;i<10;i++) wt[i] = pcw[i*64+c];
    wt[10] = pcb[c];
    const float* G = gram + 32;
    float sum=0.f, ssq=0.f;
    #pragma unroll
    for (int i=0;i<11;i++){
      int offi = i*11 - (i*(i-1))/2;
      sum += wt[i]*G[offi + (10-i)];
      #pragma unroll
      for (int j=0;j<11;j++){
        int ii = i<j? i : j, jj = i<j? j : i;
        int o = ii*11 - (ii*(ii-1))/2 + (jj-ii);
        ssq += wt[i]*wt[j]*G[o];
      }
    }
    stats[5*256+c] = sum; stats[5*256+128+c] = ssq;
  }
}

// ---------------- MFMA y1 stats: 4x64-row tiles/block, weights direct from global ----------------
__global__ __launch_bounds__(256) void k_mfma_stats1(
    const _Float16* __restrict__ X1, const _Float16* __restrict__ w1h,
    float* stats)
{
  __shared__ float ssum[128], sssq[128];
  int tid = threadIdx.x;
  if (tid < 128){ ssum[tid]=0.f; sssq[tid]=0.f; }
  __syncthreads();
  int wave = tid >> 6, lane = tid & 63;
  int quad = lane >> 4, n16 = lane & 15;
  float r1[8], r2[8];
  #pragma unroll
  for (int i=0;i<8;i++){ r1[i]=0.f; r2[i]=0.f; }
  for (int t=0;t<4;t++){
    int m0 = blockIdx.x*256 + t*64 + wave*16;
    const _Float16* xr = X1 + (size_t)(m0 + n16)*96 + quad*8;
    f16x8 a0 = *(const f16x8*)(xr);
    f16x8 a1 = *(const f16x8*)(xr + 32);
    f16x8 a2 = *(const f16x8*)(xr + 64);
    #pragma unroll
    for (int nt = 0; nt < 8; nt++){
      const _Float16* wr = w1h + (size_t)(nt*16 + n16)*96 + quad*8;
      f16x8 b0 = *(const f16x8*)(wr);
      f16x8 b1 = *(const f16x8*)(wr + 32);
      f16x8 b2 = *(const f16x8*)(wr + 64);
      f32x4 acc = {0.f,0.f,0.f,0.f};
      acc = __builtin_amdgcn_mfma_f32_16x16x32_f16(a0, b0, acc, 0,0,0);
      acc = __builtin_amdgcn_mfma_f32_16x16x32_f16(a1, b1, acc, 0,0,0);
      acc = __builtin_amdgcn_mfma_f32_16x16x32_f16(a2, b2, acc, 0,0,0);
      float s1 = acc[0]+acc[1]+acc[2]+acc[3];
      float s2 = acc[0]*acc[0]+acc[1]*acc[1]+acc[2]*acc[2]+acc[3]*acc[3];
      s1 += __shfl_xor(s1, 16, 64); s1 += __shfl_xor(s1, 32, 64);
      s2 += __shfl_xor(s2, 16, 64); s2 += __shfl_xor(s2, 32, 64);
      r1[nt] += s1; r2[nt] += s2;
    }
  }
  if (quad == 0){
    #pragma unroll
    for (int nt=0;nt<8;nt++){
      atomicAdd(&ssum[nt*16+n16], r1[nt]); atomicAdd(&sssq[nt*16+n16], r2[nt]);
    }
  }
  __syncthreads();
  if (tid < 128){ atomicAdd(&stats[tid], ssum[tid]); atomicAdd(&stats[128+tid], sssq[tid]); }
}

// ---------------- MFMA m1: 4 tiles/block; y1 -> BN/leaky -> t (LDS) -> x W2 -> y2 ----------------
__global__ __launch_bounds__(256) void k_mfma_m1(
    const _Float16* __restrict__ X1, const _Float16* __restrict__ w1h,
    const _Float16* __restrict__ w2h,
    const float* __restrict__ m1g0, const float* __restrict__ m1e0,
    float* stats, _Float16* __restrict__ y2h)
{
  __shared__ _Float16 st[64*136];
  __shared__ float sc1[128], sh1[128], ssum[64], sssq[64];
  int tid = threadIdx.x;
  if (tid < 128){
    float s,h; bn_param(stats, tid, INV_R1, m1g0, m1e0, s, h);
    sc1[tid]=s; sh1[tid]=h;
  }
  if (tid < 64){ ssum[tid]=0.f; sssq[tid]=0.f; }
  __syncthreads();
  int wave = tid >> 6, lane = tid & 63;
  int quad = lane >> 4, n16 = lane & 15;
  float r1[4], r2[4];
  #pragma unroll
  for (int i=0;i<4;i++){ r1[i]=0.f; r2[i]=0.f; }
  for (int t=0;t<4;t++){
    int m0 = blockIdx.x*256 + t*64 + wave*16;
    const _Float16* xr = X1 + (size_t)(m0 + n16)*96 + quad*8;
    f16x8 a0 = *(const f16x8*)(xr);
    f16x8 a1 = *(const f16x8*)(xr + 32);
    f16x8 a2 = *(const f16x8*)(xr + 64);
    #pragma unroll
    for (int nt = 0; nt < 8; nt++){
      const _Float16* wr = w1h + (size_t)(nt*16 + n16)*96 + quad*8;
      f16x8 b0 = *(const f16x8*)(wr);
      f16x8 b1 = *(const f16x8*)(wr + 32);
      f16x8 b2 = *(const f16x8*)(wr + 64);
      f32x4 acc = {0.f,0.f,0.f,0.f};
      acc = __builtin_amdgcn_mfma_f32_16x16x32_f16(a0, b0, acc, 0,0,0);
      acc = __builtin_amdgcn_mfma_f32_16x16x32_f16(a1, b1, acc, 0,0,0);
      acc = __builtin_amdgcn_mfma_f32_16x16x32_f16(a2, b2, acc, 0,0,0);
      int ch = nt*16 + n16;
      float sc = sc1[ch], sh = sh1[ch];
      #pragma unroll
      for (int r=0;r<4;r++){
        float v = leakyf(acc[r]*sc + sh);
        st[(size_t)(wave*16 + quad*4 + r)*136 + ch] = (_Float16)v;
      }
    }
    __syncthreads();
    const _Float16* tr = st + (size_t)(wave*16 + n16)*136 + quad*8;
    f16x8 t0 = *(const f16x8*)(tr);
    f16x8 t1 = *(const f16x8*)(tr + 32);
    f16x8 t2 = *(const f16x8*)(tr + 64);
    f16x8 t3 = *(const f16x8*)(tr + 96);
    #pragma unroll
    for (int nt = 0; nt < 4; nt++){
      const _Float16* wr = w2h + (size_t)(nt*16 + n16)*128 + quad*8;
      f16x8 b0 = *(const f16x8*)(wr);
      f16x8 b1 = *(const f16x8*)(wr + 32);
      f16x8 b2 = *(const f16x8*)(wr + 64);
      f16x8 b3 = *(const f16x8*)(wr + 96);
      f32x4 acc = {0.f,0.f,0.f,0.f};
      acc = __builtin_amdgcn_mfma_f32_16x16x32_f16(t0, b0, acc, 0,0,0);
      acc = __builtin_amdgcn_mfma_f32_16x16x32_f16(t1, b1, acc, 0,0,0);
      acc = __builtin_amdgcn_mfma_f32_16x16x32_f16(t2, b2, acc, 0,0,0);
      acc = __builtin_amdgcn_mfma_f32_16x16x32_f16(t3, b3, acc, 0,0,0);
      int ch = nt*16 + n16;
      #pragma unroll
      for (int r=0;r<4;r++){
        int rowg = blockIdx.x*256 + t*64 + wave*16 + quad*4 + r;
        y2h[(size_t)rowg*64 + ch] = (_Float16)acc[r];
      }
      float s1 = acc[0]+acc[1]+acc[2]+acc[3];
      float s2 = acc[0]*acc[0]+acc[1]*acc[1]+acc[2]*acc[2]+acc[3]*acc[3];
      s1 += __shfl_xor(s1, 16, 64); s1 += __shfl_xor(s1, 32, 64);
      s2 += __shfl_xor(s2, 16, 64); s2 += __shfl_xor(s2, 32, 64);
      r1[nt] += s1; r2[nt] += s2;
    }
    __syncthreads();
  }
  if (quad == 0){
    #pragma unroll
    for (int nt=0;nt<4;nt++){
      atomicAdd(&ssum[nt*16+n16], r1[nt]); atomicAdd(&sssq[nt*16+n16], r2[nt]);
    }
  }
  __syncthreads();
  if (tid < 64){ atomicAdd(&stats[1*256+tid], ssum[tid]); atomicAdd(&stats[1*256+128+tid], sssq[tid]); }
}

// ---------------- MFMA m2a: 4 tiles/block; u=[pi_enc|feat] in LDS, y3 = u x W3 ----------------
__global__ __launch_bounds__(256) void k_mfma_m2a(
    const float* __restrict__ wxyz, const float* __restrict__ f2_xyz,
    const int* __restrict__ idxq,
    const float* __restrict__ piwT, const float* __restrict__ pib,
    const float* __restrict__ pig, const float* __restrict__ pie,
    const float* __restrict__ m1g1, const float* __restrict__ m1e1,
    const _Float16* __restrict__ y2h, const _Float16* __restrict__ w3h,
    float* stats, _Float16* __restrict__ y3h)
{
  __shared__ _Float16 su[64*136];
  __shared__ float spw[384];
  __shared__ float scp[64], shp[64], sc2[64], sh2[64], ssum[64], sssq[64];
  int tid = threadIdx.x;
  for (int d = tid; d < 384; d += 256) spw[d] = piwT[d];
  if (tid < 64){
    float s,h;
    bn_param(stats+2*256, tid, INV_R1, pig,  pie,  s, h); scp[tid]=s; shp[tid]=h;
    bn_param(stats+1*256, tid, INV_R1, m1g1, m1e1, s, h); sc2[tid]=s; sh2[tid]=h;
    ssum[tid]=0.f; sssq[tid]=0.f;
  }
  __syncthreads();
  int r = tid & 63, cg = tid >> 6;
  int wave = tid >> 6, lane = tid & 63, quad = lane >> 4, n16 = lane & 15;
  float r1[4], r2[4];
  #pragma unroll
  for (int i=0;i<4;i++){ r1[i]=0.f; r2[i]=0.f; }
  for (int t=0;t<4;t++){
    int rowg = blockIdx.x*256 + t*64 + r;
    {
      int p = rowg >> 5, b = p >> 12;
      int idx = idxq[rowg];
      const float* wx = wxyz + (size_t)p*3;
      const float* fx = f2_xyz + ((size_t)b*Nn + idx)*3;
      float x0=wx[0],x1=wx[1],x2=wx[2],x3=fx[0],x4=fx[1],x5=fx[2];
      #pragma unroll
      for (int jj=0;jj<16;jj++){
        int j = cg*16 + jj;
        const float* pw = spw + j*6;
        float e = pib[j] + x0*pw[0]+x1*pw[1]+x2*pw[2]+x3*pw[3]+x4*pw[4]+x5*pw[5];
        su[r*136 + j] = (_Float16)leakyf(e*scp[j] + shp[j]);
      }
      const f16x8* yr = (const f16x8*)(y2h + (size_t)rowg*64 + cg*16);
      f16x8 q0 = yr[0], q1 = yr[1];
      #pragma unroll
      for (int jj=0;jj<8;jj++){
        int c = cg*16 + jj;
        su[r*136 + 64 + c] = (_Float16)leakyf((float)q0[jj]*sc2[c] + sh2[c]);
      }
      #pragma unroll
      for (int jj=0;jj<8;jj++){
        int c = cg*16 + 8 + jj;
        su[r*136 + 64 + c] = (_Float16)leakyf((float)q1[jj]*sc2[c] + sh2[c]);
      }
    }
    __syncthreads();
    const _Float16* ur = su + (size_t)(wave*16 + n16)*136 + quad*8;
    f16x8 a0 = *(const f16x8*)(ur);
    f16x8 a1 = *(const f16x8*)(ur + 32);
    f16x8 a2 = *(const f16x8*)(ur + 64);
    f16x8 a3 = *(const f16x8*)(ur + 96);
    #pragma unroll
    for (int nt = 0; nt < 4; nt++){
      const _Float16* wr = w3h + (size_t)(nt*16 + n16)*128 + quad*8;
      f16x8 b0 = *(const f16x8*)(wr);
      f16x8 b1 = *(const f16x8*)(wr + 32);
      f16x8 b2 = *(const f16x8*)(wr + 64);
      f16x8 b3 = *(const f16x8*)(wr + 96);
      f32x4 acc = {0.f,0.f,0.f,0.f};
      acc = __builtin_amdgcn_mfma_f32_16x16x32_f16(a0, b0, acc, 0,0,0);
      acc = __builtin_amdgcn_mfma_f32_16x16x32_f16(a1, b1, acc, 0,0,0);
      acc = __builtin_amdgcn_mfma_f32_16x16x32_f16(a2, b2, acc, 0,0,0);
      acc = __builtin_amdgcn_mfma_f32_16x16x32_f16(a3, b3, acc, 0,0,0);
      int ch = nt*16 + n16;
      #pragma unroll
      for (int rr=0;rr<4;rr++){
        int rg = blockIdx.x*256 + t*64 + wave*16 + quad*4 + rr;
        y3h[(size_t)rg*64 + ch] = (_Float16)acc[rr];
      }
      float s1 = acc[0]+acc[1]+acc[2]+acc[3];
      float s2 = acc[0]*acc[0]+acc[1]*acc[1]+acc[2]*acc[2]+acc[3]*acc[3];
      s1 += __shfl_xor(s1, 16, 64); s1 += __shfl_xor(s1, 32, 64);
      s2 += __shfl_xor(s2, 16, 64); s2 += __shfl_xor(s2, 32, 64);
      r1[nt] += s1; r2[nt] += s2;
    }
    __syncthreads();
  }
  if (quad == 0){
    #pragma unroll
    for (int nt=0;nt<4;nt++){
      atomicAdd(&ssum[nt*16+n16], r1[nt]); atomicAdd(&sssq[nt*16+n16], r2[nt]);
    }
  }
  __syncthreads();
  if (tid < 64){ atomicAdd(&stats[3*256+tid], ssum[tid]); atomicAdd(&stats[3*256+128+tid], sssq[tid]); }
}

// ---------------- generic MFMA pointwise 64->64, 4 tiles/block ----------------
__global__ __launch_bounds__(256) void k_mfma_pw64(
    const _Float16* __restrict__ yin, const _Float16* __restrict__ wh,
    const float* __restrict__ g, const float* __restrict__ e,
    const float* statsIn, float* statsOut, float inv_n,
    _Float16* __restrict__ yout)
{
  __shared__ _Float16 stt[64*72];
  __shared__ float sc[64], sh[64], ssum[64], sssq[64];
  int tid = threadIdx.x;
  if (tid < 64){
    float s,h; bn_param(statsIn, tid, inv_n, g, e, s, h);
    sc[tid]=s; sh[tid]=h; ssum[tid]=0.f; sssq[tid]=0.f;
  }
  __syncthreads();
  int r = tid & 63, cg = tid >> 6;
  int wave = tid >> 6, lane = tid & 63, quad = lane >> 4, n16 = lane & 15;
  float r1[4], r2[4];
  #pragma unroll
  for (int i=0;i<4;i++){ r1[i]=0.f; r2[i]=0.f; }
  for (int t=0;t<4;t++){
    int rowg = blockIdx.x*256 + t*64 + r;
    const f16x8* yr = (const f16x8*)(yin + (size_t)rowg*64 + cg*16);
    f16x8 q0 = yr[0], q1 = yr[1];
    #pragma unroll
    for (int jj=0;jj<8;jj++){
      int c = cg*16 + jj;
      stt[r*72 + c] = (_Float16)leakyf((float)q0[jj]*sc[c] + sh[c]);
    }
    #pragma unroll
    for (int jj=0;jj<8;jj++){
      int c = cg*16 + 8 + jj;
      stt[r*72 + c] = (_Float16)leakyf((float)q1[jj]*sc[c] + sh[c]);
    }
    __syncthreads();
    const _Float16* tr = stt + (size_t)(wave*16 + n16)*72 + quad*8;
    f16x8 a0 = *(const f16x8*)(tr);
    f16x8 a1 = *(const f16x8*)(tr + 32);
    #pragma unroll
    for (int nt = 0; nt < 4; nt++){
      const _Float16* wr = wh + (size_t)(nt*16 + n16)*64 + quad*8;
      f16x8 b0 = *(const f16x8*)(wr);
      f16x8 b1 = *(const f16x8*)(wr + 32);
      f32x4 acc = {0.f,0.f,0.f,0.f};
      acc = __builtin_amdgcn_mfma_f32_16x16x32_f16(a0, b0, acc, 0,0,0);
      acc = __builtin_amdgcn_mfma_f32_16x16x32_f16(a1, b1, acc, 0,0,0);
      int ch = nt*16 + n16;
      #pragma unroll
      for (int rr=0;rr<4;rr++){
        int rg = blockIdx.x*256 + t*64 + wave*16 + quad*4 + rr;
        yout[(size_t)rg*64 + ch] = (_Float16)acc[rr];
      }
      float s1 = acc[0]+acc[1]+acc[2]+acc[3];
      float s2 = acc[0]*acc[0]+acc[1]*acc[1]+acc[2]*acc[2]+acc[3]*acc[3];
      s1 += __shfl_xor(s1, 16, 64); s1 += __shfl_xor(s1, 32, 64);
      s2 += __shfl_xor(s2, 16, 64); s2 += __shfl_xor(s2, 32, 64);
      r1[nt] += s1; r2[nt] += s2;
    }
    __syncthreads();
  }
  if (quad == 0){
    #pragma unroll
    for (int nt=0;nt<4;nt++){
      atomicAdd(&ssum[nt*16+n16], r1[nt]); atomicAdd(&sssq[nt*16+n16], r2[nt]);
    }
  }
  __syncthreads();
  if (tid < 64){ atomicAdd(&statsOut[tid], ssum[tid]); atomicAdd(&statsOut[128+tid], sssq[tid]); }
}

// ---------------- MFMA m3a: 4 tiles/block; v=[pc_enc|wp|pif1_g] (192ch), y5 = v x W5 ----------------
__global__ __launch_bounds__(256) void k_mfma_m3a(
    const float* __restrict__ wxyz, const float* __restrict__ warped_points,
    const _Float16* __restrict__ pif1h, const int* __restrict__ idx2,
    const float* __restrict__ pcwT, const float* __restrict__ pcb,
    const float* __restrict__ pcg, const float* __restrict__ pce,
    const _Float16* __restrict__ w5h,
    float* stats, _Float16* __restrict__ y5h)
{
  __shared__ _Float16 sv[64*200];
  __shared__ float spw[640];
  __shared__ float scp[64], shp[64], ssum[64], sssq[64];
  int tid = threadIdx.x;
  for (int d = tid; d < 640; d += 256) spw[d] = pcwT[d];
  if (tid < 64){
    float s,h; bn_param(stats+5*256, tid, INV_R2, pcg, pce, s, h);
    scp[tid]=s; shp[tid]=h; ssum[tid]=0.f; sssq[tid]=0.f;
  }
  __syncthreads();
  int r = tid & 63, cg = tid >> 6;
  int wave = tid >> 6, lane = tid & 63, quad = lane >> 4, n16 = lane & 15;
  float r1[4], r2[4];
  #pragma unroll
  for (int i=0;i<4;i++){ r1[i]=0.f; r2[i]=0.f; }
  for (int t=0;t<4;t++){
    int rowg = blockIdx.x*256 + t*64 + r;
    {
      int p = rowg >> 4, b = p >> 12;
      int idx = idx2[rowg];
      float x[10];
      build_x10(rowg, wxyz, idx2, x);
      #pragma unroll
      for (int jj=0;jj<16;jj++){
        int j = cg*16 + jj;
        const float* pw = spw + j*10;
        float e = pcb[j];
        #pragma unroll
        for (int i=0;i<10;i++) e += x[i]*pw[i];
        sv[r*200 + j] = (_Float16)leakyf(e*scp[j] + shp[j]);
      }
      const float4* wp = (const float4*)(warped_points + (size_t)p*64 + cg*16);
      #pragma unroll
      for (int v4=0; v4<4; v4++){
        float4 q = wp[v4];
        int c = 64 + cg*16 + v4*4;
        sv[r*200 + c + 0] = (_Float16)q.x;
        sv[r*200 + c + 1] = (_Float16)q.y;
        sv[r*200 + c + 2] = (_Float16)q.z;
        sv[r*200 + c + 3] = (_Float16)q.w;
      }
      const f16x8* pg = (const f16x8*)(pif1h + ((size_t)(b*HWn) + idx)*64 + cg*16);
      f16x8 g0 = pg[0], g1 = pg[1];
      #pragma unroll
      for (int jj=0;jj<8;jj++) sv[r*200 + 128 + cg*16 + jj] = g0[jj];
      #pragma unroll
      for (int jj=0;jj<8;jj++) sv[r*200 + 136 + cg*16 + jj] = g1[jj];
    }
    __syncthreads();
    const _Float16* vr = sv + (size_t)(wave*16 + n16)*200 + quad*8;
    f16x8 a0 = *(const f16x8*)(vr);
    f16x8 a1 = *(const f16x8*)(vr + 32);
    f16x8 a2 = *(const f16x8*)(vr + 64);
    f16x8 a3 = *(const f16x8*)(vr + 96);
    f16x8 a4 = *(const f16x8*)(vr + 128);
    f16x8 a5 = *(const f16x8*)(vr + 160);
    #pragma unroll
    for (int nt = 0; nt < 4; nt++){
      const _Float16* wr = w5h + (size_t)(nt*16 + n16)*192 + quad*8;
      f32x4 acc = {0.f,0.f,0.f,0.f};
      acc = __builtin_amdgcn_mfma_f32_16x16x32_f16(a0, *(const f16x8*)(wr),       acc, 0,0,0);
      acc = __builtin_amdgcn_mfma_f32_16x16x32_f16(a1, *(const f16x8*)(wr + 32),  acc, 0,0,0);
      acc = __builtin_amdgcn_mfma_f32_16x16x32_f16(a2, *(const f16x8*)(wr + 64),  acc, 0,0,0);
      acc = __builtin_amdgcn_mfma_f32_16x16x32_f16(a3, *(const f16x8*)(wr + 96),  acc, 0,0,0);
      acc = __builtin_amdgcn_mfma_f32_16x16x32_f16(a4, *(const f16x8*)(wr + 128), acc, 0,0,0);
      acc = __builtin_amdgcn_mfma_f32_16x16x32_f16(a5, *(const f16x8*)(wr + 160), acc, 0,0,0);
      int ch = nt*16 + n16;
      #pragma unroll
      for (int rr=0;rr<4;rr++){
        int rg = blockIdx.x*256 + t*64 + wave*16 + quad*4 + rr;
        y5h[(size_t)rg*64 + ch] = (_Float16)acc[rr];
      }
      float s1 = acc[0]+acc[1]+acc[2]+acc[3];
      float s2 = acc[0]*acc[0]+acc[1]*acc[1]+acc[2]*acc[2]+acc[3]*acc[3];
      s1 += __shfl_xor(s1, 16, 64); s1 += __shfl_xor(s1, 32, 64);
      s2 += __shfl_xor(s2, 16, 64); s2 += __shfl_xor(s2, 32, 64);
      r1[nt] += s1; r2[nt] += s2;
    }
    __syncthreads();
  }
  if (quad == 0){
    #pragma unroll
    for (int nt=0;nt<4;nt++){
      atomicAdd(&ssum[nt*16+n16], r1[nt]); atomicAdd(&sssq[nt*16+n16], r2[nt]);
    }
  }
  __syncthreads();
  if (tid < 64){ atomicAdd(&stats[6*256+tid], ssum[tid]); atomicAdd(&stats[6*256+128+tid], sssq[tid]); }
}

// ---------------- stage-1 softmax over KQ, weighted sum of feat -> pif1 (f16) ----------------
__global__ __launch_bounds__(256) void k_softmax1(
    const _Float16* __restrict__ y2h, const _Float16* __restrict__ y4h,
    const float* stats,
    const float* __restrict__ m1g1, const float* __restrict__ m1e1,
    const float* __restrict__ m2g1, const float* __restrict__ m2e1,
    _Float16* __restrict__ pif1h)
{
  int tid = threadIdx.x, lane = tid & 63;
  int p = blockIdx.x*4 + (tid >> 6);
  int d = lane;
  float sc2,sh2,sc4,sh4;
  bn_param(stats+1*256, d, INV_R1, m1g1, m1e1, sc2, sh2);
  bn_param(stats+4*256, d, INV_R1, m2g1, m2e1, sc4, sh4);
  size_t rb = (size_t)p*KQn;
  float v[32]; float mx = -1e30f;
  #pragma unroll
  for (int k=0;k<32;k++){
    float t = leakyf((float)y4h[(rb+k)*64 + d]*sc4 + sh4);
    v[k] = t; mx = fmaxf(mx, t);
  }
  float se = 0.f;
  #pragma unroll
  for (int k=0;k<32;k++){ float ev = __expf(v[k]-mx); v[k]=ev; se += ev; }
  float inv = 1.f/se, acc = 0.f;
  #pragma unroll
  for (int k=0;k<32;k++){
    float f = leakyf((float)y2h[(rb+k)*64 + d]*sc2 + sh2);
    acc += v[k]*f;
  }
  pif1h[(size_t)p*64 + d] = (_Float16)(acc*inv);
}

// ---------------- stage-2 masked softmax over KN, weighted sum of gathered pif1 ----------------
__global__ __launch_bounds__(256) void k_softmax2(
    const _Float16* __restrict__ y6h, const _Float16* __restrict__ pif1h,
    const int* __restrict__ idx2, const float* __restrict__ validf,
    const float* stats,
    const float* __restrict__ m3g1, const float* __restrict__ m3e1,
    float* __restrict__ out)
{
  int tid = threadIdx.x, lane = tid & 63;
  int p = blockIdx.x*4 + (tid >> 6);
  int b = p >> 12;
  int d = lane;
  float sc,sh; bn_param(stats+7*256, d, INV_R2, m3g1, m3e1, sc, sh);
  size_t rb = (size_t)p*KNn;
  float v[16]; float mx = -1e30f;
  #pragma unroll
  for (int k=0;k<16;k++){
    float t = leakyf((float)y6h[(rb+k)*64 + d]*sc + sh);
    t = (validf[rb+k] > 0.5f) ? t : -1e10f;
    v[k] = t; mx = fmaxf(mx, t);
  }
  float se = 0.f;
  #pragma unroll
  for (int k=0;k<16;k++){ float ev = __expf(v[k]-mx); v[k]=ev; se += ev; }
  float inv = 1.f/se, acc = 0.f;
  #pragma unroll
  for (int k=0;k<16;k++){
    int idx = idx2[rb+k];
    acc += v[k]*(float)pif1h[((size_t)(b*HWn) + idx)*64 + d];
  }
  out[(size_t)p*64 + d] = acc*inv;
}

// ---------------- launcher ----------------
extern "C" void kernel_launch(void* const* d_in, const int* in_sizes, int n_in,
                              void* d_out, int out_size, void* d_ws, size_t ws_size,
                              hipStream_t stream)
{
  (void)in_sizes; (void)n_in; (void)out_size; (void)ws_size;
  const float* xyz_proj      = (const float*)d_in[0];
  const float* warped_xyz    = (const float*)d_in[1];
  const float* warped_points = (const float*)d_in[2];
  const float* f2_xyz        = (const float*)d_in[4];
  const float* f2_points     = (const float*)d_in[5];
  const float* lidar_z       = (const float*)d_in[6];
  const float* m1w0=(const float*)d_in[7],  *m1g0=(const float*)d_in[9],  *m1e0=(const float*)d_in[10];
  const float* m1w1=(const float*)d_in[11], *m1g1=(const float*)d_in[13], *m1e1=(const float*)d_in[14];
  const float* piw =(const float*)d_in[15], *pib =(const float*)d_in[16], *pig =(const float*)d_in[17], *pie =(const float*)d_in[18];
  const float* m2w0=(const float*)d_in[19], *m2g0=(const float*)d_in[21], *m2e0=(const float*)d_in[22];
  const float* m2w1=(const float*)d_in[23], *m2g1=(const float*)d_in[25], *m2e1=(const float*)d_in[26];
  const float* pcw =(const float*)d_in[27], *pcb =(const float*)d_in[28], *pcg =(const float*)d_in[29], *pce =(const float*)d_in[30];
  const float* m3w0=(const float*)d_in[31], *m3g0=(const float*)d_in[33], *m3e0=(const float*)d_in[34];
  const float* m3w1=(const float*)d_in[35], *m3g1=(const float*)d_in[37], *m3e1=(const float*)d_in[38];
  float* out = (float*)d_out;

  float* ws     = (float*)d_ws;
  float* wxyz   = ws;                        // 24576
  float* normW  = wxyz   + 24576;            // 524288
  float* normF2 = normW  + 524288;           // 524288
  float* piwT   = normF2 + 524288;           // 384
  float* pcwT   = piwT   + 384;              // 640
  float* stats  = pcwT   + 640;              // 2048
  float* gram   = stats  + 2048;             // 128
  int*   idxq   = (int*)(gram + 128);        // 262144
  int*   idx2   = idxq   + 262144;           // 131072
  float* validf = (float*)(idx2 + 131072);   // 131072
  _Float16* pif1h = (_Float16*)(validf + 131072);   // 1048576 f16 = 524288 floats
  float* X1f    = validf + 131072 + 524288;
  _Float16* X1  = (_Float16*)X1f;            // 25165824 f16 = 12582912 floats
  float* y2f    = X1f + 12582912;
  _Float16* y2h = (_Float16*)y2f;            // 16777216 f16 = 8388608 floats
  float* y3f    = y2f + 8388608;
  _Float16* y3h = (_Float16*)y3f;            // 8388608 floats
  float* whb    = y3f + 8388608;             // f16 weights: 49152 f16 = 24576 floats
  _Float16* w1h = (_Float16*)whb;            // 12288
  _Float16* w2h = w1h + 12288;               // 8192
  _Float16* w3h = w2h + 8192;                // 8192
  _Float16* w4h = w3h + 8192;                // 4096
  _Float16* w5h = w4h + 4096;                // 12288
  _Float16* w6h = w5h + 12288;               // 4096
  // aliases (regions dead by the time they're overwritten):
  _Float16* y4h = (_Float16*)X1f;            // X1 dead after k_mfma_m1
  _Float16* y5h = (_Float16*)(X1f + 8388608);
  _Float16* y6h = y3h;                       // y3 dead after first k_mfma_pw64

  hipMemsetAsync(stats, 0, (2048+128)*sizeof(float), stream);
  k_prep<<<4388,256,0,stream>>>(warped_xyz, lidar_z, warped_points, f2_points,
                                m1w0, m1w1, piw, pcw, m2w0, m2w1, m3w0, m3w1,
                                wxyz, normW, normF2, piwT, pcwT,
                                w1h, w2h, w3h, w4h, w5h, w6h);
  k_knn<32,false><<<8192,256,0,stream>>>(warped_xyz, f2_xyz, idxq, nullptr);
  k_knn<16,true ><<<8192,256,0,stream>>>(xyz_proj, xyz_proj, idx2, validf);
  k_buildX1<<<1024,256,0,stream>>>(wxyz, f2_xyz, normW, normF2, idxq, X1);
  k_gram<<<96,256,0,stream>>>(wxyz, f2_xyz, idxq, idx2, gram);
  k_gram_fin<<<1,128,0,stream>>>(gram, piw, pib, pcw, pcb, stats);
  k_mfma_stats1<<<1024,256,0,stream>>>(X1, w1h, stats);
  k_mfma_m1<<<1024,256,0,stream>>>(X1, w1h, w2h, m1g0, m1e0, stats, y2h);
  k_mfma_m2a<<<1024,256,0,stream>>>(wxyz, f2_xyz, idxq, piwT, pib, pig, pie,
                                    m1g1, m1e1, y2h, w3h, stats, y3h);
  k_mfma_pw64<<<1024,256,0,stream>>>(y3h, w4h, m2g0, m2e0,
                                     stats+3*256, stats+4*256, INV_R1, y4h);
  k_softmax1<<<2048,256,0,stream>>>(y2h, y4h, stats, m1g1, m1e1, m2g1, m2e1, pif1h);
  k_mfma_m3a<<<512,256,0,stream>>>(wxyz, warped_points, pif1h, idx2,
                                   pcwT, pcb, pcg, pce, w5h, stats, y5h);
  k_mfma_pw64<<<512,256,0,stream>>>(y5h, w6h, m3g0, m3e0,
                                    stats+6*256, stats+7*256, INV_R2, y6h);
  k_softmax2<<<2048,256,0,stream>>>(y6h, pif1h, idx2, validf, stats, m3g1, m3e1, out);
}

// Round 8
// 548.312 us; speedup vs baseline: 2.8291x; 1.0512x over previous
//
#include <hip/hip_runtime.h>
#include <math.h>

// ---------------- problem constants ----------------
constexpr int Bn  = 2;
constexpr int HWn = 4096;     // H*W
constexpr int Nn  = 4096;
constexpr int KQn = 32;
constexpr int KNn = 16;
constexpr float INV_R1 = 1.0f/262144.0f;   // exact pow2
constexpr float INV_R2 = 1.0f/131072.0f;   // exact pow2

typedef _Float16 f16x8 __attribute__((ext_vector_type(8)));
typedef float    f32x4 __attribute__((ext_vector_type(4)));

__device__ __forceinline__ float wred64(float v){
  #pragma unroll
  for (int m = 32; m > 0; m >>= 1) v += __shfl_xor(v, m, 64);
  return v;
}
__device__ __forceinline__ float leakyf(float v){ return v > 0.f ? v : 0.1f*v; }

__device__ __forceinline__ void bn_param(const float* st, int c, float inv_n,
                                         const float* g, const float* e,
                                         float& sc, float& sh){
  float mu  = st[c]*inv_n;
  float var = st[128+c]*inv_n - mu*mu;
  float s   = g[c]*rsqrtf(var + 1e-5f);
  sc = s; sh = e[c] - mu*s;
}

// Build the 70-channel stage-1 input row: [wxyz(3), f2_xyz[idx](3), normW*normF2(64)]
__device__ __forceinline__ void build_x70(int row,
    const float* __restrict__ wxyz, const float* __restrict__ f2_xyz,
    const float* __restrict__ normW, const float* __restrict__ normF2,
    const int* __restrict__ idxq, float* x){
  int p = row >> 5;
  int b = p >> 12;
  int idx = idxq[row];
  const float* wx = wxyz + (size_t)p*3;
  const float* fx = f2_xyz + ((size_t)b*Nn + idx)*3;
  x[0]=wx[0]; x[1]=wx[1]; x[2]=wx[2];
  x[3]=fx[0]; x[4]=fx[1]; x[5]=fx[2];
  const float4* nw = (const float4*)(normW  + (size_t)p*64);
  const float4* nf = (const float4*)(normF2 + ((size_t)b*Nn + idx)*64);
  #pragma unroll
  for (int c=0;c<16;c++){
    float4 a = nw[c], q = nf[c];
    x[6+4*c+0]=a.x*q.x; x[6+4*c+1]=a.y*q.y; x[6+4*c+2]=a.z*q.z; x[6+4*c+3]=a.w*q.w;
  }
}

// Build the 10-channel stage-2 geometry row
__device__ __forceinline__ void build_x10(int row,
    const float* __restrict__ wxyz, const int* __restrict__ idx2, float* x){
  int p = row >> 4, b = p >> 12;
  int idx = idx2[row];
  const float* nw = wxyz + (size_t)p*3;
  const float* gw = wxyz + ((size_t)b*HWn + idx)*3;
  float n0=nw[0],n1=nw[1],n2=nw[2];
  float g0=gw[0],g1=gw[1],g2=gw[2];
  float d0=g0-n0, d1=g1-n1, d2=g2-n2;
  x[0]=n0;x[1]=n1;x[2]=n2; x[3]=g0;x[4]=g1;x[5]=g2;
  x[6]=d0;x[7]=d1;x[8]=d2; x[9]=sqrtf(d0*d0+d1*d1+d2*d2+1e-20f);
}

// ---------------- prep: norms, wxyz, weight transposes + f16 weights ----------------
__global__ __launch_bounds__(256) void k_prep(
    const float* __restrict__ warped_xyz, const float* __restrict__ lidar_z,
    const float* __restrict__ warped_points, const float* __restrict__ f2_points,
    const float* __restrict__ m1w0, const float* __restrict__ m1w1,
    const float* __restrict__ piw, const float* __restrict__ pcw,
    const float* __restrict__ m2w0, const float* __restrict__ m2w1,
    const float* __restrict__ m3w0, const float* __restrict__ m3w1,
    float* __restrict__ wxyz, float* __restrict__ normW, float* __restrict__ normF2,
    float* __restrict__ piwT, float* __restrict__ pcwT,
    _Float16* __restrict__ w1h, _Float16* __restrict__ w2h,
    _Float16* __restrict__ w3h, _Float16* __restrict__ w4h,
    _Float16* __restrict__ w5h, _Float16* __restrict__ w6h)
{
  int blk = blockIdx.x, tid = threadIdx.x;
  if (blk < 4096){
    int lane = tid & 63;
    int p = blk*4 + (tid >> 6);            // 0..16383
    const float* src; float* dst;
    if (p < Bn*HWn){ src = warped_points + (size_t)p*64; dst = normW + (size_t)p*64; }
    else { int q = p - Bn*HWn; src = f2_points + (size_t)q*64; dst = normF2 + (size_t)q*64; }
    float x = src[lane];
    float m = wred64(x) * (1.f/64.f);
    float d = x - m;
    float ss = wred64(d*d);
    float s = fmaxf(sqrtf(ss*(1.f/63.f)), 1e-12f);
    dst[lane] = d / s;
  } else if (blk < 4192){
    int e = (blk-4096)*256 + tid;          // < 24576
    wxyz[e] = warped_xyz[e] * lidar_z[e/3];
  } else if (blk < 4196){
    int e = (blk-4192)*256 + tid;          // < 1024
    if (e < 384){ piwT[(e & 63)*6  + (e >> 6)] = piw[e]; }
    else if (e < 1024){ int f = e-384; pcwT[(f & 63)*10 + (f >> 6)] = pcw[f]; }
  } else {
    int e = (blk-4196)*256 + tid;          // < 49152
    if (e < 12288){                        // w1h[j][k] : [128 out][96 in-pad]
      int j = e/96, k = e - j*96;
      w1h[e] = (k < 70) ? (_Float16)m1w0[k*128 + j] : (_Float16)0.f;
    } else if (e < 20480){                 // w2h[d][c] : [64][128]
      int f = e - 12288; int d = f >> 7, c = f & 127;
      w2h[f] = (_Float16)m1w1[c*64 + d];
    } else if (e < 28672){                 // w3h[d][c] : [64][128]
      int f = e - 20480; int d = f >> 7, c = f & 127;
      w3h[f] = (_Float16)m2w0[c*64 + d];
    } else if (e < 32768){                 // w4h[d][c] : [64][64]
      int f = e - 28672; int d = f >> 6, c = f & 63;
      w4h[f] = (_Float16)m2w1[c*64 + d];
    } else if (e < 45056){                 // w5h[d][c] : [64][192]
      int f = e - 32768; int d = f/192, c = f - 192*d;
      w5h[f] = (_Float16)m3w0[c*64 + d];
    } else {                               // w6h[d][c] : [64][64]
      int f = e - 45056; int d = f >> 6, c = f & 63;
      w6h[f] = (_Float16)m3w1[c*64 + d];
    }
  }
}

// ---------------- exact k-smallest radix select on informative bits ----------------
// Per-thread points are CONTIGUOUS (16 pts = 192B = 12 float4 loads).
// Keys biased by block-min; first digit starts at msb(max-min).
template<int K, bool WRITE_VALID>
__global__ __launch_bounds__(256) void k_knn(
    const float* __restrict__ qpts, const float* __restrict__ pts,
    int* __restrict__ oidx, float* __restrict__ ovalid)
{
  __shared__ int hist[4*256];
  __shared__ int wsum[4];
  __shared__ unsigned int redm[4], redM[4];
  __shared__ unsigned int sh_sel;
  __shared__ int sh_rem, sh_cls, cnt_lt, cnt_eq;
  int b = blockIdx.x >> 12;
  int qi = blockIdx.x & 4095;
  int tid = threadIdx.x;
  int lane = tid & 63, wv = tid >> 6;
  const float* qp = qpts + ((size_t)(b*HWn+qi))*3;
  float qx=qp[0], qy=qp[1], qz=qp[2];
  const float* pb = pts + (size_t)b*Nn*3;
  unsigned int key[16];
  {
    const float4* pb4 = (const float4*)(pb + (size_t)tid*48);  // 16 pts = 48 floats
    float4 v[12];
    #pragma unroll
    for (int i=0;i<12;i++) v[i] = pb4[i];
    const float* f = (const float*)v;
    #pragma unroll
    for (int i=0;i<16;i++){
      float dx = __fsub_rn(qx, f[i*3+0]);
      float dy = __fsub_rn(qy, f[i*3+1]);
      float dz = __fsub_rn(qz, f[i*3+2]);
      float d2 = __fadd_rn(__fadd_rn(__fmul_rn(dx,dx), __fmul_rn(dy,dy)), __fmul_rn(dz,dz));
      key[i] = __float_as_uint(d2);        // nonneg floats: uint order == float order
    }
  }
  // block min/max of keys
  unsigned int mn = key[0], mx = key[0];
  #pragma unroll
  for (int i=1;i<16;i++){ mn = min(mn, key[i]); mx = max(mx, key[i]); }
  #pragma unroll
  for (int m=32;m>0;m>>=1){
    mn = min(mn, (unsigned int)__shfl_xor((int)mn, m, 64));
    mx = max(mx, (unsigned int)__shfl_xor((int)mx, m, 64));
  }
  if (lane == 0){ redm[wv] = mn; redM[wv] = mx; }
  if (tid == 0){ cnt_lt = 0; cnt_eq = 0; }
  __syncthreads();
  mn = min(min(redm[0],redm[1]), min(redm[2],redm[3]));
  mx = max(max(redM[0],redM[1]), max(redM[2],redM[3]));
  unsigned int R = mx - mn;
  int L = (R == 0u) ? 0 : (31 - __clz(R));
  int shift = (L > 7) ? (L - 7) : 0;
  unsigned int dmask = 255u;

  unsigned int active = 0xFFFFu, below = 0u;
  int rem = K;
  for (;;){
    __syncthreads();                       // guard hist reuse
    #pragma unroll
    for (int j=0;j<4;j++) hist[j*256 + tid] = 0;
    __syncthreads();
    #pragma unroll
    for (int i=0;i<16;i++){
      if (active & (1u<<i))
        atomicAdd(&hist[wv*256 + (int)(((key[i]-mn) >> shift) & dmask)], 1);
    }
    __syncthreads();
    int h = hist[tid] + hist[256+tid] + hist[512+tid] + hist[768+tid];
    int pref = h;
    #pragma unroll
    for (int m=1;m<64;m<<=1){ int t = __shfl_up(pref, m, 64); if (lane >= m) pref += t; }
    if (lane == 63) wsum[wv] = pref;
    __syncthreads();
    int off = 0;
    #pragma unroll
    for (int i=0;i<3;i++) if (i < wv) off += wsum[i];
    pref += off;                           // inclusive prefix over buckets 0..tid
    if (pref >= rem && (pref - h) < rem){
      sh_sel = (unsigned int)tid;
      sh_rem = rem - (pref - h);
      sh_cls = h;
    }
    __syncthreads();
    unsigned int sel = sh_sel; rem = sh_rem; int cls = sh_cls;
    #pragma unroll
    for (int i=0;i<16;i++){
      if (active & (1u<<i)){
        unsigned int d = ((key[i]-mn) >> shift) & dmask;
        if (d < sel) below |= (1u<<i);
        if (d != sel) active &= ~(1u<<i);
      }
    }
    if (cls == rem || shift == 0) break;
    int w = (shift < 8) ? shift : 8;
    shift -= w;
    dmask = (w == 8) ? 255u : ((1u<<w) - 1u);
  }
  // output: all 'below' + rem of the final equal-class
  size_t obase = ((size_t)(b*HWn+qi))*K;
  int nless = K - rem;
  const unsigned int U100 = __float_as_uint(100.0f);  // DIST*DIST
  #pragma unroll
  for (int i=0;i<16;i++){
    if (below & (1u<<i)){
      int s = atomicAdd(&cnt_lt, 1);
      oidx[obase+s] = tid*16 + i;
      if constexpr (WRITE_VALID) ovalid[obase+s] = (key[i] < U100) ? 1.f : 0.f;
    } else if (active & (1u<<i)){
      int s = atomicAdd(&cnt_eq, 1);
      if (s < rem){
        oidx[obase+nless+s] = tid*16 + i;
        if constexpr (WRITE_VALID) ovalid[obase+nless+s] = (key[i] < U100) ? 1.f : 0.f;
      }
    }
  }
}

// ---------------- fused: build X1 rows + y1 stats MFMA + Gram matrices ----------------
// Blocks 0..1023: build 256 X1 rows, then MFMA stats on own rows (L1/L2-hot).
// Blocks 1024..1087: pi Gram (7x7). Blocks 1088..1119: pc Gram (11x11).
__global__ __launch_bounds__(256) void k_build_stats(
    const float* __restrict__ wxyz, const float* __restrict__ f2_xyz,
    const float* __restrict__ normW, const float* __restrict__ normF2,
    const int* __restrict__ idxq, const int* __restrict__ idx2,
    const _Float16* __restrict__ w1h,
    _Float16* __restrict__ X1, float* stats, float* __restrict__ gram)
{
  __shared__ float ssum[128], sssq[128];
  __shared__ float sacc[66];
  int blk = blockIdx.x, tid = threadIdx.x, lane = tid & 63;
  if (blk < 1024){
    // ---- build phase ----
    int row = blk*256 + tid;
    {
      float x[70];
      build_x70(row, wxyz, f2_xyz, normW, normF2, idxq, x);
      unsigned int* d32 = (unsigned int*)(X1 + (size_t)row*96);
      union { unsigned int u; _Float16 h[2]; } pk;
      #pragma unroll
      for (int c=0;c<35;c++){
        pk.h[0] = (_Float16)x[2*c]; pk.h[1] = (_Float16)x[2*c+1];
        d32[c] = pk.u;
      }
      #pragma unroll
      for (int c=35;c<48;c++) d32[c] = 0u;
    }
    if (tid < 128){ ssum[tid]=0.f; sssq[tid]=0.f; }
    __syncthreads();
    // ---- stats phase ----
    int wave = tid >> 6;
    int quad = lane >> 4, n16 = lane & 15;
    float r1[8], r2[8];
    #pragma unroll
    for (int i=0;i<8;i++){ r1[i]=0.f; r2[i]=0.f; }
    for (int t=0;t<4;t++){
      int m0 = blk*256 + t*64 + wave*16;
      const _Float16* xr = X1 + (size_t)(m0 + n16)*96 + quad*8;
      f16x8 a0 = *(const f16x8*)(xr);
      f16x8 a1 = *(const f16x8*)(xr + 32);
      f16x8 a2 = *(const f16x8*)(xr + 64);
      #pragma unroll
      for (int nt = 0; nt < 8; nt++){
        const _Float16* wr = w1h + (size_t)(nt*16 + n16)*96 + quad*8;
        f16x8 b0 = *(const f16x8*)(wr);
        f16x8 b1 = *(const f16x8*)(wr + 32);
        f16x8 b2 = *(const f16x8*)(wr + 64);
        f32x4 acc = {0.f,0.f,0.f,0.f};
        acc = __builtin_amdgcn_mfma_f32_16x16x32_f16(a0, b0, acc, 0,0,0);
        acc = __builtin_amdgcn_mfma_f32_16x16x32_f16(a1, b1, acc, 0,0,0);
        acc = __builtin_amdgcn_mfma_f32_16x16x32_f16(a2, b2, acc, 0,0,0);
        float s1 = acc[0]+acc[1]+acc[2]+acc[3];
        float s2 = acc[0]*acc[0]+acc[1]*acc[1]+acc[2]*acc[2]+acc[3]*acc[3];
        s1 += __shfl_xor(s1, 16, 64); s1 += __shfl_xor(s1, 32, 64);
        s2 += __shfl_xor(s2, 16, 64); s2 += __shfl_xor(s2, 32, 64);
        r1[nt] += s1; r2[nt] += s2;
      }
    }
    if (quad == 0){
      #pragma unroll
      for (int nt=0;nt<8;nt++){
        atomicAdd(&ssum[nt*16+n16], r1[nt]); atomicAdd(&sssq[nt*16+n16], r2[nt]);
      }
    }
    __syncthreads();
    if (tid < 128){ atomicAdd(&stats[tid], ssum[tid]); atomicAdd(&stats[128+tid], sssq[tid]); }
  } else if (blk < 1088){
    float a[28];
    #pragma unroll
    for (int q=0;q<28;q++) a[q]=0.f;
    int g = (blk-1024)*256 + tid;
    for (int s=0;s<16;s++){
      int row = g + s*16384;
      int p = row >> 5, b = p >> 12;
      int idx = idxq[row];
      const float* wx = wxyz + (size_t)p*3;
      const float* fx = f2_xyz + ((size_t)b*Nn + idx)*3;
      float xt[7] = {wx[0],wx[1],wx[2],fx[0],fx[1],fx[2],1.f};
      int q=0;
      #pragma unroll
      for (int i=0;i<7;i++)
        #pragma unroll
        for (int j=i;j<7;j++) a[q++] += xt[i]*xt[j];
    }
    if (tid < 28) sacc[tid]=0.f;
    __syncthreads();
    #pragma unroll
    for (int q=0;q<28;q++){
      float v = wred64(a[q]);
      if (lane==0) atomicAdd(&sacc[q], v);
    }
    __syncthreads();
    if (tid < 28) atomicAdd(&gram[tid], sacc[tid]);
  } else {
    float a[66];
    #pragma unroll
    for (int q=0;q<66;q++) a[q]=0.f;
    int g = (blk-1088)*256 + tid;
    for (int s=0;s<16;s++){
      int row = g + s*8192;
      float x[10];
      build_x10(row, wxyz, idx2, x);
      float xt[11] = {x[0],x[1],x[2],x[3],x[4],x[5],x[6],x[7],x[8],x[9],1.f};
      int q=0;
      #pragma unroll
      for (int i=0;i<11;i++)
        #pragma unroll
        for (int j=i;j<11;j++) a[q++] += xt[i]*xt[j];
    }
    if (tid < 66) sacc[tid]=0.f;
    __syncthreads();
    #pragma unroll
    for (int q=0;q<66;q++){
      float v = wred64(a[q]);
      if (lane==0) atomicAdd(&sacc[q], v);
    }
    __syncthreads();
    if (tid < 66) atomicAdd(&gram[32+tid], sacc[tid]);
  }
}

__global__ __launch_bounds__(128) void k_gram_fin(
    const float* __restrict__ gram,
    const float* __restrict__ piw, const float* __restrict__ pib,
    const float* __restrict__ pcw, const float* __restrict__ pcb,
    float* stats)
{
  int tid = threadIdx.x;
  if (tid < 64){
    int c = tid;
    float wt[7];
    #pragma unroll
    for (int i=0;i<6;i++) wt[i] = piw[i*64+c];
    wt[6] = pib[c];
    const float* G = gram;
    float sum=0.f, ssq=0.f;
    #pragma unroll
    for (int i=0;i<7;i++){
      int offi = i*7 - (i*(i-1))/2;
      sum += wt[i]*G[offi + (6-i)];
      #pragma unroll
      for (int j=0;j<7;j++){
        int ii = i<j? i : j, jj = i<j? j : i;
        int o = ii*7 - (ii*(ii-1))/2 + (jj-ii);
        ssq += wt[i]*wt[j]*G[o];
      }
    }
    stats[2*256+c] = sum; stats[2*256+128+c] = ssq;
  } else {
    int c = tid-64;
    float wt[11];
    #pragma unroll
    for (int i=0;i<10;i++) wt[i] = pcw[i*64+c];
    wt[10] = pcb[c];
    const float* G = gram + 32;
    float sum=0.f, ssq=0.f;
    #pragma unroll
    for (int i=0;i<11;i++){
      int offi = i*11 - (i*(i-1))/2;
      sum += wt[i]*G[offi + (10-i)];
      #pragma unroll
      for (int j=0;j<11;j++){
        int ii = i<j? i : j, jj = i<j? j : i;
        int o = ii*11 - (ii*(ii-1))/2 + (jj-ii);
        ssq += wt[i]*wt[j]*G[o];
      }
    }
    stats[5*256+c] = sum; stats[5*256+128+c] = ssq;
  }
}

// ---------------- MFMA m1: 4 tiles/block; y1 -> BN/leaky -> t (LDS) -> x W2 -> y2 ----------------
__global__ __launch_bounds__(256) void k_mfma_m1(
    const _Float16* __restrict__ X1, const _Float16* __restrict__ w1h,
    const _Float16* __restrict__ w2h,
    const float* __restrict__ m1g0, const float* __restrict__ m1e0,
    float* stats, _Float16* __restrict__ y2h)
{
  __shared__ _Float16 st[64*136];
  __shared__ float sc1[128], sh1[128], ssum[64], sssq[64];
  int tid = threadIdx.x;
  if (tid < 128){
    float s,h; bn_param(stats, tid, INV_R1, m1g0, m1e0, s, h);
    sc1[tid]=s; sh1[tid]=h;
  }
  if (tid < 64){ ssum[tid]=0.f; sssq[tid]=0.f; }
  __syncthreads();
  int wave = tid >> 6, lane = tid & 63;
  int quad = lane >> 4, n16 = lane & 15;
  float r1[4], r2[4];
  #pragma unroll
  for (int i=0;i<4;i++){ r1[i]=0.f; r2[i]=0.f; }
  for (int t=0;t<4;t++){
    int m0 = blockIdx.x*256 + t*64 + wave*16;
    const _Float16* xr = X1 + (size_t)(m0 + n16)*96 + quad*8;
    f16x8 a0 = *(const f16x8*)(xr);
    f16x8 a1 = *(const f16x8*)(xr + 32);
    f16x8 a2 = *(const f16x8*)(xr + 64);
    #pragma unroll
    for (int nt = 0; nt < 8; nt++){
      const _Float16* wr = w1h + (size_t)(nt*16 + n16)*96 + quad*8;
      f16x8 b0 = *(const f16x8*)(wr);
      f16x8 b1 = *(const f16x8*)(wr + 32);
      f16x8 b2 = *(const f16x8*)(wr + 64);
      f32x4 acc = {0.f,0.f,0.f,0.f};
      acc = __builtin_amdgcn_mfma_f32_16x16x32_f16(a0, b0, acc, 0,0,0);
      acc = __builtin_amdgcn_mfma_f32_16x16x32_f16(a1, b1, acc, 0,0,0);
      acc = __builtin_amdgcn_mfma_f32_16x16x32_f16(a2, b2, acc, 0,0,0);
      int ch = nt*16 + n16;
      float sc = sc1[ch], sh = sh1[ch];
      #pragma unroll
      for (int r=0;r<4;r++){
        float v = leakyf(acc[r]*sc + sh);
        st[(size_t)(wave*16 + quad*4 + r)*136 + ch] = (_Float16)v;
      }
    }
    __syncthreads();
    const _Float16* tr = st + (size_t)(wave*16 + n16)*136 + quad*8;
    f16x8 t0 = *(const f16x8*)(tr);
    f16x8 t1 = *(const f16x8*)(tr + 32);
    f16x8 t2 = *(const f16x8*)(tr + 64);
    f16x8 t3 = *(const f16x8*)(tr + 96);
    #pragma unroll
    for (int nt = 0; nt < 4; nt++){
      const _Float16* wr = w2h + (size_t)(nt*16 + n16)*128 + quad*8;
      f16x8 b0 = *(const f16x8*)(wr);
      f16x8 b1 = *(const f16x8*)(wr + 32);
      f16x8 b2 = *(const f16x8*)(wr + 64);
      f16x8 b3 = *(const f16x8*)(wr + 96);
      f32x4 acc = {0.f,0.f,0.f,0.f};
      acc = __builtin_amdgcn_mfma_f32_16x16x32_f16(t0, b0, acc, 0,0,0);
      acc = __builtin_amdgcn_mfma_f32_16x16x32_f16(t1, b1, acc, 0,0,0);
      acc = __builtin_amdgcn_mfma_f32_16x16x32_f16(t2, b2, acc, 0,0,0);
      acc = __builtin_amdgcn_mfma_f32_16x16x32_f16(t3, b3, acc, 0,0,0);
      int ch = nt*16 + n16;
      #pragma unroll
      for (int r=0;r<4;r++){
        int rowg = blockIdx.x*256 + t*64 + wave*16 + quad*4 + r;
        y2h[(size_t)rowg*64 + ch] = (_Float16)acc[r];
      }
      float s1 = acc[0]+acc[1]+acc[2]+acc[3];
      float s2 = acc[0]*acc[0]+acc[1]*acc[1]+acc[2]*acc[2]+acc[3]*acc[3];
      s1 += __shfl_xor(s1, 16, 64); s1 += __shfl_xor(s1, 32, 64);
      s2 += __shfl_xor(s2, 16, 64); s2 += __shfl_xor(s2, 32, 64);
      r1[nt] += s1; r2[nt] += s2;
    }
    __syncthreads();
  }
  if (quad == 0){
    #pragma unroll
    for (int nt=0;nt<4;nt++){
      atomicAdd(&ssum[nt*16+n16], r1[nt]); atomicAdd(&sssq[nt*16+n16], r2[nt]);
    }
  }
  __syncthreads();
  if (tid < 64){ atomicAdd(&stats[1*256+tid], ssum[tid]); atomicAdd(&stats[1*256+128+tid], sssq[tid]); }
}

// ---------------- MFMA m2a: 4 tiles/block; u=[pi_enc|feat] in LDS, y3 = u x W3 ----------------
__global__ __launch_bounds__(256) void k_mfma_m2a(
    const float* __restrict__ wxyz, const float* __restrict__ f2_xyz,
    const int* __restrict__ idxq,
    const float* __restrict__ piwT, const float* __restrict__ pib,
    const float* __restrict__ pig, const float* __restrict__ pie,
    const float* __restrict__ m1g1, const float* __restrict__ m1e1,
    const _Float16* __restrict__ y2h, const _Float16* __restrict__ w3h,
    float* stats, _Float16* __restrict__ y3h)
{
  __shared__ _Float16 su[64*136];
  __shared__ float spw[384];
  __shared__ float scp[64], shp[64], sc2[64], sh2[64], ssum[64], sssq[64];
  int tid = threadIdx.x;
  for (int d = tid; d < 384; d += 256) spw[d] = piwT[d];
  if (tid < 64){
    float s,h;
    bn_param(stats+2*256, tid, INV_R1, pig,  pie,  s, h); scp[tid]=s; shp[tid]=h;
    bn_param(stats+1*256, tid, INV_R1, m1g1, m1e1, s, h); sc2[tid]=s; sh2[tid]=h;
    ssum[tid]=0.f; sssq[tid]=0.f;
  }
  __syncthreads();
  int r = tid & 63, cg = tid >> 6;
  int wave = tid >> 6, lane = tid & 63, quad = lane >> 4, n16 = lane & 15;
  float r1[4], r2[4];
  #pragma unroll
  for (int i=0;i<4;i++){ r1[i]=0.f; r2[i]=0.f; }
  for (int t=0;t<4;t++){
    int rowg = blockIdx.x*256 + t*64 + r;
    {
      int p = rowg >> 5, b = p >> 12;
      int idx = idxq[rowg];
      const float* wx = wxyz + (size_t)p*3;
      const float* fx = f2_xyz + ((size_t)b*Nn + idx)*3;
      float x0=wx[0],x1=wx[1],x2=wx[2],x3=fx[0],x4=fx[1],x5=fx[2];
      #pragma unroll
      for (int jj=0;jj<16;jj++){
        int j = cg*16 + jj;
        const float* pw = spw + j*6;
        float e = pib[j] + x0*pw[0]+x1*pw[1]+x2*pw[2]+x3*pw[3]+x4*pw[4]+x5*pw[5];
        su[r*136 + j] = (_Float16)leakyf(e*scp[j] + shp[j]);
      }
      const f16x8* yr = (const f16x8*)(y2h + (size_t)rowg*64 + cg*16);
      f16x8 q0 = yr[0], q1 = yr[1];
      #pragma unroll
      for (int jj=0;jj<8;jj++){
        int c = cg*16 + jj;
        su[r*136 + 64 + c] = (_Float16)leakyf((float)q0[jj]*sc2[c] + sh2[c]);
      }
      #pragma unroll
      for (int jj=0;jj<8;jj++){
        int c = cg*16 + 8 + jj;
        su[r*136 + 64 + c] = (_Float16)leakyf((float)q1[jj]*sc2[c] + sh2[c]);
      }
    }
    __syncthreads();
    const _Float16* ur = su + (size_t)(wave*16 + n16)*136 + quad*8;
    f16x8 a0 = *(const f16x8*)(ur);
    f16x8 a1 = *(const f16x8*)(ur + 32);
    f16x8 a2 = *(const f16x8*)(ur + 64);
    f16x8 a3 = *(const f16x8*)(ur + 96);
    #pragma unroll
    for (int nt = 0; nt < 4; nt++){
      const _Float16* wr = w3h + (size_t)(nt*16 + n16)*128 + quad*8;
      f16x8 b0 = *(const f16x8*)(wr);
      f16x8 b1 = *(const f16x8*)(wr + 32);
      f16x8 b2 = *(const f16x8*)(wr + 64);
      f16x8 b3 = *(const f16x8*)(wr + 96);
      f32x4 acc = {0.f,0.f,0.f,0.f};
      acc = __builtin_amdgcn_mfma_f32_16x16x32_f16(a0, b0, acc, 0,0,0);
      acc = __builtin_amdgcn_mfma_f32_16x16x32_f16(a1, b1, acc, 0,0,0);
      acc = __builtin_amdgcn_mfma_f32_16x16x32_f16(a2, b2, acc, 0,0,0);
      acc = __builtin_amdgcn_mfma_f32_16x16x32_f16(a3, b3, acc, 0,0,0);
      int ch = nt*16 + n16;
      #pragma unroll
      for (int rr=0;rr<4;rr++){
        int rg = blockIdx.x*256 + t*64 + wave*16 + quad*4 + rr;
        y3h[(size_t)rg*64 + ch] = (_Float16)acc[rr];
      }
      float s1 = acc[0]+acc[1]+acc[2]+acc[3];
      float s2 = acc[0]*acc[0]+acc[1]*acc[1]+acc[2]*acc[2]+acc[3]*acc[3];
      s1 += __shfl_xor(s1, 16, 64); s1 += __shfl_xor(s1, 32, 64);
      s2 += __shfl_xor(s2, 16, 64); s2 += __shfl_xor(s2, 32, 64);
      r1[nt] += s1; r2[nt] += s2;
    }
    __syncthreads();
  }
  if (quad == 0){
    #pragma unroll
    for (int nt=0;nt<4;nt++){
      atomicAdd(&ssum[nt*16+n16], r1[nt]); atomicAdd(&sssq[nt*16+n16], r2[nt]);
    }
  }
  __syncthreads();
  if (tid < 64){ atomicAdd(&stats[3*256+tid], ssum[tid]); atomicAdd(&stats[3*256+128+tid], sssq[tid]); }
}

// ---------------- generic MFMA pointwise 64->64, 4 tiles/block ----------------
__global__ __launch_bounds__(256) void k_mfma_pw64(
    const _Float16* __restrict__ yin, const _Float16* __restrict__ wh,
    const float* __restrict__ g, const float* __restrict__ e,
    const float* statsIn, float* statsOut, float inv_n,
    _Float16* __restrict__ yout)
{
  __shared__ _Float16 stt[64*72];
  __shared__ float sc[64], sh[64], ssum[64], sssq[64];
  int tid = threadIdx.x;
  if (tid < 64){
    float s,h; bn_param(statsIn, tid, inv_n, g, e, s, h);
    sc[tid]=s; sh[tid]=h; ssum[tid]=0.f; sssq[tid]=0.f;
  }
  __syncthreads();
  int r = tid & 63, cg = tid >> 6;
  int wave = tid >> 6, lane = tid & 63, quad = lane >> 4, n16 = lane & 15;
  float r1[4], r2[4];
  #pragma unroll
  for (int i=0;i<4;i++){ r1[i]=0.f; r2[i]=0.f; }
  for (int t=0;t<4;t++){
    int rowg = blockIdx.x*256 + t*64 + r;
    const f16x8* yr = (const f16x8*)(yin + (size_t)rowg*64 + cg*16);
    f16x8 q0 = yr[0], q1 = yr[1];
    #pragma unroll
    for (int jj=0;jj<8;jj++){
      int c = cg*16 + jj;
      stt[r*72 + c] = (_Float16)leakyf((float)q0[jj]*sc[c] + sh[c]);
    }
    #pragma unroll
    for (int jj=0;jj<8;jj++){
      int c = cg*16 + 8 + jj;
      stt[r*72 + c] = (_Float16)leakyf((float)q1[jj]*sc[c] + sh[c]);
    }
    __syncthreads();
    const _Float16* tr = stt + (size_t)(wave*16 + n16)*72 + quad*8;
    f16x8 a0 = *(const f16x8*)(tr);
    f16x8 a1 = *(const f16x8*)(tr + 32);
    #pragma unroll
    for (int nt = 0; nt < 4; nt++){
      const _Float16* wr = wh + (size_t)(nt*16 + n16)*64 + quad*8;
      f16x8 b0 = *(const f16x8*)(wr);
      f16x8 b1 = *(const f16x8*)(wr + 32);
      f32x4 acc = {0.f,0.f,0.f,0.f};
      acc = __builtin_amdgcn_mfma_f32_16x16x32_f16(a0, b0, acc, 0,0,0);
      acc = __builtin_amdgcn_mfma_f32_16x16x32_f16(a1, b1, acc, 0,0,0);
      int ch = nt*16 + n16;
      #pragma unroll
      for (int rr=0;rr<4;rr++){
        int rg = blockIdx.x*256 + t*64 + wave*16 + quad*4 + rr;
        yout[(size_t)rg*64 + ch] = (_Float16)acc[rr];
      }
      float s1 = acc[0]+acc[1]+acc[2]+acc[3];
      float s2 = acc[0]*acc[0]+acc[1]*acc[1]+acc[2]*acc[2]+acc[3]*acc[3];
      s1 += __shfl_xor(s1, 16, 64); s1 += __shfl_xor(s1, 32, 64);
      s2 += __shfl_xor(s2, 16, 64); s2 += __shfl_xor(s2, 32, 64);
      r1[nt] += s1; r2[nt] += s2;
    }
    __syncthreads();
  }
  if (quad == 0){
    #pragma unroll
    for (int nt=0;nt<4;nt++){
      atomicAdd(&ssum[nt*16+n16], r1[nt]); atomicAdd(&sssq[nt*16+n16], r2[nt]);
    }
  }
  __syncthreads();
  if (tid < 64){ atomicAdd(&statsOut[tid], ssum[tid]); atomicAdd(&statsOut[128+tid], sssq[tid]); }
}

// ---------------- MFMA m3a: 4 tiles/block; v=[pc_enc|wp|pif1_g] (192ch), y5 = v x W5 ----------------
__global__ __launch_bounds__(256) void k_mfma_m3a(
    const float* __restrict__ wxyz, const float* __restrict__ warped_points,
    const _Float16* __restrict__ pif1h, const int* __restrict__ idx2,
    const float* __restrict__ pcwT, const float* __restrict__ pcb,
    const float* __restrict__ pcg, const float* __restrict__ pce,
    const _Float16* __restrict__ w5h,
    float* stats, _Float16* __restrict__ y5h)
{
  __shared__ _Float16 sv[64*200];
  __shared__ float spw[640];
  __shared__ float scp[64], shp[64], ssum[64], sssq[64];
  int tid = threadIdx.x;
  for (int d = tid; d < 640; d += 256) spw[d] = pcwT[d];
  if (tid < 64){
    float s,h; bn_param(stats+5*256, tid, INV_R2, pcg, pce, s, h);
    scp[tid]=s; shp[tid]=h; ssum[tid]=0.f; sssq[tid]=0.f;
  }
  __syncthreads();
  int r = tid & 63, cg = tid >> 6;
  int wave = tid >> 6, lane = tid & 63, quad = lane >> 4, n16 = lane & 15;
  float r1[4], r2[4];
  #pragma unroll
  for (int i=0;i<4;i++){ r1[i]=0.f; r2[i]=0.f; }
  for (int t=0;t<4;t++){
    int rowg = blockIdx.x*256 + t*64 + r;
    {
      int p = rowg >> 4, b = p >> 12;
      int idx = idx2[rowg];
      float x[10];
      build_x10(rowg, wxyz, idx2, x);
      #pragma unroll
      for (int jj=0;jj<16;jj++){
        int j = cg*16 + jj;
        const float* pw = spw + j*10;
        float e = pcb[j];
        #pragma unroll
        for (int i=0;i<10;i++) e += x[i]*pw[i];
        sv[r*200 + j] = (_Float16)leakyf(e*scp[j] + shp[j]);
      }
      const float4* wp = (const float4*)(warped_points + (size_t)p*64 + cg*16);
      #pragma unroll
      for (int v4=0; v4<4; v4++){
        float4 q = wp[v4];
        int c = 64 + cg*16 + v4*4;
        sv[r*200 + c + 0] = (_Float16)q.x;
        sv[r*200 + c + 1] = (_Float16)q.y;
        sv[r*200 + c + 2] = (_Float16)q.z;
        sv[r*200 + c + 3] = (_Float16)q.w;
      }
      const f16x8* pg = (const f16x8*)(pif1h + ((size_t)(b*HWn) + idx)*64 + cg*16);
      f16x8 g0 = pg[0], g1 = pg[1];
      #pragma unroll
      for (int jj=0;jj<8;jj++) sv[r*200 + 128 + cg*16 + jj] = g0[jj];
      #pragma unroll
      for (int jj=0;jj<8;jj++) sv[r*200 + 136 + cg*16 + jj] = g1[jj];
    }
    __syncthreads();
    const _Float16* vr = sv + (size_t)(wave*16 + n16)*200 + quad*8;
    f16x8 a0 = *(const f16x8*)(vr);
    f16x8 a1 = *(const f16x8*)(vr + 32);
    f16x8 a2 = *(const f16x8*)(vr + 64);
    f16x8 a3 = *(const f16x8*)(vr + 96);
    f16x8 a4 = *(const f16x8*)(vr + 128);
    f16x8 a5 = *(const f16x8*)(vr + 160);
    #pragma unroll
    for (int nt = 0; nt < 4; nt++){
      const _Float16* wr = w5h + (size_t)(nt*16 + n16)*192 + quad*8;
      f32x4 acc = {0.f,0.f,0.f,0.f};
      acc = __builtin_amdgcn_mfma_f32_16x16x32_f16(a0, *(const f16x8*)(wr),       acc, 0,0,0);
      acc = __builtin_amdgcn_mfma_f32_16x16x32_f16(a1, *(const f16x8*)(wr + 32),  acc, 0,0,0);
      acc = __builtin_amdgcn_mfma_f32_16x16x32_f16(a2, *(const f16x8*)(wr + 64),  acc, 0,0,0);
      acc = __builtin_amdgcn_mfma_f32_16x16x32_f16(a3, *(const f16x8*)(wr + 96),  acc, 0,0,0);
      acc = __builtin_amdgcn_mfma_f32_16x16x32_f16(a4, *(const f16x8*)(wr + 128), acc, 0,0,0);
      acc = __builtin_amdgcn_mfma_f32_16x16x32_f16(a5, *(const f16x8*)(wr + 160), acc, 0,0,0);
      int ch = nt*16 + n16;
      #pragma unroll
      for (int rr=0;rr<4;rr++){
        int rg = blockIdx.x*256 + t*64 + wave*16 + quad*4 + rr;
        y5h[(size_t)rg*64 + ch] = (_Float16)acc[rr];
      }
      float s1 = acc[0]+acc[1]+acc[2]+acc[3];
      float s2 = acc[0]*acc[0]+acc[1]*acc[1]+acc[2]*acc[2]+acc[3]*acc[3];
      s1 += __shfl_xor(s1, 16, 64); s1 += __shfl_xor(s1, 32, 64);
      s2 += __shfl_xor(s2, 16, 64); s2 += __shfl_xor(s2, 32, 64);
      r1[nt] += s1; r2[nt] += s2;
    }
    __syncthreads();
  }
  if (quad == 0){
    #pragma unroll
    for (int nt=0;nt<4;nt++){
      atomicAdd(&ssum[nt*16+n16], r1[nt]); atomicAdd(&sssq[nt*16+n16], r2[nt]);
    }
  }
  __syncthreads();
  if (tid < 64){ atomicAdd(&stats[6*256+tid], ssum[tid]); atomicAdd(&stats[6*256+128+tid], sssq[tid]); }
}

// ---------------- stage-1 softmax over KQ, weighted sum of feat -> pif1 (f16) ----------------
__global__ __launch_bounds__(256) void k_softmax1(
    const _Float16* __restrict__ y2h, const _Float16* __restrict__ y4h,
    const float* stats,
    const float* __restrict__ m1g1, const float* __restrict__ m1e1,
    const float* __restrict__ m2g1, const float* __restrict__ m2e1,
    _Float16* __restrict__ pif1h)
{
  int tid = threadIdx.x, lane = tid & 63;
  int p = blockIdx.x*4 + (tid >> 6);
  int d = lane;
  float sc2,sh2,sc4,sh4;
  bn_param(stats+1*256, d, INV_R1, m1g1, m1e1, sc2, sh2);
  bn_param(stats+4*256, d, INV_R1, m2g1, m2e1, sc4, sh4);
  size_t rb = (size_t)p*KQn;
  float v[32]; float mx = -1e30f;
  #pragma unroll
  for (int k=0;k<32;k++){
    float t = leakyf((float)y4h[(rb+k)*64 + d]*sc4 + sh4);
    v[k] = t; mx = fmaxf(mx, t);
  }
  float se = 0.f;
  #pragma unroll
  for (int k=0;k<32;k++){ float ev = __expf(v[k]-mx); v[k]=ev; se += ev; }
  float inv = 1.f/se, acc = 0.f;
  #pragma unroll
  for (int k=0;k<32;k++){
    float f = leakyf((float)y2h[(rb+k)*64 + d]*sc2 + sh2);
    acc += v[k]*f;
  }
  pif1h[(size_t)p*64 + d] = (_Float16)(acc*inv);
}

// ---------------- stage-2 masked softmax over KN, weighted sum of gathered pif1 ----------------
__global__ __launch_bounds__(256) void k_softmax2(
    const _Float16* __restrict__ y6h, const _Float16* __restrict__ pif1h,
    const int* __restrict__ idx2, const float* __restrict__ validf,
    const float* stats,
    const float* __restrict__ m3g1, const float* __restrict__ m3e1,
    float* __restrict__ out)
{
  int tid = threadIdx.x, lane = tid & 63;
  int p = blockIdx.x*4 + (tid >> 6);
  int b = p >> 12;
  int d = lane;
  float sc,sh; bn_param(stats+7*256, d, INV_R2, m3g1, m3e1, sc, sh);
  size_t rb = (size_t)p*KNn;
  float v[16]; float mx = -1e30f;
  #pragma unroll
  for (int k=0;k<16;k++){
    float t = leakyf((float)y6h[(rb+k)*64 + d]*sc + sh);
    t = (validf[rb+k] > 0.5f) ? t : -1e10f;
    v[k] = t; mx = fmaxf(mx, t);
  }
  float se = 0.f;
  #pragma unroll
  for (int k=0;k<16;k++){ float ev = __expf(v[k]-mx); v[k]=ev; se += ev; }
  float inv = 1.f/se, acc = 0.f;
  #pragma unroll
  for (int k=0;k<16;k++){
    int idx = idx2[rb+k];
    acc += v[k]*(float)pif1h[((size_t)(b*HWn) + idx)*64 + d];
  }
  out[(size_t)p*64 + d] = acc*inv;
}

// ---------------- launcher ----------------
extern "C" void kernel_launch(void* const* d_in, const int* in_sizes, int n_in,
                              void* d_out, int out_size, void* d_ws, size_t ws_size,
                              hipStream_t stream)
{
  (void)in_sizes; (void)n_in; (void)out_size; (void)ws_size;
  const float* xyz_proj      = (const float*)d_in[0];
  const float* warped_xyz    = (const float*)d_in[1];
  const float* warped_points = (const float*)d_in[2];
  const float* f2_xyz        = (const float*)d_in[4];
  const float* f2_points     = (const float*)d_in[5];
  const float* lidar_z       = (const float*)d_in[6];
  const float* m1w0=(const float*)d_in[7],  *m1g0=(const float*)d_in[9],  *m1e0=(const float*)d_in[10];
  const float* m1w1=(const float*)d_in[11], *m1g1=(const float*)d_in[13], *m1e1=(const float*)d_in[14];
  const float* piw =(const float*)d_in[15], *pib =(const float*)d_in[16], *pig =(const float*)d_in[17], *pie =(const float*)d_in[18];
  const float* m2w0=(const float*)d_in[19], *m2g0=(const float*)d_in[21], *m2e0=(const float*)d_in[22];
  const float* m2w1=(const float*)d_in[23], *m2g1=(const float*)d_in[25], *m2e1=(const float*)d_in[26];
  const float* pcw =(const float*)d_in[27], *pcb =(const float*)d_in[28], *pcg =(const float*)d_in[29], *pce =(const float*)d_in[30];
  const float* m3w0=(const float*)d_in[31], *m3g0=(const float*)d_in[33], *m3e0=(const float*)d_in[34];
  const float* m3w1=(const float*)d_in[35], *m3g1=(const float*)d_in[37], *m3e1=(const float*)d_in[38];
  float* out = (float*)d_out;

  float* ws     = (float*)d_ws;
  float* wxyz   = ws;                        // 24576
  float* normW  = wxyz   + 24576;            // 524288
  float* normF2 = normW  + 524288;           // 524288
  float* piwT   = normF2 + 524288;           // 384
  float* pcwT   = piwT   + 384;              // 640
  float* stats  = pcwT   + 640;              // 2048
  float* gram   = stats  + 2048;             // 128
  int*   idxq   = (int*)(gram + 128);        // 262144
  int*   idx2   = idxq   + 262144;           // 131072
  float* validf = (float*)(idx2 + 131072);   // 131072
  _Float16* pif1h = (_Float16*)(validf + 131072);   // 1048576 f16 = 524288 floats
  float* X1f    = validf + 131072 + 524288;
  _Float16* X1  = (_Float16*)X1f;            // 25165824 f16 = 12582912 floats
  float* y2f    = X1f + 12582912;
  _Float16* y2h = (_Float16*)y2f;            // 16777216 f16 = 8388608 floats
  float* y3f    = y2f + 8388608;
  _Float16* y3h = (_Float16*)y3f;            // 8388608 floats
  float* whb    = y3f + 8388608;             // f16 weights: 49152 f16 = 24576 floats
  _Float16* w1h = (_Float16*)whb;            // 12288
  _Float16* w2h = w1h + 12288;               // 8192
  _Float16* w3h = w2h + 8192;                // 8192
  _Float16* w4h = w3h + 8192;                // 4096
  _Float16* w5h = w4h + 4096;                // 12288
  _Float16* w6h = w5h + 12288;               // 4096
  // aliases (regions dead by the time they're overwritten):
  _Float16* y4h = (_Float16*)X1f;            // X1 dead after k_mfma_m1
  _Float16* y5h = (_Float16*)(X1f + 8388608);
  _Float16* y6h = y3h;                       // y3 dead after first k_mfma_pw64

  hipMemsetAsync(stats, 0, (2048+128)*sizeof(float), stream);
  k_prep<<<4388,256,0,stream>>>(warped_xyz, lidar_z, warped_points, f2_points,
                                m1w0, m1w1, piw, pcw, m2w0, m2w1, m3w0, m3w1,
                                wxyz, normW, normF2, piwT, pcwT,
                                w1h, w2h, w3h, w4h, w5h, w6h);
  k_knn<32,false><<<8192,256,0,stream>>>(warped_xyz, f2_xyz, idxq, nullptr);
  k_knn<16,true ><<<8192,256,0,stream>>>(xyz_proj, xyz_proj, idx2, validf);
  k_build_stats<<<1120,256,0,stream>>>(wxyz, f2_xyz, normW, normF2, idxq, idx2,
                                       w1h, X1, stats, gram);
  k_gram_fin<<<1,128,0,stream>>>(gram, piw, pib, pcw, pcb, stats);
  k_mfma_m1<<<1024,256,0,stream>>>(X1, w1h, w2h, m1g0, m1e0, stats, y2h);
  k_mfma_m2a<<<1024,256,0,stream>>>(wxyz, f2_xyz, idxq, piwT, pib, pig, pie,
                                    m1g1, m1e1, y2h, w3h, stats, y3h);
  k_mfma_pw64<<<1024,256,0,stream>>>(y3h, w4h, m2g0, m2e0,
                                     stats+3*256, stats+4*256, INV_R1, y4h);
  k_softmax1<<<2048,256,0,stream>>>(y2h, y4h, stats, m1g1, m1e1, m2g1, m2e1, pif1h);
  k_mfma_m3a<<<512,256,0,stream>>>(wxyz, warped_points, pif1h, idx2,
                                   pcwT, pcb, pcg, pce, w5h, stats, y5h);
  k_mfma_pw64<<<512,256,0,stream>>>(y5h, w6h, m3g0, m3e0,
                                    stats+6*256, stats+7*256, INV_R2, y6h);
  k_softmax2<<<2048,256,0,stream>>>(y6h, pif1h, idx2, validf, stats, m3g1, m3e1, out);
}

// Round 9
// 516.192 us; speedup vs baseline: 3.0051x; 1.0622x over previous
//
#include <hip/hip_runtime.h>
#include <math.h>

// ---------------- problem constants ----------------
constexpr int Bn  = 2;
constexpr int HWn = 4096;     // H*W
constexpr int Nn  = 4096;
constexpr int KQn = 32;
constexpr int KNn = 16;
constexpr float INV_R1 = 1.0f/262144.0f;   // exact pow2
constexpr float INV_R2 = 1.0f/131072.0f;   // exact pow2

typedef _Float16 f16x8 __attribute__((ext_vector_type(8)));
typedef float    f32x4 __attribute__((ext_vector_type(4)));

__device__ __forceinline__ float wred64(float v){
  #pragma unroll
  for (int m = 32; m > 0; m >>= 1) v += __shfl_xor(v, m, 64);
  return v;
}
__device__ __forceinline__ float leakyf(float v){ return v > 0.f ? v : 0.1f*v; }

__device__ __forceinline__ void bn_param(const float* st, int c, float inv_n,
                                         const float* g, const float* e,
                                         float& sc, float& sh){
  float mu  = st[c]*inv_n;
  float var = st[128+c]*inv_n - mu*mu;
  float s   = g[c]*rsqrtf(var + 1e-5f);
  sc = s; sh = e[c] - mu*s;
}

// Build the 70-channel stage-1 input row: [wxyz(3), f2_xyz[idx](3), normW*normF2(64)]
__device__ __forceinline__ void build_x70(int row,
    const float* __restrict__ wxyz, const float* __restrict__ f2_xyz,
    const float* __restrict__ normW, const float* __restrict__ normF2,
    const int* __restrict__ idxq, float* x){
  int p = row >> 5;
  int b = p >> 12;
  int idx = idxq[row];
  const float* wx = wxyz + (size_t)p*3;
  const float* fx = f2_xyz + ((size_t)b*Nn + idx)*3;
  x[0]=wx[0]; x[1]=wx[1]; x[2]=wx[2];
  x[3]=fx[0]; x[4]=fx[1]; x[5]=fx[2];
  const float4* nw = (const float4*)(normW  + (size_t)p*64);
  const float4* nf = (const float4*)(normF2 + ((size_t)b*Nn + idx)*64);
  #pragma unroll
  for (int c=0;c<16;c++){
    float4 a = nw[c], q = nf[c];
    x[6+4*c+0]=a.x*q.x; x[6+4*c+1]=a.y*q.y; x[6+4*c+2]=a.z*q.z; x[6+4*c+3]=a.w*q.w;
  }
}

// Build the 10-channel stage-2 geometry row
__device__ __forceinline__ void build_x10(int row,
    const float* __restrict__ wxyz, const int* __restrict__ idx2, float* x){
  int p = row >> 4, b = p >> 12;
  int idx = idx2[row];
  const float* nw = wxyz + (size_t)p*3;
  const float* gw = wxyz + ((size_t)b*HWn + idx)*3;
  float n0=nw[0],n1=nw[1],n2=nw[2];
  float g0=gw[0],g1=gw[1],g2=gw[2];
  float d0=g0-n0, d1=g1-n1, d2=g2-n2;
  x[0]=n0;x[1]=n1;x[2]=n2; x[3]=g0;x[4]=g1;x[5]=g2;
  x[6]=d0;x[7]=d1;x[8]=d2; x[9]=sqrtf(d0*d0+d1*d1+d2*d2+1e-20f);
}

// ---------------- prep: norms, wxyz, weight transposes + f16 weights ----------------
__global__ __launch_bounds__(256) void k_prep(
    const float* __restrict__ warped_xyz, const float* __restrict__ lidar_z,
    const float* __restrict__ warped_points, const float* __restrict__ f2_points,
    const float* __restrict__ m1w0, const float* __restrict__ m1w1,
    const float* __restrict__ piw, const float* __restrict__ pcw,
    const float* __restrict__ m2w0, const float* __restrict__ m2w1,
    const float* __restrict__ m3w0, const float* __restrict__ m3w1,
    float* __restrict__ wxyz, float* __restrict__ normW, float* __restrict__ normF2,
    float* __restrict__ piwT, float* __restrict__ pcwT,
    _Float16* __restrict__ w1h, _Float16* __restrict__ w2h,
    _Float16* __restrict__ w3h, _Float16* __restrict__ w4h,
    _Float16* __restrict__ w5h, _Float16* __restrict__ w6h)
{
  int blk = blockIdx.x, tid = threadIdx.x;
  if (blk < 4096){
    int lane = tid & 63;
    int p = blk*4 + (tid >> 6);            // 0..16383
    const float* src; float* dst;
    if (p < Bn*HWn){ src = warped_points + (size_t)p*64; dst = normW + (size_t)p*64; }
    else { int q = p - Bn*HWn; src = f2_points + (size_t)q*64; dst = normF2 + (size_t)q*64; }
    float x = src[lane];
    float m = wred64(x) * (1.f/64.f);
    float d = x - m;
    float ss = wred64(d*d);
    float s = fmaxf(sqrtf(ss*(1.f/63.f)), 1e-12f);
    dst[lane] = d / s;
  } else if (blk < 4192){
    int e = (blk-4096)*256 + tid;          // < 24576
    wxyz[e] = warped_xyz[e] * lidar_z[e/3];
  } else if (blk < 4196){
    int e = (blk-4192)*256 + tid;          // < 1024
    if (e < 384){ piwT[(e & 63)*6  + (e >> 6)] = piw[e]; }
    else if (e < 1024){ int f = e-384; pcwT[(f & 63)*10 + (f >> 6)] = pcw[f]; }
  } else {
    int e = (blk-4196)*256 + tid;          // < 49152
    if (e < 12288){                        // w1h[j][k] : [128 out][96 in-pad]
      int j = e/96, k = e - j*96;
      w1h[e] = (k < 70) ? (_Float16)m1w0[k*128 + j] : (_Float16)0.f;
    } else if (e < 20480){                 // w2h[d][c] : [64][128]
      int f = e - 12288; int d = f >> 7, c = f & 127;
      w2h[f] = (_Float16)m1w1[c*64 + d];
    } else if (e < 28672){                 // w3h[d][c] : [64][128]
      int f = e - 20480; int d = f >> 7, c = f & 127;
      w3h[f] = (_Float16)m2w0[c*64 + d];
    } else if (e < 32768){                 // w4h[d][c] : [64][64]
      int f = e - 28672; int d = f >> 6, c = f & 63;
      w4h[f] = (_Float16)m2w1[c*64 + d];
    } else if (e < 45056){                 // w5h[d][c] : [64][192]
      int f = e - 32768; int d = f/192, c = f - 192*d;
      w5h[f] = (_Float16)m3w0[c*64 + d];
    } else {                               // w6h[d][c] : [64][64]
      int f = e - 45056; int d = f >> 6, c = f & 63;
      w6h[f] = (_Float16)m3w1[c*64 + d];
    }
  }
}

// ---------------- exact k-smallest: 12-bit first-digit radix select ----------------
// Pass 1 uses 4096 bins over the informative bits [L-11, L] of (key - blockmin):
// expected bucket size ~1 => atomics spread (no serialization), class==rem => exit
// after one pass. Fallback 8-bit passes for residual ties. Both kNN problems in
// one launch: blocks 0..8191 = KQ(32), 8192..16383 = KN(16)+valid.
__global__ __launch_bounds__(256) void k_knn_all(
    const float* __restrict__ qA, const float* __restrict__ pA, int* __restrict__ oA,
    const float* __restrict__ qB, const float* __restrict__ pB, int* __restrict__ oB,
    float* __restrict__ ovalid)
{
  __shared__ int hist[4096];
  __shared__ int wsum[4];
  __shared__ unsigned int redm[4], redM[4];
  __shared__ int sh_sel, sh_rem, sh_cls, cnt_lt, cnt_eq;
  bool second = blockIdx.x >= 8192;
  int blk = second ? (blockIdx.x - 8192) : blockIdx.x;
  int K = second ? KNn : KQn;
  const float* qpts = second ? qB : qA;
  const float* pts  = second ? pB : pA;
  int* oidx = second ? oB : oA;
  int b = blk >> 12;
  int qi = blk & 4095;
  int tid = threadIdx.x;
  int lane = tid & 63, wv = tid >> 6;
  const float* qp = qpts + ((size_t)(b*HWn+qi))*3;
  float qx=qp[0], qy=qp[1], qz=qp[2];
  const float* pb = pts + (size_t)b*Nn*3;
  unsigned int key[16];
  {
    const float4* pb4 = (const float4*)(pb + (size_t)tid*48);  // 16 pts = 48 floats
    float4 v[12];
    #pragma unroll
    for (int i=0;i<12;i++) v[i] = pb4[i];
    const float* f = (const float*)v;
    #pragma unroll
    for (int i=0;i<16;i++){
      float dx = __fsub_rn(qx, f[i*3+0]);
      float dy = __fsub_rn(qy, f[i*3+1]);
      float dz = __fsub_rn(qz, f[i*3+2]);
      float d2 = __fadd_rn(__fadd_rn(__fmul_rn(dx,dx), __fmul_rn(dy,dy)), __fmul_rn(dz,dz));
      key[i] = __float_as_uint(d2);        // nonneg floats: uint order == float order
    }
  }
  // block min/max of keys
  unsigned int mn = key[0], mx = key[0];
  #pragma unroll
  for (int i=1;i<16;i++){ mn = min(mn, key[i]); mx = max(mx, key[i]); }
  #pragma unroll
  for (int m=32;m>0;m>>=1){
    mn = min(mn, (unsigned int)__shfl_xor((int)mn, m, 64));
    mx = max(mx, (unsigned int)__shfl_xor((int)mx, m, 64));
  }
  if (lane == 0){ redm[wv] = mn; redM[wv] = mx; }
  if (tid == 0){ cnt_lt = 0; cnt_eq = 0; }
  __syncthreads();
  mn = min(min(redm[0],redm[1]), min(redm[2],redm[3]));
  mx = max(max(redM[0],redM[1]), max(redM[2],redM[3]));
  unsigned int R = mx - mn;
  int L = (R == 0u) ? 0 : (31 - __clz(R));
  int shift = (L > 11) ? (L - 11) : 0;
  unsigned int dmask = 4095u;

  unsigned int active = 0xFFFFu, below = 0u;
  int rem = K;
  bool first = true;
  for (;;){
    __syncthreads();                       // guard hist reuse
    if (first){
      int4 z = {0,0,0,0};
      #pragma unroll
      for (int j=0;j<4;j++) ((int4*)hist)[tid + j*256] = z;
    } else {
      hist[tid] = 0;
    }
    __syncthreads();
    #pragma unroll
    for (int i=0;i<16;i++){
      if (active & (1u<<i))
        atomicAdd(&hist[(int)(((key[i]-mn) >> shift) & dmask)], 1);
    }
    __syncthreads();
    if (first){
      // hierarchical scan over 4096 bins: 16/thread
      int base = tid*16;
      int hv[16]; int tot = 0;
      #pragma unroll
      for (int i=0;i<16;i++){ hv[i] = hist[base+i]; tot += hv[i]; }
      int pref = tot;
      #pragma unroll
      for (int m=1;m<64;m<<=1){ int t = __shfl_up(pref, m, 64); if (lane >= m) pref += t; }
      if (lane == 63) wsum[wv] = pref;
      __syncthreads();
      int off = 0;
      #pragma unroll
      for (int i=0;i<3;i++) if (i < wv) off += wsum[i];
      pref += off;                         // inclusive prefix of thread totals
      if (pref >= rem && (pref - tot) < rem){
        int running = pref - tot;
        bool done = false;
        #pragma unroll
        for (int i=0;i<16;i++){
          if (!done && running + hv[i] >= rem){
            sh_sel = base + i;
            sh_rem = rem - running;
            sh_cls = hv[i];
            done = true;
          }
          if (!done) running += hv[i];
        }
      }
    } else {
      int h = hist[tid];
      int pref = h;
      #pragma unroll
      for (int m=1;m<64;m<<=1){ int t = __shfl_up(pref, m, 64); if (lane >= m) pref += t; }
      if (lane == 63) wsum[wv] = pref;
      __syncthreads();
      int off = 0;
      #pragma unroll
      for (int i=0;i<3;i++) if (i < wv) off += wsum[i];
      pref += off;
      if (pref >= rem && (pref - h) < rem){
        sh_sel = tid;
        sh_rem = rem - (pref - h);
        sh_cls = h;
      }
    }
    __syncthreads();
    unsigned int sel = (unsigned int)sh_sel; rem = sh_rem; int cls = sh_cls;
    #pragma unroll
    for (int i=0;i<16;i++){
      if (active & (1u<<i)){
        unsigned int d = ((key[i]-mn) >> shift) & dmask;
        if (d < sel) below |= (1u<<i);
        if (d != sel) active &= ~(1u<<i);
      }
    }
    if (cls == rem || shift == 0) break;
    int w = (shift < 8) ? shift : 8;
    shift -= w;
    dmask = (w == 8) ? 255u : ((1u<<w) - 1u);
    first = false;
  }
  // output: all 'below' + rem of the final equal-class
  size_t obase = ((size_t)(b*HWn+qi))*K;
  int nless = K - rem;
  const unsigned int U100 = __float_as_uint(100.0f);  // DIST*DIST
  #pragma unroll
  for (int i=0;i<16;i++){
    if (below & (1u<<i)){
      int s = atomicAdd(&cnt_lt, 1);
      oidx[obase+s] = tid*16 + i;
      if (second) ovalid[obase+s] = (key[i] < U100) ? 1.f : 0.f;
    } else if (active & (1u<<i)){
      int s = atomicAdd(&cnt_eq, 1);
      if (s < rem){
        oidx[obase+nless+s] = tid*16 + i;
        if (second) ovalid[obase+nless+s] = (key[i] < U100) ? 1.f : 0.f;
      }
    }
  }
}

// ---------------- fused: build X1 rows + y1 stats MFMA + Gram matrices ----------------
__global__ __launch_bounds__(256) void k_build_stats(
    const float* __restrict__ wxyz, const float* __restrict__ f2_xyz,
    const float* __restrict__ normW, const float* __restrict__ normF2,
    const int* __restrict__ idxq, const int* __restrict__ idx2,
    const _Float16* __restrict__ w1h,
    _Float16* __restrict__ X1, float* stats, float* __restrict__ gram)
{
  __shared__ float ssum[128], sssq[128];
  __shared__ float sacc[66];
  int blk = blockIdx.x, tid = threadIdx.x, lane = tid & 63;
  if (blk < 1024){
    int row = blk*256 + tid;
    {
      float x[70];
      build_x70(row, wxyz, f2_xyz, normW, normF2, idxq, x);
      unsigned int* d32 = (unsigned int*)(X1 + (size_t)row*96);
      union { unsigned int u; _Float16 h[2]; } pk;
      #pragma unroll
      for (int c=0;c<35;c++){
        pk.h[0] = (_Float16)x[2*c]; pk.h[1] = (_Float16)x[2*c+1];
        d32[c] = pk.u;
      }
      #pragma unroll
      for (int c=35;c<48;c++) d32[c] = 0u;
    }
    if (tid < 128){ ssum[tid]=0.f; sssq[tid]=0.f; }
    __syncthreads();
    int wave = tid >> 6;
    int quad = lane >> 4, n16 = lane & 15;
    float r1[8], r2[8];
    #pragma unroll
    for (int i=0;i<8;i++){ r1[i]=0.f; r2[i]=0.f; }
    for (int t=0;t<4;t++){
      int m0 = blk*256 + t*64 + wave*16;
      const _Float16* xr = X1 + (size_t)(m0 + n16)*96 + quad*8;
      f16x8 a0 = *(const f16x8*)(xr);
      f16x8 a1 = *(const f16x8*)(xr + 32);
      f16x8 a2 = *(const f16x8*)(xr + 64);
      #pragma unroll
      for (int nt = 0; nt < 8; nt++){
        const _Float16* wr = w1h + (size_t)(nt*16 + n16)*96 + quad*8;
        f16x8 b0 = *(const f16x8*)(wr);
        f16x8 b1 = *(const f16x8*)(wr + 32);
        f16x8 b2 = *(const f16x8*)(wr + 64);
        f32x4 acc = {0.f,0.f,0.f,0.f};
        acc = __builtin_amdgcn_mfma_f32_16x16x32_f16(a0, b0, acc, 0,0,0);
        acc = __builtin_amdgcn_mfma_f32_16x16x32_f16(a1, b1, acc, 0,0,0);
        acc = __builtin_amdgcn_mfma_f32_16x16x32_f16(a2, b2, acc, 0,0,0);
        float s1 = acc[0]+acc[1]+acc[2]+acc[3];
        float s2 = acc[0]*acc[0]+acc[1]*acc[1]+acc[2]*acc[2]+acc[3]*acc[3];
        s1 += __shfl_xor(s1, 16, 64); s1 += __shfl_xor(s1, 32, 64);
        s2 += __shfl_xor(s2, 16, 64); s2 += __shfl_xor(s2, 32, 64);
        r1[nt] += s1; r2[nt] += s2;
      }
    }
    if (quad == 0){
      #pragma unroll
      for (int nt=0;nt<8;nt++){
        atomicAdd(&ssum[nt*16+n16], r1[nt]); atomicAdd(&sssq[nt*16+n16], r2[nt]);
      }
    }
    __syncthreads();
    if (tid < 128){ atomicAdd(&stats[tid], ssum[tid]); atomicAdd(&stats[128+tid], sssq[tid]); }
  } else if (blk < 1088){
    float a[28];
    #pragma unroll
    for (int q=0;q<28;q++) a[q]=0.f;
    int g = (blk-1024)*256 + tid;
    for (int s=0;s<16;s++){
      int row = g + s*16384;
      int p = row >> 5, b = p >> 12;
      int idx = idxq[row];
      const float* wx = wxyz + (size_t)p*3;
      const float* fx = f2_xyz + ((size_t)b*Nn + idx)*3;
      float xt[7] = {wx[0],wx[1],wx[2],fx[0],fx[1],fx[2],1.f};
      int q=0;
      #pragma unroll
      for (int i=0;i<7;i++)
        #pragma unroll
        for (int j=i;j<7;j++) a[q++] += xt[i]*xt[j];
    }
    if (tid < 28) sacc[tid]=0.f;
    __syncthreads();
    #pragma unroll
    for (int q=0;q<28;q++){
      float v = wred64(a[q]);
      if (lane==0) atomicAdd(&sacc[q], v);
    }
    __syncthreads();
    if (tid < 28) atomicAdd(&gram[tid], sacc[tid]);
  } else {
    float a[66];
    #pragma unroll
    for (int q=0;q<66;q++) a[q]=0.f;
    int g = (blk-1088)*256 + tid;
    for (int s=0;s<16;s++){
      int row = g + s*8192;
      float x[10];
      build_x10(row, wxyz, idx2, x);
      float xt[11] = {x[0],x[1],x[2],x[3],x[4],x[5],x[6],x[7],x[8],x[9],1.f};
      int q=0;
      #pragma unroll
      for (int i=0;i<11;i++)
        #pragma unroll
        for (int j=i;j<11;j++) a[q++] += xt[i]*xt[j];
    }
    if (tid < 66) sacc[tid]=0.f;
    __syncthreads();
    #pragma unroll
    for (int q=0;q<66;q++){
      float v = wred64(a[q]);
      if (lane==0) atomicAdd(&sacc[q], v);
    }
    __syncthreads();
    if (tid < 66) atomicAdd(&gram[32+tid], sacc[tid]);
  }
}

__global__ __launch_bounds__(128) void k_gram_fin(
    const float* __restrict__ gram,
    const float* __restrict__ piw, const float* __restrict__ pib,
    const float* __restrict__ pcw, const float* __restrict__ pcb,
    float* stats)
{
  int tid = threadIdx.x;
  if (tid < 64){
    int c = tid;
    float wt[7];
    #pragma unroll
    for (int i=0;i<6;i++) wt[i] = piw[i*64+c];
    wt[6] = pib[c];
    const float* G = gram;
    float sum=0.f, ssq=0.f;
    #pragma unroll
    for (int i=0;i<7;i++){
      int offi = i*7 - (i*(i-1))/2;
      sum += wt[i]*G[offi + (6-i)];
      #pragma unroll
      for (int j=0;j<7;j++){
        int ii = i<j? i : j, jj = i<j? j : i;
        int o = ii*7 - (ii*(ii-1))/2 + (jj-ii);
        ssq += wt[i]*wt[j]*G[o];
      }
    }
    stats[2*256+c] = sum; stats[2*256+128+c] = ssq;
  } else {
    int c = tid-64;
    float wt[11];
    #pragma unroll
    for (int i=0;i<10;i++) wt[i] = pcw[i*64+c];
    wt[10] = pcb[c];
    const float* G = gram + 32;
    float sum=0.f, ssq=0.f;
    #pragma unroll
    for (int i=0;i<11;i++){
      int offi = i*11 - (i*(i-1))/2;
      sum += wt[i]*G[offi + (10-i)];
      #pragma unroll
      for (int j=0;j<11;j++){
        int ii = i<j? i : j, jj = i<j? j : i;
        int o = ii*11 - (ii*(ii-1))/2 + (jj-ii);
        ssq += wt[i]*wt[j]*G[o];
      }
    }
    stats[5*256+c] = sum; stats[5*256+128+c] = ssq;
  }
}

// ---------------- MFMA m1: 4 tiles/block; y1 -> BN/leaky -> t (LDS) -> x W2 -> y2 ----------------
__global__ __launch_bounds__(256) void k_mfma_m1(
    const _Float16* __restrict__ X1, const _Float16* __restrict__ w1h,
    const _Float16* __restrict__ w2h,
    const float* __restrict__ m1g0, const float* __restrict__ m1e0,
    float* stats, _Float16* __restrict__ y2h)
{
  __shared__ _Float16 st[64*136];
  __shared__ float sc1[128], sh1[128], ssum[64], sssq[64];
  int tid = threadIdx.x;
  if (tid < 128){
    float s,h; bn_param(stats, tid, INV_R1, m1g0, m1e0, s, h);
    sc1[tid]=s; sh1[tid]=h;
  }
  if (tid < 64){ ssum[tid]=0.f; sssq[tid]=0.f; }
  __syncthreads();
  int wave = tid >> 6, lane = tid & 63;
  int quad = lane >> 4, n16 = lane & 15;
  float r1[4], r2[4];
  #pragma unroll
  for (int i=0;i<4;i++){ r1[i]=0.f; r2[i]=0.f; }
  for (int t=0;t<4;t++){
    int m0 = blockIdx.x*256 + t*64 + wave*16;
    const _Float16* xr = X1 + (size_t)(m0 + n16)*96 + quad*8;
    f16x8 a0 = *(const f16x8*)(xr);
    f16x8 a1 = *(const f16x8*)(xr + 32);
    f16x8 a2 = *(const f16x8*)(xr + 64);
    #pragma unroll
    for (int nt = 0; nt < 8; nt++){
      const _Float16* wr = w1h + (size_t)(nt*16 + n16)*96 + quad*8;
      f16x8 b0 = *(const f16x8*)(wr);
      f16x8 b1 = *(const f16x8*)(wr + 32);
      f16x8 b2 = *(const f16x8*)(wr + 64);
      f32x4 acc = {0.f,0.f,0.f,0.f};
      acc = __builtin_amdgcn_mfma_f32_16x16x32_f16(a0, b0, acc, 0,0,0);
      acc = __builtin_amdgcn_mfma_f32_16x16x32_f16(a1, b1, acc, 0,0,0);
      acc = __builtin_amdgcn_mfma_f32_16x16x32_f16(a2, b2, acc, 0,0,0);
      int ch = nt*16 + n16;
      float sc = sc1[ch], sh = sh1[ch];
      #pragma unroll
      for (int r=0;r<4;r++){
        float v = leakyf(acc[r]*sc + sh);
        st[(size_t)(wave*16 + quad*4 + r)*136 + ch] = (_Float16)v;
      }
    }
    __syncthreads();
    const _Float16* tr = st + (size_t)(wave*16 + n16)*136 + quad*8;
    f16x8 t0 = *(const f16x8*)(tr);
    f16x8 t1 = *(const f16x8*)(tr + 32);
    f16x8 t2 = *(const f16x8*)(tr + 64);
    f16x8 t3 = *(const f16x8*)(tr + 96);
    #pragma unroll
    for (int nt = 0; nt < 4; nt++){
      const _Float16* wr = w2h + (size_t)(nt*16 + n16)*128 + quad*8;
      f16x8 b0 = *(const f16x8*)(wr);
      f16x8 b1 = *(const f16x8*)(wr + 32);
      f16x8 b2 = *(const f16x8*)(wr + 64);
      f16x8 b3 = *(const f16x8*)(wr + 96);
      f32x4 acc = {0.f,0.f,0.f,0.f};
      acc = __builtin_amdgcn_mfma_f32_16x16x32_f16(t0, b0, acc, 0,0,0);
      acc = __builtin_amdgcn_mfma_f32_16x16x32_f16(t1, b1, acc, 0,0,0);
      acc = __builtin_amdgcn_mfma_f32_16x16x32_f16(t2, b2, acc, 0,0,0);
      acc = __builtin_amdgcn_mfma_f32_16x16x32_f16(t3, b3, acc, 0,0,0);
      int ch = nt*16 + n16;
      #pragma unroll
      for (int r=0;r<4;r++){
        int rowg = blockIdx.x*256 + t*64 + wave*16 + quad*4 + r;
        y2h[(size_t)rowg*64 + ch] = (_Float16)acc[r];
      }
      float s1 = acc[0]+acc[1]+acc[2]+acc[3];
      float s2 = acc[0]*acc[0]+acc[1]*acc[1]+acc[2]*acc[2]+acc[3]*acc[3];
      s1 += __shfl_xor(s1, 16, 64); s1 += __shfl_xor(s1, 32, 64);
      s2 += __shfl_xor(s2, 16, 64); s2 += __shfl_xor(s2, 32, 64);
      r1[nt] += s1; r2[nt] += s2;
    }
    __syncthreads();
  }
  if (quad == 0){
    #pragma unroll
    for (int nt=0;nt<4;nt++){
      atomicAdd(&ssum[nt*16+n16], r1[nt]); atomicAdd(&sssq[nt*16+n16], r2[nt]);
    }
  }
  __syncthreads();
  if (tid < 64){ atomicAdd(&stats[1*256+tid], ssum[tid]); atomicAdd(&stats[1*256+128+tid], sssq[tid]); }
}

// ---------------- MFMA m2a: 4 tiles/block; u=[pi_enc|feat] in LDS, y3 = u x W3 ----------------
__global__ __launch_bounds__(256) void k_mfma_m2a(
    const float* __restrict__ wxyz, const float* __restrict__ f2_xyz,
    const int* __restrict__ idxq,
    const float* __restrict__ piwT, const float* __restrict__ pib,
    const float* __restrict__ pig, const float* __restrict__ pie,
    const float* __restrict__ m1g1, const float* __restrict__ m1e1,
    const _Float16* __restrict__ y2h, const _Float16* __restrict__ w3h,
    float* stats, _Float16* __restrict__ y3h)
{
  __shared__ _Float16 su[64*136];
  __shared__ float spw[384];
  __shared__ float scp[64], shp[64], sc2[64], sh2[64], ssum[64], sssq[64];
  int tid = threadIdx.x;
  for (int d = tid; d < 384; d += 256) spw[d] = piwT[d];
  if (tid < 64){
    float s,h;
    bn_param(stats+2*256, tid, INV_R1, pig,  pie,  s, h); scp[tid]=s; shp[tid]=h;
    bn_param(stats+1*256, tid, INV_R1, m1g1, m1e1, s, h); sc2[tid]=s; sh2[tid]=h;
    ssum[tid]=0.f; sssq[tid]=0.f;
  }
  __syncthreads();
  int r = tid & 63, cg = tid >> 6;
  int wave = tid >> 6, lane = tid & 63, quad = lane >> 4, n16 = lane & 15;
  float r1[4], r2[4];
  #pragma unroll
  for (int i=0;i<4;i++){ r1[i]=0.f; r2[i]=0.f; }
  for (int t=0;t<4;t++){
    int rowg = blockIdx.x*256 + t*64 + r;
    {
      int p = rowg >> 5, b = p >> 12;
      int idx = idxq[rowg];
      const float* wx = wxyz + (size_t)p*3;
      const float* fx = f2_xyz + ((size_t)b*Nn + idx)*3;
      float x0=wx[0],x1=wx[1],x2=wx[2],x3=fx[0],x4=fx[1],x5=fx[2];
      #pragma unroll
      for (int jj=0;jj<16;jj++){
        int j = cg*16 + jj;
        const float* pw = spw + j*6;
        float e = pib[j] + x0*pw[0]+x1*pw[1]+x2*pw[2]+x3*pw[3]+x4*pw[4]+x5*pw[5];
        su[r*136 + j] = (_Float16)leakyf(e*scp[j] + shp[j]);
      }
      const f16x8* yr = (const f16x8*)(y2h + (size_t)rowg*64 + cg*16);
      f16x8 q0 = yr[0], q1 = yr[1];
      #pragma unroll
      for (int jj=0;jj<8;jj++){
        int c = cg*16 + jj;
        su[r*136 + 64 + c] = (_Float16)leakyf((float)q0[jj]*sc2[c] + sh2[c]);
      }
      #pragma unroll
      for (int jj=0;jj<8;jj++){
        int c = cg*16 + 8 + jj;
        su[r*136 + 64 + c] = (_Float16)leakyf((float)q1[jj]*sc2[c] + sh2[c]);
      }
    }
    __syncthreads();
    const _Float16* ur = su + (size_t)(wave*16 + n16)*136 + quad*8;
    f16x8 a0 = *(const f16x8*)(ur);
    f16x8 a1 = *(const f16x8*)(ur + 32);
    f16x8 a2 = *(const f16x8*)(ur + 64);
    f16x8 a3 = *(const f16x8*)(ur + 96);
    #pragma unroll
    for (int nt = 0; nt < 4; nt++){
      const _Float16* wr = w3h + (size_t)(nt*16 + n16)*128 + quad*8;
      f16x8 b0 = *(const f16x8*)(wr);
      f16x8 b1 = *(const f16x8*)(wr + 32);
      f16x8 b2 = *(const f16x8*)(wr + 64);
      f16x8 b3 = *(const f16x8*)(wr + 96);
      f32x4 acc = {0.f,0.f,0.f,0.f};
      acc = __builtin_amdgcn_mfma_f32_16x16x32_f16(a0, b0, acc, 0,0,0);
      acc = __builtin_amdgcn_mfma_f32_16x16x32_f16(a1, b1, acc, 0,0,0);
      acc = __builtin_amdgcn_mfma_f32_16x16x32_f16(a2, b2, acc, 0,0,0);
      acc = __builtin_amdgcn_mfma_f32_16x16x32_f16(a3, b3, acc, 0,0,0);
      int ch = nt*16 + n16;
      #pragma unroll
      for (int rr=0;rr<4;rr++){
        int rg = blockIdx.x*256 + t*64 + wave*16 + quad*4 + rr;
        y3h[(size_t)rg*64 + ch] = (_Float16)acc[rr];
      }
      float s1 = acc[0]+acc[1]+acc[2]+acc[3];
      float s2 = acc[0]*acc[0]+acc[1]*acc[1]+acc[2]*acc[2]+acc[3]*acc[3];
      s1 += __shfl_xor(s1, 16, 64); s1 += __shfl_xor(s1, 32, 64);
      s2 += __shfl_xor(s2, 16, 64); s2 += __shfl_xor(s2, 32, 64);
      r1[nt] += s1; r2[nt] += s2;
    }
    __syncthreads();
  }
  if (quad == 0){
    #pragma unroll
    for (int nt=0;nt<4;nt++){
      atomicAdd(&ssum[nt*16+n16], r1[nt]); atomicAdd(&sssq[nt*16+n16], r2[nt]);
    }
  }
  __syncthreads();
  if (tid < 64){ atomicAdd(&stats[3*256+tid], ssum[tid]); atomicAdd(&stats[3*256+128+tid], sssq[tid]); }
}

// ---------------- generic MFMA pointwise 64->64, 4 tiles/block ----------------
__global__ __launch_bounds__(256) void k_mfma_pw64(
    const _Float16* __restrict__ yin, const _Float16* __restrict__ wh,
    const float* __restrict__ g, const float* __restrict__ e,
    const float* statsIn, float* statsOut, float inv_n,
    _Float16* __restrict__ yout)
{
  __shared__ _Float16 stt[64*72];
  __shared__ float sc[64], sh[64], ssum[64], sssq[64];
  int tid = threadIdx.x;
  if (tid < 64){
    float s,h; bn_param(statsIn, tid, inv_n, g, e, s, h);
    sc[tid]=s; sh[tid]=h; ssum[tid]=0.f; sssq[tid]=0.f;
  }
  __syncthreads();
  int r = tid & 63, cg = tid >> 6;
  int wave = tid >> 6, lane = tid & 63, quad = lane >> 4, n16 = lane & 15;
  float r1[4], r2[4];
  #pragma unroll
  for (int i=0;i<4;i++){ r1[i]=0.f; r2[i]=0.f; }
  for (int t=0;t<4;t++){
    int rowg = blockIdx.x*256 + t*64 + r;
    const f16x8* yr = (const f16x8*)(yin + (size_t)rowg*64 + cg*16);
    f16x8 q0 = yr[0], q1 = yr[1];
    #pragma unroll
    for (int jj=0;jj<8;jj++){
      int c = cg*16 + jj;
      stt[r*72 + c] = (_Float16)leakyf((float)q0[jj]*sc[c] + sh[c]);
    }
    #pragma unroll
    for (int jj=0;jj<8;jj++){
      int c = cg*16 + 8 + jj;
      stt[r*72 + c] = (_Float16)leakyf((float)q1[jj]*sc[c] + sh[c]);
    }
    __syncthreads();
    const _Float16* tr = stt + (size_t)(wave*16 + n16)*72 + quad*8;
    f16x8 a0 = *(const f16x8*)(tr);
    f16x8 a1 = *(const f16x8*)(tr + 32);
    #pragma unroll
    for (int nt = 0; nt < 4; nt++){
      const _Float16* wr = wh + (size_t)(nt*16 + n16)*64 + quad*8;
      f16x8 b0 = *(const f16x8*)(wr);
      f16x8 b1 = *(const f16x8*)(wr + 32);
      f32x4 acc = {0.f,0.f,0.f,0.f};
      acc = __builtin_amdgcn_mfma_f32_16x16x32_f16(a0, b0, acc, 0,0,0);
      acc = __builtin_amdgcn_mfma_f32_16x16x32_f16(a1, b1, acc, 0,0,0);
      int ch = nt*16 + n16;
      #pragma unroll
      for (int rr=0;rr<4;rr++){
        int rg = blockIdx.x*256 + t*64 + wave*16 + quad*4 + rr;
        yout[(size_t)rg*64 + ch] = (_Float16)acc[rr];
      }
      float s1 = acc[0]+acc[1]+acc[2]+acc[3];
      float s2 = acc[0]*acc[0]+acc[1]*acc[1]+acc[2]*acc[2]+acc[3]*acc[3];
      s1 += __shfl_xor(s1, 16, 64); s1 += __shfl_xor(s1, 32, 64);
      s2 += __shfl_xor(s2, 16, 64); s2 += __shfl_xor(s2, 32, 64);
      r1[nt] += s1; r2[nt] += s2;
    }
    __syncthreads();
  }
  if (quad == 0){
    #pragma unroll
    for (int nt=0;nt<4;nt++){
      atomicAdd(&ssum[nt*16+n16], r1[nt]); atomicAdd(&sssq[nt*16+n16], r2[nt]);
    }
  }
  __syncthreads();
  if (tid < 64){ atomicAdd(&statsOut[tid], ssum[tid]); atomicAdd(&statsOut[128+tid], sssq[tid]); }
}

// ---------------- MFMA m3a: 4 tiles/block; v=[pc_enc|wp|pif1_g] (192ch), y5 = v x W5 ----------------
__global__ __launch_bounds__(256) void k_mfma_m3a(
    const float* __restrict__ wxyz, const float* __restrict__ warped_points,
    const _Float16* __restrict__ pif1h, const int* __restrict__ idx2,
    const float* __restrict__ pcwT, const float* __restrict__ pcb,
    const float* __restrict__ pcg, const float* __restrict__ pce,
    const _Float16* __restrict__ w5h,
    float* stats, _Float16* __restrict__ y5h)
{
  __shared__ _Float16 sv[64*200];
  __shared__ float spw[640];
  __shared__ float scp[64], shp[64], ssum[64], sssq[64];
  int tid = threadIdx.x;
  for (int d = tid; d < 640; d += 256) spw[d] = pcwT[d];
  if (tid < 64){
    float s,h; bn_param(stats+5*256, tid, INV_R2, pcg, pce, s, h);
    scp[tid]=s; shp[tid]=h; ssum[tid]=0.f; sssq[tid]=0.f;
  }
  __syncthreads();
  int r = tid & 63, cg = tid >> 6;
  int wave = tid >> 6, lane = tid & 63, quad = lane >> 4, n16 = lane & 15;
  float r1[4], r2[4];
  #pragma unroll
  for (int i=0;i<4;i++){ r1[i]=0.f; r2[i]=0.f; }
  for (int t=0;t<4;t++){
    int rowg = blockIdx.x*256 + t*64 + r;
    {
      int p = rowg >> 4, b = p >> 12;
      int idx = idx2[rowg];
      float x[10];
      build_x10(rowg, wxyz, idx2, x);
      #pragma unroll
      for (int jj=0;jj<16;jj++){
        int j = cg*16 + jj;
        const float* pw = spw + j*10;
        float e = pcb[j];
        #pragma unroll
        for (int i=0;i<10;i++) e += x[i]*pw[i];
        sv[r*200 + j] = (_Float16)leakyf(e*scp[j] + shp[j]);
      }
      const float4* wp = (const float4*)(warped_points + (size_t)p*64 + cg*16);
      #pragma unroll
      for (int v4=0; v4<4; v4++){
        float4 q = wp[v4];
        int c = 64 + cg*16 + v4*4;
        sv[r*200 + c + 0] = (_Float16)q.x;
        sv[r*200 + c + 1] = (_Float16)q.y;
        sv[r*200 + c + 2] = (_Float16)q.z;
        sv[r*200 + c + 3] = (_Float16)q.w;
      }
      const f16x8* pg = (const f16x8*)(pif1h + ((size_t)(b*HWn) + idx)*64 + cg*16);
      f16x8 g0 = pg[0], g1 = pg[1];
      #pragma unroll
      for (int jj=0;jj<8;jj++) sv[r*200 + 128 + cg*16 + jj] = g0[jj];
      #pragma unroll
      for (int jj=0;jj<8;jj++) sv[r*200 + 136 + cg*16 + jj] = g1[jj];
    }
    __syncthreads();
    const _Float16* vr = sv + (size_t)(wave*16 + n16)*200 + quad*8;
    f16x8 a0 = *(const f16x8*)(vr);
    f16x8 a1 = *(const f16x8*)(vr + 32);
    f16x8 a2 = *(const f16x8*)(vr + 64);
    f16x8 a3 = *(const f16x8*)(vr + 96);
    f16x8 a4 = *(const f16x8*)(vr + 128);
    f16x8 a5 = *(const f16x8*)(vr + 160);
    #pragma unroll
    for (int nt = 0; nt < 4; nt++){
      const _Float16* wr = w5h + (size_t)(nt*16 + n16)*192 + quad*8;
      f32x4 acc = {0.f,0.f,0.f,0.f};
      acc = __builtin_amdgcn_mfma_f32_16x16x32_f16(a0, *(const f16x8*)(wr),       acc, 0,0,0);
      acc = __builtin_amdgcn_mfma_f32_16x16x32_f16(a1, *(const f16x8*)(wr + 32),  acc, 0,0,0);
      acc = __builtin_amdgcn_mfma_f32_16x16x32_f16(a2, *(const f16x8*)(wr + 64),  acc, 0,0,0);
      acc = __builtin_amdgcn_mfma_f32_16x16x32_f16(a3, *(const f16x8*)(wr + 96),  acc, 0,0,0);
      acc = __builtin_amdgcn_mfma_f32_16x16x32_f16(a4, *(const f16x8*)(wr + 128), acc, 0,0,0);
      acc = __builtin_amdgcn_mfma_f32_16x16x32_f16(a5, *(const f16x8*)(wr + 160), acc, 0,0,0);
      int ch = nt*16 + n16;
      #pragma unroll
      for (int rr=0;rr<4;rr++){
        int rg = blockIdx.x*256 + t*64 + wave*16 + quad*4 + rr;
        y5h[(size_t)rg*64 + ch] = (_Float16)acc[rr];
      }
      float s1 = acc[0]+acc[1]+acc[2]+acc[3];
      float s2 = acc[0]*acc[0]+acc[1]*acc[1]+acc[2]*acc[2]+acc[3]*acc[3];
      s1 += __shfl_xor(s1, 16, 64); s1 += __shfl_xor(s1, 32, 64);
      s2 += __shfl_xor(s2, 16, 64); s2 += __shfl_xor(s2, 32, 64);
      r1[nt] += s1; r2[nt] += s2;
    }
    __syncthreads();
  }
  if (quad == 0){
    #pragma unroll
    for (int nt=0;nt<4;nt++){
      atomicAdd(&ssum[nt*16+n16], r1[nt]); atomicAdd(&sssq[nt*16+n16], r2[nt]);
    }
  }
  __syncthreads();
  if (tid < 64){ atomicAdd(&stats[6*256+tid], ssum[tid]); atomicAdd(&stats[6*256+128+tid], sssq[tid]); }
}

// ---------------- stage-1 softmax over KQ, weighted sum of feat -> pif1 (f16) ----------------
__global__ __launch_bounds__(256) void k_softmax1(
    const _Float16* __restrict__ y2h, const _Float16* __restrict__ y4h,
    const float* stats,
    const float* __restrict__ m1g1, const float* __restrict__ m1e1,
    const float* __restrict__ m2g1, const float* __restrict__ m2e1,
    _Float16* __restrict__ pif1h)
{
  int tid = threadIdx.x, lane = tid & 63;
  int p = blockIdx.x*4 + (tid >> 6);
  int d = lane;
  float sc2,sh2,sc4,sh4;
  bn_param(stats+1*256, d, INV_R1, m1g1, m1e1, sc2, sh2);
  bn_param(stats+4*256, d, INV_R1, m2g1, m2e1, sc4, sh4);
  size_t rb = (size_t)p*KQn;
  float v[32]; float mx = -1e30f;
  #pragma unroll
  for (int k=0;k<32;k++){
    float t = leakyf((float)y4h[(rb+k)*64 + d]*sc4 + sh4);
    v[k] = t; mx = fmaxf(mx, t);
  }
  float se = 0.f;
  #pragma unroll
  for (int k=0;k<32;k++){ float ev = __expf(v[k]-mx); v[k]=ev; se += ev; }
  float inv = 1.f/se, acc = 0.f;
  #pragma unroll
  for (int k=0;k<32;k++){
    float f = leakyf((float)y2h[(rb+k)*64 + d]*sc2 + sh2);
    acc += v[k]*f;
  }
  pif1h[(size_t)p*64 + d] = (_Float16)(acc*inv);
}

// ---------------- stage-2 masked softmax over KN, weighted sum of gathered pif1 ----------------
__global__ __launch_bounds__(256) void k_softmax2(
    const _Float16* __restrict__ y6h, const _Float16* __restrict__ pif1h,
    const int* __restrict__ idx2, const float* __restrict__ validf,
    const float* stats,
    const float* __restrict__ m3g1, const float* __restrict__ m3e1,
    float* __restrict__ out)
{
  int tid = threadIdx.x, lane = tid & 63;
  int p = blockIdx.x*4 + (tid >> 6);
  int b = p >> 12;
  int d = lane;
  float sc,sh; bn_param(stats+7*256, d, INV_R2, m3g1, m3e1, sc, sh);
  size_t rb = (size_t)p*KNn;
  float v[16]; float mx = -1e30f;
  #pragma unroll
  for (int k=0;k<16;k++){
    float t = leakyf((float)y6h[(rb+k)*64 + d]*sc + sh);
    t = (validf[rb+k] > 0.5f) ? t : -1e10f;
    v[k] = t; mx = fmaxf(mx, t);
  }
  float se = 0.f;
  #pragma unroll
  for (int k=0;k<16;k++){ float ev = __expf(v[k]-mx); v[k]=ev; se += ev; }
  float inv = 1.f/se, acc = 0.f;
  #pragma unroll
  for (int k=0;k<16;k++){
    int idx = idx2[rb+k];
    acc += v[k]*(float)pif1h[((size_t)(b*HWn) + idx)*64 + d];
  }
  out[(size_t)p*64 + d] = acc*inv;
}

// ---------------- launcher ----------------
extern "C" void kernel_launch(void* const* d_in, const int* in_sizes, int n_in,
                              void* d_out, int out_size, void* d_ws, size_t ws_size,
                              hipStream_t stream)
{
  (void)in_sizes; (void)n_in; (void)out_size; (void)ws_size;
  const float* xyz_proj      = (const float*)d_in[0];
  const float* warped_xyz    = (const float*)d_in[1];
  const float* warped_points = (const float*)d_in[2];
  const float* f2_xyz        = (const float*)d_in[4];
  const float* f2_points     = (const float*)d_in[5];
  const float* lidar_z       = (const float*)d_in[6];
  const float* m1w0=(const float*)d_in[7],  *m1g0=(const float*)d_in[9],  *m1e0=(const float*)d_in[10];
  const float* m1w1=(const float*)d_in[11], *m1g1=(const float*)d_in[13], *m1e1=(const float*)d_in[14];
  const float* piw =(const float*)d_in[15], *pib =(const float*)d_in[16], *pig =(const float*)d_in[17], *pie =(const float*)d_in[18];
  const float* m2w0=(const float*)d_in[19], *m2g0=(const float*)d_in[21], *m2e0=(const float*)d_in[22];
  const float* m2w1=(const float*)d_in[23], *m2g1=(const float*)d_in[25], *m2e1=(const float*)d_in[26];
  const float* pcw =(const float*)d_in[27], *pcb =(const float*)d_in[28], *pcg =(const float*)d_in[29], *pce =(const float*)d_in[30];
  const float* m3w0=(const float*)d_in[31], *m3g0=(const float*)d_in[33], *m3e0=(const float*)d_in[34];
  const float* m3w1=(const float*)d_in[35], *m3g1=(const float*)d_in[37], *m3e1=(const float*)d_in[38];
  float* out = (float*)d_out;

  float* ws     = (float*)d_ws;
  float* wxyz   = ws;                        // 24576
  float* normW  = wxyz   + 24576;            // 524288
  float* normF2 = normW  + 524288;           // 524288
  float* piwT   = normF2 + 524288;           // 384
  float* pcwT   = piwT   + 384;              // 640
  float* stats  = pcwT   + 640;              // 2048
  float* gram   = stats  + 2048;             // 128
  int*   idxq   = (int*)(gram + 128);        // 262144
  int*   idx2   = idxq   + 262144;           // 131072
  float* validf = (float*)(idx2 + 131072);   // 131072
  _Float16* pif1h = (_Float16*)(validf + 131072);   // 1048576 f16 = 524288 floats
  float* X1f    = validf + 131072 + 524288;
  _Float16* X1  = (_Float16*)X1f;            // 25165824 f16 = 12582912 floats
  float* y2f    = X1f + 12582912;
  _Float16* y2h = (_Float16*)y2f;            // 16777216 f16 = 8388608 floats
  float* y3f    = y2f + 8388608;
  _Float16* y3h = (_Float16*)y3f;            // 8388608 floats
  float* whb    = y3f + 8388608;             // f16 weights: 49152 f16 = 24576 floats
  _Float16* w1h = (_Float16*)whb;            // 12288
  _Float16* w2h = w1h + 12288;               // 8192
  _Float16* w3h = w2h + 8192;                // 8192
  _Float16* w4h = w3h + 8192;                // 4096
  _Float16* w5h = w4h + 4096;                // 12288
  _Float16* w6h = w5h + 12288;               // 4096
  // aliases (regions dead by the time they're overwritten):
  _Float16* y4h = (_Float16*)X1f;            // X1 dead after k_mfma_m1
  _Float16* y5h = (_Float16*)(X1f + 8388608);
  _Float16* y6h = y3h;                       // y3 dead after first k_mfma_pw64

  hipMemsetAsync(stats, 0, (2048+128)*sizeof(float), stream);
  k_prep<<<4388,256,0,stream>>>(warped_xyz, lidar_z, warped_points, f2_points,
                                m1w0, m1w1, piw, pcw, m2w0, m2w1, m3w0, m3w1,
                                wxyz, normW, normF2, piwT, pcwT,
                                w1h, w2h, w3h, w4h, w5h, w6h);
  k_knn_all<<<16384,256,0,stream>>>(warped_xyz, f2_xyz, idxq,
                                    xyz_proj, xyz_proj, idx2, validf);
  k_build_stats<<<1120,256,0,stream>>>(wxyz, f2_xyz, normW, normF2, idxq, idx2,
                                       w1h, X1, stats, gram);
  k_gram_fin<<<1,128,0,stream>>>(gram, piw, pib, pcw, pcb, stats);
  k_mfma_m1<<<1024,256,0,stream>>>(X1, w1h, w2h, m1g0, m1e0, stats, y2h);
  k_mfma_m2a<<<1024,256,0,stream>>>(wxyz, f2_xyz, idxq, piwT, pib, pig, pie,
                                    m1g1, m1e1, y2h, w3h, stats, y3h);
  k_mfma_pw64<<<1024,256,0,stream>>>(y3h, w4h, m2g0, m2e0,
                                     stats+3*256, stats+4*256, INV_R1, y4h);
  k_softmax1<<<2048,256,0,stream>>>(y2h, y4h, stats, m1g1, m1e1, m2g1, m2e1, pif1h);
  k_mfma_m3a<<<512,256,0,stream>>>(wxyz, warped_points, pif1h, idx2,
                                   pcwT, pcb, pcg, pce, w5h, stats, y5h);
  k_mfma_pw64<<<512,256,0,stream>>>(y5h, w6h, m3g0, m3e0,
                                    stats+6*256, stats+7*256, INV_R2, y6h);
  k_softmax2<<<2048,256,0,stream>>>(y6h, pif1h, idx2, validf, stats, m3g1, m3e1, out);
}